// Round 4
// baseline (385.305 us; speedup 1.0000x reference)
//
#include <hip/hip_runtime.h>
#include <math.h>
#include <stddef.h>

#define L9   9
#define NB   2
#define CF   1024
#define HW   400     // 20*20
#define CH   256
#define TEMPF 20.0f
#define EPSF  1e-12f

typedef _Float16 half8 __attribute__((ext_vector_type(8)));
typedef float f32x4 __attribute__((ext_vector_type(4)));
typedef unsigned short ushort_t;

// ---------------------------------------------------------------------------
// Kernel 1 (v2): sums of squares over C, vectorized float4 along ij.
// ---------------------------------------------------------------------------
__global__ __launch_bounds__(256) void norm_partial2(const float* __restrict__ fq,
                                                     const float* __restrict__ fs,
                                                     float* __restrict__ partial2) {
    int chunk = blockIdx.x, lb = blockIdx.y, t = blockIdx.z;
    int tid = threadIdx.x;
    if (tid >= 200) return;
    int half = tid / 100, p4 = tid - half * 100;
    const float* src = (t == 0 ? fq : fs) + (size_t)lb * CF * HW + p4 * 4;
    int c0 = chunk * 64 + half;
    f32x4 acc = {};
    #pragma unroll 8
    for (int it = 0; it < 32; ++it) {
        const float4 v = *(const float4*)(src + (size_t)(c0 + it * 2) * HW);
        acc[0] = fmaf(v.x, v.x, acc[0]);
        acc[1] = fmaf(v.y, v.y, acc[1]);
        acc[2] = fmaf(v.z, v.z, acc[2]);
        acc[3] = fmaf(v.w, v.w, acc[3]);
    }
    float* dst = partial2 + ((size_t)((t * 18 + lb) * 32) + chunk * 2 + half) * HW + p4 * 4;
    *(f32x4*)dst = acc;
}

// ---------------------------------------------------------------------------
// Kernel 2 (v2): finalize inverse norms (sum 32 subs).
// ---------------------------------------------------------------------------
__global__ __launch_bounds__(256) void norm_finalize2(const float* __restrict__ partial2,
                                                      float* __restrict__ invn) {
    int idx = blockIdx.x * 256 + threadIdx.x;
    if (idx >= 2 * 18 * HW) return;
    int t_lb = idx / HW;
    int ij = idx - t_lb * HW;
    const float* p = partial2 + (size_t)t_lb * 32 * HW + ij;
    float ss = 0.f;
    #pragma unroll
    for (int c = 0; c < 32; ++c) ss += p[c * HW];
    invn[idx] = 1.0f / fmaxf(sqrtf(ss), EPSF);
}

// ---------------------------------------------------------------------------
// Kernel 3a: transpose+convert: fq[lb][c][ij] -> At[li][ij][c] fp16 (ditto fs->Bt)
// ---------------------------------------------------------------------------
__global__ __launch_bounds__(256) void transpose_f16(const float* __restrict__ fq,
                                                     const float* __restrict__ fs,
                                                     ushort_t* __restrict__ At,
                                                     ushort_t* __restrict__ Bt,
                                                     int lb_base) {
    __shared__ float tile[64][65];
    int z = blockIdx.z;
    int tsel = z / 9, li = z - tsel * 9;
    int lb = lb_base + li;
    const float* src = (tsel ? fs : fq) + (size_t)lb * CF * HW;
    ushort_t* dst = (tsel ? Bt : At) + (size_t)li * HW * CF;
    int c0 = blockIdx.x * 64, ij0 = blockIdx.y * 64;
    int tid = threadIdx.x;
    int cl = tid >> 6;
    int col = tid & 63;
    #pragma unroll
    for (int rr = 0; rr < 16; ++rr) {
        int c_local = rr * 4 + cl;
        int ij = ij0 + col;
        tile[c_local][col] = (ij < HW) ? src[(size_t)(c0 + c_local) * HW + ij] : 0.f;
    }
    __syncthreads();
    int cp = (tid & 31) * 2;
    int rowsel = tid >> 5;
    #pragma unroll
    for (int rr = 0; rr < 8; ++rr) {
        int ij_local = rr * 8 + rowsel;
        int ij = ij0 + ij_local;
        if (ij < HW) {
            union { _Float16 h; ushort_t u; } h0, h1;
            h0.h = (_Float16)tile[cp][ij_local];
            h1.h = (_Float16)tile[cp + 1][ij_local];
            ushort2 o; o.x = h0.u; o.y = h1.u;
            *(ushort2*)(dst + (size_t)ij * CF + c0 + cp) = o;
        }
    }
}

// ---------------------------------------------------------------------------
// Kernel 3b: MFMA fp16 correlation GEMM -> f16 corr output (feeds convs only).
// ---------------------------------------------------------------------------
__global__ __launch_bounds__(256) void corr_gemm_mfma(const ushort_t* __restrict__ At,
                                                      const ushort_t* __restrict__ Bt,
                                                      const float* __restrict__ invn,
                                                      ushort_t* __restrict__ corr,
                                                      int lb_base) {
    __shared__ ushort_t As[64][72];
    __shared__ ushort_t Bs[64][72];
    int li = blockIdx.z, lb = lb_base + li;
    int l = lb >> 1, b = lb & 1;
    int i0 = blockIdx.y * 64, j0 = blockIdx.x * 64;
    int tid = threadIdx.x, lane = tid & 63, w = tid >> 6;
    int mw = (w >> 1) * 32, nw = (w & 1) * 32;
    f32x4 acc[2][2] = {};
    const ushort_t* Abase = At + (size_t)li * HW * CF;
    const ushort_t* Bbase = Bt + (size_t)li * HW * CF;

    for (int kt = 0; kt < 16; ++kt) {
        int c0 = kt * 64;
        __syncthreads();
        #pragma unroll
        for (int p = 0; p < 2; ++p) {
            int idx = tid + p * 256;
            int row = idx >> 3, c8 = idx & 7;
            uint4 va = make_uint4(0, 0, 0, 0), vb = make_uint4(0, 0, 0, 0);
            if (i0 + row < HW) va = *(const uint4*)(Abase + (size_t)(i0 + row) * CF + c0 + c8 * 8);
            if (j0 + row < HW) vb = *(const uint4*)(Bbase + (size_t)(j0 + row) * CF + c0 + c8 * 8);
            *(uint4*)&As[row][c8 * 8] = va;
            *(uint4*)&Bs[row][c8 * 8] = vb;
        }
        __syncthreads();
        #pragma unroll
        for (int ks = 0; ks < 2; ++ks) {
            int k0 = ks * 32 + (lane >> 4) * 8;
            half8 a0 = *(const half8*)&As[mw + (lane & 15)][k0];
            half8 a1 = *(const half8*)&As[mw + 16 + (lane & 15)][k0];
            half8 b0 = *(const half8*)&Bs[nw + (lane & 15)][k0];
            half8 b1 = *(const half8*)&Bs[nw + 16 + (lane & 15)][k0];
            acc[0][0] = __builtin_amdgcn_mfma_f32_16x16x32_f16(a0, b0, acc[0][0], 0, 0, 0);
            acc[0][1] = __builtin_amdgcn_mfma_f32_16x16x32_f16(a0, b1, acc[0][1], 0, 0, 0);
            acc[1][0] = __builtin_amdgcn_mfma_f32_16x16x32_f16(a1, b0, acc[1][0], 0, 0, 0);
            acc[1][1] = __builtin_amdgcn_mfma_f32_16x16x32_f16(a1, b1, acc[1][1], 0, 0, 0);
        }
    }
    int obase = (b * 9 + l) * HW;
    #pragma unroll
    for (int mi = 0; mi < 2; ++mi) {
        #pragma unroll
        for (int ni = 0; ni < 2; ++ni) {
            #pragma unroll
            for (int r = 0; r < 4; ++r) {
                int ij = i0 + mw + mi * 16 + (lane >> 4) * 4 + r;
                int km = j0 + nw + ni * 16 + (lane & 15);
                if (ij < HW && km < HW) {
                    union { _Float16 h; ushort_t u; } cv;
                    cv.h = (_Float16)(acc[mi][ni][r] * invn[lb * HW + ij] * invn[7200 + lb * HW + km]);
                    corr[(size_t)(obase + ij) * HW + km] = cv.u;
                }
            }
        }
    }
}

// ---------------------------------------------------------------------------
// Kernel W (v7): weight prep — dense-K B-fragment tables, fp16.
// ---------------------------------------------------------------------------
template <int CIN, int COUT, bool SWAP>
__global__ __launch_bounds__(256) void wprep7(const float* __restrict__ wt,
                                              ushort_t* __restrict__ wb) {
    constexpr int S = CIN * 9;
    constexpr int NCH = (S + 31) / 32;
    int idx = blockIdx.x * 256 + threadIdx.x;
    int total = NCH * 4608;
    if (idx >= total) return;
    int k = idx & 31, n = (idx >> 5) & 15, dd = (idx >> 9) % 9, ch = idx / 4608;
    int slot = ch * 32 + k;
    float v = 0.f;
    if (n < COUT && slot < S) {
        int ci = slot / 9, pl = slot - ci * 9;
        int di = pl / 3, dj = pl % 3, dk = dd / 3, dm = dd % 3;
        int widx = SWAP ? ((((n * CIN + ci) * 3 + dk) * 3 + dm) * 3 + di) * 3 + dj
                        : ((((n * CIN + ci) * 3 + di) * 3 + dj) * 3 + dk) * 3 + dm;
        v = wt[widx];
    }
    union { _Float16 h; ushort_t u; } cv; cv.h = (_Float16)v;
    wb[idx] = cv.u;
}

// ---------------------------------------------------------------------------
// Kernel 4 (v12): 4D conv + ReLU, MFMA implicit GEMM, f16 — PIPELINED.
// v11 with the STAGE addressing bug fixed: the macro previously computed
// (HSEL)*32 while call sites also passed ((ch+1)&1)*32 -> half-1 staging
// landed at +1024 halfs (14 rows off) leaving half 1 uninitialized (NaN).
// Now HSEL is the literal half-element offset (0 or 32).
// Structure: double-buffered A-tile in ONE row, pitch 72 halfs = two
// 32-slot halves + 8 pad. Per chunk: pf-load(ch+1) -> compute(half ch&1)
// -> pack+write(half (ch+1)&1) -> ONE barrier. No barrier between compute
// and stage, so the scheduler interleaves them; prefetch loads hide under
// compute. Pitch 72 (9 odd 16B-slots) walks all 8 bank-groups across rows.
// Zero-init only the 84 halo rows.
// ---------------------------------------------------------------------------
template <int CIN, int COUT, bool DUAL, bool OUTF16>
__global__ __launch_bounds__(256) void conv4d_v12(const ushort_t* __restrict__ inA,
                                                  const ushort_t* __restrict__ inB,
                                                  const ushort_t* __restrict__ wbA,
                                                  const ushort_t* __restrict__ wbB,
                                                  void* __restrict__ outA,
                                                  void* __restrict__ outB) {
    constexpr int S = CIN * 9;
    constexpr int NCH = (S + 31) / 32;
    __shared__ __align__(16) ushort_t Ah[484 * 72];
    const int b = blockIdx.y, ij = blockIdx.x;
    const int z = blockIdx.z;
    const ushort_t* in = (DUAL || z == 0) ? inA : inB;
    const ushort_t* wbS = (DUAL || z == 0) ? wbA : wbB;
    void* outS = (DUAL || z == 0) ? outA : outB;
    const int i = ij / 20, j = ij - (ij / 20) * 20;
    const int tid = threadIdx.x, wv = tid >> 6, lane = tid & 63;
    const int m16 = lane & 15, q4 = lane >> 4;

    // zero only the 84 halo rows (both halves + pad = 36 uints/row)
    for (int h = tid; h < 84 * 36; h += 256) {
        int rs = h / 36, c = h - rs * 36;
        int row = rs < 22 ? rs
                : rs < 44 ? 440 + rs
                : rs < 64 ? (rs - 43) * 22
                          : (rs - 63) * 22 + 21;
        ((uint*)Ah)[row * 36 + c] = 0;
    }

    // linear v8 tile map
    int baseh[7];
    #pragma unroll
    for (int s = 0; s < 7; ++s) {
        int t = wv + 4 * s;
        if (t < 25) {
            int km = t * 16 + m16;
            int kk = km / 20, mm = km - kk * 20;
            baseh[s] = (kk * 22 + mm) * 72 + q4 * 8;
        } else baseh[s] = 0;
    }
    f32x4 accA[7] = {};
    f32x4 accB[7] = {};

    const bool stager = tid < 200;
    const int km1 = 2 * tid;
    const int r1 = stager ? ((km1 / 20 + 1) * 22 + (km1 % 20) + 1) : 0;
    int hofs[9]; bool vld[9];
    #pragma unroll
    for (int pl = 0; pl < 9; ++pl) {
        int ii = i + pl / 3 - 1, jj = j + pl % 3 - 1;
        vld[pl] = (unsigned)ii < 20u && (unsigned)jj < 20u;
        hofs[pl] = (ii * 20 + jj) * HW + km1;
    }
    const ushort_t* in_b = in + (size_t)b * CIN * HW * HW;
    const int wbase = m16 * 32 + q4 * 8;

    uint pf[32];

#define PFLOAD(CHV)                                                            \
    do {                                                                       \
        _Pragma("unroll")                                                      \
        for (int u = 0; u < 32; ++u) {                                         \
            int slot = (CHV) * 32 + u;                                         \
            if (slot < S) {                                                    \
                int ci = slot / 9, pl = slot - ci * 9;                         \
                pf[u] = (stager && vld[pl])                                    \
                        ? *(const uint*)(in_b + ci * (HW * HW) + hofs[pl])     \
                        : 0u;                                                  \
            } else pf[u] = 0u;                                                 \
        }                                                                      \
    } while (0)

// HSEL is the half-element offset within a row: 0 or 32.
#define STAGE(HSEL)                                                            \
    do {                                                                       \
        if (stager) {                                                          \
            _Pragma("unroll")                                                  \
            for (int g8 = 0; g8 < 4; ++g8) {                                   \
                uint4 wlo, whi;                                                \
                wlo.x = (pf[8 * g8 + 0] & 0xFFFFu) | (pf[8 * g8 + 1] << 16);   \
                wlo.y = (pf[8 * g8 + 2] & 0xFFFFu) | (pf[8 * g8 + 3] << 16);   \
                wlo.z = (pf[8 * g8 + 4] & 0xFFFFu) | (pf[8 * g8 + 5] << 16);   \
                wlo.w = (pf[8 * g8 + 6] & 0xFFFFu) | (pf[8 * g8 + 7] << 16);   \
                whi.x = (pf[8 * g8 + 0] >> 16) | (pf[8 * g8 + 1] & 0xFFFF0000u);\
                whi.y = (pf[8 * g8 + 2] >> 16) | (pf[8 * g8 + 3] & 0xFFFF0000u);\
                whi.z = (pf[8 * g8 + 4] >> 16) | (pf[8 * g8 + 5] & 0xFFFF0000u);\
                whi.w = (pf[8 * g8 + 6] >> 16) | (pf[8 * g8 + 7] & 0xFFFF0000u);\
                *(uint4*)&Ah[(size_t)r1 * 72 + (HSEL) + 8 * g8] = wlo;         \
                *(uint4*)&Ah[(size_t)(r1 + 1) * 72 + (HSEL) + 8 * g8] = whi;   \
            }                                                                  \
        }                                                                      \
    } while (0)

    PFLOAD(0);
    STAGE(0);
    __syncthreads();

    #pragma unroll
    for (int ch = 0; ch < NCH; ++ch) {
        if (ch + 1 < NCH) PFLOAD(ch + 1);
        const int hsel = (ch & 1) * 32;
        #pragma unroll
        for (int dd = 0; dd < 9; ++dd) {
            half8 bfA = *(const half8*)(wbS + (ch * 9 + dd) * 512 + wbase);
            half8 bfB;
            if (DUAL) bfB = *(const half8*)(wbB + (ch * 9 + dd) * 512 + wbase);
            const int doff = ((dd / 3) * 22 + (dd % 3)) * 72 + hsel;
            #pragma unroll
            for (int s = 0; s < 7; ++s) {
                if (wv + 4 * s < 25) {
                    half8 af = *(const half8*)(Ah + baseh[s] + doff);
                    accA[s] = __builtin_amdgcn_mfma_f32_16x16x32_f16(af, bfA, accA[s], 0, 0, 0);
                    if (DUAL) accB[s] = __builtin_amdgcn_mfma_f32_16x16x32_f16(af, bfB, accB[s], 0, 0, 0);
                }
            }
        }
        if (ch + 1 < NCH) {
            STAGE(((ch + 1) & 1) * 32);
            __syncthreads();
        }
    }
#undef PFLOAD
#undef STAGE

    const int co = m16;
    if (co < COUT) {
        #pragma unroll
        for (int s = 0; s < 7; ++s) {
            int t = wv + 4 * s;
            if (t < 25) {
                int km0 = t * 16 + q4 * 4;
                size_t o = ((size_t)(b * COUT + co) * HW + ij) * HW + km0;
                if (OUTF16) {
                    union { ushort_t us[4]; uint2 u2; } pk;
                    #pragma unroll
                    for (int r = 0; r < 4; ++r) {
                        union { _Float16 h; ushort_t u16; } cv;
                        cv.h = (_Float16)fmaxf(accA[s][r], 0.f);
                        pk.us[r] = cv.u16;
                    }
                    *(uint2*)((ushort_t*)outS + o) = pk.u2;
                    if (DUAL) {
                        #pragma unroll
                        for (int r = 0; r < 4; ++r) {
                            union { _Float16 h; ushort_t u16; } cv;
                            cv.h = (_Float16)fmaxf(accB[s][r], 0.f);
                            pk.us[r] = cv.u16;
                        }
                        *(uint2*)((ushort_t*)outB + o) = pk.u2;
                    }
                } else {
                    f32x4 ov;
                    #pragma unroll
                    for (int r = 0; r < 4; ++r) ov[r] = fmaxf(accA[s][r], 0.f);
                    *(f32x4*)((float*)outS + o) = ov;
                }
            }
        }
    }
}

// ---------------------------------------------------------------------------
// Kernel F: f_s -> f16 padded copy fsh[b][c][416] (s >= 400 zero).
// ---------------------------------------------------------------------------
__global__ __launch_bounds__(256) void fs_prep(const float* __restrict__ f_s,
                                               ushort_t* __restrict__ fsh) {
    int idx = blockIdx.x * 256 + threadIdx.x;
    if (idx >= NB * CH * 416) return;
    int s = idx % 416, bc = idx / 416;
    float v = (s < HW) ? f_s[(size_t)bc * HW + s] : 0.f;
    union { _Float16 h; ushort_t u; } cv; cv.h = (_Float16)v;
    fsh[idx] = cv.u;
}

// ---------------------------------------------------------------------------
// Kernel 5 (v3): softmax + attn.V via MFMA, summing the two L3 path outputs.
// ---------------------------------------------------------------------------
__global__ __launch_bounds__(256) void softmax_av_mfma2(const float* __restrict__ c4A,
                                                        const float* __restrict__ c4B,
                                                        const ushort_t* __restrict__ fsh,
                                                        float* __restrict__ att) {
    __shared__ ushort_t P[64 * 424];
    __shared__ float invl[64];
    const int b = blockIdx.z, qb = blockIdx.x * 64;
    const int tid = threadIdx.x, wv = tid >> 6, lane = tid & 63;
    const int m16 = lane & 15, q4 = lane >> 4;
    const int lane16 = lane & 15, rg4 = lane >> 4;

    // ---- phase 1: softmax of this wave's 16 rows, 4 rows at a time ----
    #pragma unroll 1
    for (int rg = 0; rg < 4; ++rg) {
        const int ql = wv * 16 + rg * 4 + rg4;
        int q = qb + ql; if (q > HW - 1) q = HW - 1;
        const float* rowA = c4A + ((size_t)b * HW + q) * HW;
        const float* rowB = c4B + ((size_t)b * HW + q) * HW;
        float4 v4[7];
        #pragma unroll
        for (int k4 = 0; k4 < 6; ++k4) {
            float4 a4 = *(const float4*)(rowA + 64 * k4 + lane16 * 4);
            float4 b4 = *(const float4*)(rowB + 64 * k4 + lane16 * 4);
            v4[k4] = make_float4(a4.x + b4.x, a4.y + b4.y, a4.z + b4.z, a4.w + b4.w);
        }
        if (lane16 < 4) {
            float4 a4 = *(const float4*)(rowA + 384 + lane16 * 4);
            float4 b4 = *(const float4*)(rowB + 384 + lane16 * 4);
            v4[6] = make_float4(a4.x + b4.x, a4.y + b4.y, a4.z + b4.z, a4.w + b4.w);
        } else {
            v4[6] = make_float4(-1e30f, -1e30f, -1e30f, -1e30f);
        }
        float mx = -1e30f;
        #pragma unroll
        for (int k4 = 0; k4 < 7; ++k4)
            mx = fmaxf(mx, fmaxf(fmaxf(v4[k4].x, v4[k4].y), fmaxf(v4[k4].z, v4[k4].w)));
        #pragma unroll
        for (int off = 8; off; off >>= 1) mx = fmaxf(mx, __shfl_xor(mx, off, 16));
        float sum = 0.f;
        #pragma unroll
        for (int k4 = 0; k4 < 7; ++k4) {
            if (k4 == 6 && lane16 >= 4) break;
            float e0 = __expf(TEMPF * (v4[k4].x - mx));
            float e1 = __expf(TEMPF * (v4[k4].y - mx));
            float e2 = __expf(TEMPF * (v4[k4].z - mx));
            float e3 = __expf(TEMPF * (v4[k4].w - mx));
            sum += e0 + e1 + e2 + e3;
            union { ushort_t us[4]; uint2 u2; } pk;
            union { _Float16 h; ushort_t u16; } cv;
            cv.h = (_Float16)e0; pk.us[0] = cv.u16;
            cv.h = (_Float16)e1; pk.us[1] = cv.u16;
            cv.h = (_Float16)e2; pk.us[2] = cv.u16;
            cv.h = (_Float16)e3; pk.us[3] = cv.u16;
            *(uint2*)&P[(size_t)ql * 424 + 64 * k4 + lane16 * 4] = pk.u2;
        }
        if (lane16 >= 4 && lane16 < 10) {
            uint2 z2; z2.x = 0; z2.y = 0;
            *(uint2*)&P[(size_t)ql * 424 + 384 + lane16 * 4] = z2;
        }
        #pragma unroll
        for (int off = 8; off; off >>= 1) sum += __shfl_xor(sum, off, 16);
        if (lane16 == 0) invl[ql] = 1.0f / sum;
    }

    // ---- phase 2: AV GEMM for this wave's 16 rows x 2 nt tiles ----
    half8 afr[13];
    #pragma unroll
    for (int ks = 0; ks < 13; ++ks)
        afr[ks] = *(const half8*)&P[(size_t)(wv * 16 + m16) * 424 + ks * 32 + q4 * 8];
    const ushort_t* fb = fsh + (size_t)b * CH * 416;
    #pragma unroll
    for (int ntl = 0; ntl < 2; ++ntl) {
        const int nt = blockIdx.y * 2 + ntl;
        const int c = nt * 16 + m16;
        const ushort_t* fc = fb + (size_t)c * 416 + q4 * 8;
        f32x4 acc = {};
        #pragma unroll
        for (int ks = 0; ks < 13; ++ks) {
            half8 bf = *(const half8*)(fc + ks * 32);
            acc = __builtin_amdgcn_mfma_f32_16x16x32_f16(afr[ks], bf, acc, 0, 0, 0);
        }
        #pragma unroll
        for (int r = 0; r < 4; ++r) {
            int ql = wv * 16 + q4 * 4 + r;
            int q = qb + ql;
            if (q < HW)
                att[((size_t)b * CH + c) * HW + q] = acc[r] * invl[ql];
        }
    }
}

// ---------------------------------------------------------------------------
// Kernel 6: fq = l2norm(f_q, ch) + 0.5 * l2norm(att_fq, ch)
// ---------------------------------------------------------------------------
__global__ __launch_bounds__(256) void final_fq(const float* __restrict__ f_q,
                                                const float* __restrict__ att,
                                                float* __restrict__ out_fq) {
    __shared__ float red[256];
    int b = blockIdx.y, q = blockIdx.x;
    int tid = threadIdx.x;
    size_t idx = (size_t)(b * CH + tid) * HW + q;
    float f = f_q[idx];
    float a = att[idx];
    red[tid] = f * f;
    __syncthreads();
    for (int s = 128; s > 0; s >>= 1) {
        if (tid < s) red[tid] += red[tid + s];
        __syncthreads();
    }
    float invf = 1.0f / fmaxf(sqrtf(red[0]), EPSF);
    __syncthreads();
    red[tid] = a * a;
    __syncthreads();
    for (int s = 128; s > 0; s >>= 1) {
        if (tid < s) red[tid] += red[tid + s];
        __syncthreads();
    }
    float inva = 1.0f / fmaxf(sqrtf(red[0]), EPSF);
    out_fq[idx] = f * invf + 0.5f * a * inva;
}

// ---------------------------------------------------------------------------
extern "C" void kernel_launch(void* const* d_in, const int* in_sizes, int n_in,
                              void* d_out, int out_size, void* d_ws, size_t ws_size,
                              hipStream_t stream) {
    const float* fq_feats = (const float*)d_in[0];
    const float* fs_feats = (const float*)d_in[1];
    const float* f_q      = (const float*)d_in[2];
    const float* f_s      = (const float*)d_in[3];
    const float* w1       = (const float*)d_in[4];
    const float* w2       = (const float*)d_in[5];
    const float* w3       = (const float*)d_in[6];
    float* out = (float*)d_out;              // fq at 0, att_fq at 204800

    float* ws      = (float*)d_ws;
    float* wbuf    = ws;                     // 115,200 fl: weight tables
    float* invn    = wbuf + 115200;          // 14,400
    float* corr    = invn + 14400;           // 2,880,000 fl region:
                                             //   [0 .. 1.44M) corr f16
                                             //   [1.44M .. 1.55M) fsh f16
                                             //   [1.60M .. 1.92M) c4A f32
                                             //   [1.92M .. 2.24M) c4B f32
    float* buf1    = corr + 2880000;         // 3,200,000 (partial2 / At / b1A+b1B)
    float* buf2    = buf1 + 3200000;         // 3,200,000 (Bt / b2A+b2B)
    float* att     = out + 204800;

    float* partial2 = buf1;
    ushort_t* corr_h = (ushort_t*)corr;
    ushort_t* fsh    = (ushort_t*)(corr + 1440000);
    float* c4A = corr + 1600000;
    float* c4B = corr + 1920000;
    ushort_t* At = (ushort_t*)buf1;
    ushort_t* Bt = (ushort_t*)buf2;
    ushort_t* b1A = (ushort_t*)buf1;
    ushort_t* b1B = b1A + 3200000;
    ushort_t* b2A = (ushort_t*)buf2;
    ushort_t* b2B = b2A + 3200000;

    ushort_t* wb0   = (ushort_t*)wbuf;
    ushort_t* wbL1A = wb0;
    ushort_t* wbL1B = wb0 + 13824;
    ushort_t* wbL2A = wb0 + 27648;
    ushort_t* wbL2B = wb0 + 41472;
    ushort_t* wbL3A = wb0 + 55296;
    ushort_t* wbL3B = wb0 + 69120;

    norm_partial2<<<dim3(16, 18, 2), 256, 0, stream>>>(fq_feats, fs_feats, partial2);
    norm_finalize2<<<(2 * 18 * HW + 255) / 256, 256, 0, stream>>>(partial2, invn);

    wprep7<9, 10, false><<<54, 256, 0, stream>>>(w1, wbL1A);
    wprep7<9, 10, true ><<<54, 256, 0, stream>>>(w1, wbL1B);
    wprep7<10, 10, false><<<54, 256, 0, stream>>>(w2, wbL2A);
    wprep7<10, 10, true ><<<54, 256, 0, stream>>>(w2, wbL2B);
    wprep7<10, 1, false><<<54, 256, 0, stream>>>(w3, wbL3A);
    wprep7<10, 1, true ><<<54, 256, 0, stream>>>(w3, wbL3B);
    fs_prep<<<(NB * CH * 416 + 255) / 256, 256, 0, stream>>>(f_s, fsh);

    for (int half = 0; half < 2; ++half) {
        int base = half * 9;
        transpose_f16<<<dim3(16, 7, 18), 256, 0, stream>>>(fq_feats, fs_feats, At, Bt, base);
        corr_gemm_mfma<<<dim3(7, 7, 9), 256, 0, stream>>>(At, Bt, invn, corr_h, base);
    }

    // L1: both paths, one staging (DUAL), 800 blocks x 256 threads
    conv4d_v12<9, 10, true, true><<<dim3(400, NB, 1), 256, 0, stream>>>(
        corr_h, corr_h, wbL1A, wbL1B, b1A, b1B);
    // L2: paths merged via grid-z, 1600 blocks x 256 threads
    conv4d_v12<10, 10, false, true><<<dim3(400, NB, 2), 256, 0, stream>>>(
        b1A, b1B, wbL2A, wbL2B, b2A, b2B);
    // L3: paths merged via grid-z, disjoint f32 outputs, 1600 blocks x 256 threads
    conv4d_v12<10, 1, false, false><<<dim3(400, NB, 2), 256, 0, stream>>>(
        b2A, b2B, wbL3A, wbL3B, c4A, c4B);

    softmax_av_mfma2<<<dim3(7, 8, NB), 256, 0, stream>>>(c4A, c4B, fsh, att);
    final_fq<<<dim3(400, NB), 256, 0, stream>>>(f_q, att, out);

    (void)in_sizes; (void)n_in; (void)out_size; (void)ws_size;
}

// Round 5
// 364.350 us; speedup vs baseline: 1.0575x; 1.0575x over previous
//
#include <hip/hip_runtime.h>
#include <math.h>
#include <stddef.h>

#define L9   9
#define NB   2
#define CF   1024
#define HW   400     // 20*20
#define CH   256
#define TEMPF 20.0f
#define EPSF  1e-12f

typedef _Float16 half8 __attribute__((ext_vector_type(8)));
typedef float f32x4 __attribute__((ext_vector_type(4)));
typedef unsigned short ushort_t;

// ---------------------------------------------------------------------------
// Kernel 1 (v2): sums of squares over C, vectorized float4 along ij.
// ---------------------------------------------------------------------------
__global__ __launch_bounds__(256) void norm_partial2(const float* __restrict__ fq,
                                                     const float* __restrict__ fs,
                                                     float* __restrict__ partial2) {
    int chunk = blockIdx.x, lb = blockIdx.y, t = blockIdx.z;
    int tid = threadIdx.x;
    if (tid >= 200) return;
    int half = tid / 100, p4 = tid - half * 100;
    const float* src = (t == 0 ? fq : fs) + (size_t)lb * CF * HW + p4 * 4;
    int c0 = chunk * 64 + half;
    f32x4 acc = {};
    #pragma unroll 8
    for (int it = 0; it < 32; ++it) {
        const float4 v = *(const float4*)(src + (size_t)(c0 + it * 2) * HW);
        acc[0] = fmaf(v.x, v.x, acc[0]);
        acc[1] = fmaf(v.y, v.y, acc[1]);
        acc[2] = fmaf(v.z, v.z, acc[2]);
        acc[3] = fmaf(v.w, v.w, acc[3]);
    }
    float* dst = partial2 + ((size_t)((t * 18 + lb) * 32) + chunk * 2 + half) * HW + p4 * 4;
    *(f32x4*)dst = acc;
}

// ---------------------------------------------------------------------------
// Kernel 2 (v2): finalize inverse norms (sum 32 subs).
// ---------------------------------------------------------------------------
__global__ __launch_bounds__(256) void norm_finalize2(const float* __restrict__ partial2,
                                                      float* __restrict__ invn) {
    int idx = blockIdx.x * 256 + threadIdx.x;
    if (idx >= 2 * 18 * HW) return;
    int t_lb = idx / HW;
    int ij = idx - t_lb * HW;
    const float* p = partial2 + (size_t)t_lb * 32 * HW + ij;
    float ss = 0.f;
    #pragma unroll
    for (int c = 0; c < 32; ++c) ss += p[c * HW];
    invn[idx] = 1.0f / fmaxf(sqrtf(ss), EPSF);
}

// ---------------------------------------------------------------------------
// Kernel 3a: transpose+convert: fq[lb][c][ij] -> At[li][ij][c] fp16 (ditto fs->Bt)
// ---------------------------------------------------------------------------
__global__ __launch_bounds__(256) void transpose_f16(const float* __restrict__ fq,
                                                     const float* __restrict__ fs,
                                                     ushort_t* __restrict__ At,
                                                     ushort_t* __restrict__ Bt,
                                                     int lb_base) {
    __shared__ float tile[64][65];
    int z = blockIdx.z;
    int tsel = z / 9, li = z - tsel * 9;
    int lb = lb_base + li;
    const float* src = (tsel ? fs : fq) + (size_t)lb * CF * HW;
    ushort_t* dst = (tsel ? Bt : At) + (size_t)li * HW * CF;
    int c0 = blockIdx.x * 64, ij0 = blockIdx.y * 64;
    int tid = threadIdx.x;
    int cl = tid >> 6;
    int col = tid & 63;
    #pragma unroll
    for (int rr = 0; rr < 16; ++rr) {
        int c_local = rr * 4 + cl;
        int ij = ij0 + col;
        tile[c_local][col] = (ij < HW) ? src[(size_t)(c0 + c_local) * HW + ij] : 0.f;
    }
    __syncthreads();
    int cp = (tid & 31) * 2;
    int rowsel = tid >> 5;
    #pragma unroll
    for (int rr = 0; rr < 8; ++rr) {
        int ij_local = rr * 8 + rowsel;
        int ij = ij0 + ij_local;
        if (ij < HW) {
            union { _Float16 h; ushort_t u; } h0, h1;
            h0.h = (_Float16)tile[cp][ij_local];
            h1.h = (_Float16)tile[cp + 1][ij_local];
            ushort2 o; o.x = h0.u; o.y = h1.u;
            *(ushort2*)(dst + (size_t)ij * CF + c0 + cp) = o;
        }
    }
}

// ---------------------------------------------------------------------------
// Kernel 3b: MFMA fp16 correlation GEMM -> f16 corr output (feeds convs only).
// ---------------------------------------------------------------------------
__global__ __launch_bounds__(256) void corr_gemm_mfma(const ushort_t* __restrict__ At,
                                                      const ushort_t* __restrict__ Bt,
                                                      const float* __restrict__ invn,
                                                      ushort_t* __restrict__ corr,
                                                      int lb_base) {
    __shared__ ushort_t As[64][72];
    __shared__ ushort_t Bs[64][72];
    int li = blockIdx.z, lb = lb_base + li;
    int l = lb >> 1, b = lb & 1;
    int i0 = blockIdx.y * 64, j0 = blockIdx.x * 64;
    int tid = threadIdx.x, lane = tid & 63, w = tid >> 6;
    int mw = (w >> 1) * 32, nw = (w & 1) * 32;
    f32x4 acc[2][2] = {};
    const ushort_t* Abase = At + (size_t)li * HW * CF;
    const ushort_t* Bbase = Bt + (size_t)li * HW * CF;

    for (int kt = 0; kt < 16; ++kt) {
        int c0 = kt * 64;
        __syncthreads();
        #pragma unroll
        for (int p = 0; p < 2; ++p) {
            int idx = tid + p * 256;
            int row = idx >> 3, c8 = idx & 7;
            uint4 va = make_uint4(0, 0, 0, 0), vb = make_uint4(0, 0, 0, 0);
            if (i0 + row < HW) va = *(const uint4*)(Abase + (size_t)(i0 + row) * CF + c0 + c8 * 8);
            if (j0 + row < HW) vb = *(const uint4*)(Bbase + (size_t)(j0 + row) * CF + c0 + c8 * 8);
            *(uint4*)&As[row][c8 * 8] = va;
            *(uint4*)&Bs[row][c8 * 8] = vb;
        }
        __syncthreads();
        #pragma unroll
        for (int ks = 0; ks < 2; ++ks) {
            int k0 = ks * 32 + (lane >> 4) * 8;
            half8 a0 = *(const half8*)&As[mw + (lane & 15)][k0];
            half8 a1 = *(const half8*)&As[mw + 16 + (lane & 15)][k0];
            half8 b0 = *(const half8*)&Bs[nw + (lane & 15)][k0];
            half8 b1 = *(const half8*)&Bs[nw + 16 + (lane & 15)][k0];
            acc[0][0] = __builtin_amdgcn_mfma_f32_16x16x32_f16(a0, b0, acc[0][0], 0, 0, 0);
            acc[0][1] = __builtin_amdgcn_mfma_f32_16x16x32_f16(a0, b1, acc[0][1], 0, 0, 0);
            acc[1][0] = __builtin_amdgcn_mfma_f32_16x16x32_f16(a1, b0, acc[1][0], 0, 0, 0);
            acc[1][1] = __builtin_amdgcn_mfma_f32_16x16x32_f16(a1, b1, acc[1][1], 0, 0, 0);
        }
    }
    int obase = (b * 9 + l) * HW;
    #pragma unroll
    for (int mi = 0; mi < 2; ++mi) {
        #pragma unroll
        for (int ni = 0; ni < 2; ++ni) {
            #pragma unroll
            for (int r = 0; r < 4; ++r) {
                int ij = i0 + mw + mi * 16 + (lane >> 4) * 4 + r;
                int km = j0 + nw + ni * 16 + (lane & 15);
                if (ij < HW && km < HW) {
                    union { _Float16 h; ushort_t u; } cv;
                    cv.h = (_Float16)(acc[mi][ni][r] * invn[lb * HW + ij] * invn[7200 + lb * HW + km]);
                    corr[(size_t)(obase + ij) * HW + km] = cv.u;
                }
            }
        }
    }
}

// ---------------------------------------------------------------------------
// Kernel W (v7): weight prep — dense-K B-fragment tables, fp16. (L1, 1-ij)
// ---------------------------------------------------------------------------
template <int CIN, int COUT, bool SWAP>
__global__ __launch_bounds__(256) void wprep7(const float* __restrict__ wt,
                                              ushort_t* __restrict__ wb) {
    constexpr int S = CIN * 9;
    constexpr int NCH = (S + 31) / 32;
    int idx = blockIdx.x * 256 + threadIdx.x;
    int total = NCH * 4608;
    if (idx >= total) return;
    int k = idx & 31, n = (idx >> 5) & 15, dd = (idx >> 9) % 9, ch = idx / 4608;
    int slot = ch * 32 + k;
    float v = 0.f;
    if (n < COUT && slot < S) {
        int ci = slot / 9, pl = slot - ci * 9;
        int di = pl / 3, dj = pl % 3, dk = dd / 3, dm = dd % 3;
        int widx = SWAP ? ((((n * CIN + ci) * 3 + dk) * 3 + dm) * 3 + di) * 3 + dj
                        : ((((n * CIN + ci) * 3 + di) * 3 + dj) * 3 + dk) * 3 + dm;
        v = wt[widx];
    }
    union { _Float16 h; ushort_t u; } cv; cv.h = (_Float16)v;
    wb[idx] = cv.u;
}

// ---------------------------------------------------------------------------
// Kernel W12: weight tables for 2-ij blocks. Slots = ci*12 (di in 0..2,
// dj4 in 0..3 covering the union halo of an ij pair along j).
// MODE 0/1: table for ij offset 0/1 (n = cout, weight dj index e = dj4-MODE).
// MODE 2 (COUT==1, L3): merged-N table — n=0 holds ij0's weights, n=1 ij1's.
// ---------------------------------------------------------------------------
template <int CIN, int COUT, bool SWAP, int MODE>
__global__ __launch_bounds__(256) void wprep12(const float* __restrict__ wt,
                                               ushort_t* __restrict__ wb) {
    constexpr int S2 = CIN * 12;
    constexpr int NCH = (S2 + 31) / 32;
    int idx = blockIdx.x * 256 + threadIdx.x;
    int total = NCH * 4608;
    if (idx >= total) return;
    int k = idx & 31, n = (idx >> 5) & 15, dd = (idx >> 9) % 9, ch = idx / 4608;
    int slot = ch * 32 + k;
    float v = 0.f;
    if (slot < S2) {
        int ci = slot / 12, r = slot - ci * 12;
        int di = r >> 2, dj4 = r & 3;
        int dk = dd / 3, dm = dd % 3;
        int off = (MODE == 2) ? n : MODE;
        int e = dj4 - off;
        int nn = (MODE == 2) ? 0 : n;
        bool ok = (MODE == 2) ? (n < 2) : (n < COUT);
        if (ok && e >= 0 && e <= 2) {
            int widx = SWAP ? ((((nn * CIN + ci) * 3 + dk) * 3 + dm) * 3 + di) * 3 + e
                            : ((((nn * CIN + ci) * 3 + di) * 3 + e) * 3 + dk) * 3 + dm;
            v = wt[widx];
        }
    }
    union { _Float16 h; ushort_t u; } cv; cv.h = (_Float16)v;
    wb[idx] = cv.u;
}

// ---------------------------------------------------------------------------
// Kernel 4a (L1, = R0's verified v8): 4D conv + ReLU, DUAL paths share A.
// ---------------------------------------------------------------------------
template <int CIN, int COUT>
__global__ __launch_bounds__(256) void conv4d_l1(const ushort_t* __restrict__ in,
                                                 const ushort_t* __restrict__ wbA,
                                                 const ushort_t* __restrict__ wbB,
                                                 ushort_t* __restrict__ outA,
                                                 ushort_t* __restrict__ outB) {
    constexpr int S = CIN * 9;
    constexpr int NCH = (S + 31) / 32;
    __shared__ __align__(16) ushort_t Ah[484 * 40];
    const int b = blockIdx.y, ij = blockIdx.x;
    const int i = ij / 20, j = ij - (ij / 20) * 20;
    const int tid = threadIdx.x, wv = tid >> 6, lane = tid & 63;
    const int m16 = lane & 15, q4 = lane >> 4;

    for (int p = tid; p < 484 * 20; p += 256) ((uint*)Ah)[p] = 0;

    int baseh[7];
    #pragma unroll
    for (int s = 0; s < 7; ++s) {
        int t = wv + 4 * s;
        if (t < 25) {
            int km = t * 16 + m16;
            int kk = km / 20, mm = km - kk * 20;
            baseh[s] = (kk * 22 + mm) * 40 + q4 * 8;
        } else baseh[s] = 0;
    }
    f32x4 accA[7] = {};
    f32x4 accB[7] = {};

    const bool stager = tid < 200;
    const int km1 = 2 * tid;
    const int r1 = stager ? ((km1 / 20 + 1) * 22 + (km1 % 20) + 1) : 0;
    int hofs[9]; bool vld[9];
    #pragma unroll
    for (int pl = 0; pl < 9; ++pl) {
        int ii = i + pl / 3 - 1, jj = j + pl % 3 - 1;
        vld[pl] = (unsigned)ii < 20u && (unsigned)jj < 20u;
        hofs[pl] = (ii * 20 + jj) * HW + km1;
    }
    const ushort_t* in_b = in + (size_t)b * CIN * HW * HW;
    const int wbase = m16 * 32 + q4 * 8;

    uint pf[32];
    #pragma unroll
    for (int u = 0; u < 32; ++u) {
        int slot = u;
        if (slot < S) {
            int ci = slot / 9, pl = slot - ci * 9;
            pf[u] = (stager && vld[pl]) ? *(const uint*)(in_b + ci * (HW * HW) + hofs[pl]) : 0u;
        } else pf[u] = 0u;
    }
    __syncthreads();

    #pragma unroll
    for (int ch = 0; ch < NCH; ++ch) {
        if (stager) {
            #pragma unroll
            for (int g4 = 0; g4 < 8; ++g4) {
                uint lo0 = (pf[4 * g4] & 0xFFFFu) | (pf[4 * g4 + 1] << 16);
                uint lo1 = (pf[4 * g4 + 2] & 0xFFFFu) | (pf[4 * g4 + 3] << 16);
                uint hi0 = (pf[4 * g4] >> 16) | (pf[4 * g4 + 1] & 0xFFFF0000u);
                uint hi1 = (pf[4 * g4 + 2] >> 16) | (pf[4 * g4 + 3] & 0xFFFF0000u);
                uint2 wlo; wlo.x = lo0; wlo.y = lo1;
                uint2 whi; whi.x = hi0; whi.y = hi1;
                *(uint2*)&Ah[(size_t)r1 * 40 + 4 * g4] = wlo;
                *(uint2*)&Ah[(size_t)(r1 + 1) * 40 + 4 * g4] = whi;
            }
        }
        __syncthreads();
        if (ch + 1 < NCH) {
            #pragma unroll
            for (int u = 0; u < 32; ++u) {
                int slot = (ch + 1) * 32 + u;
                if (slot < S) {
                    int ci = slot / 9, pl = slot - ci * 9;
                    pf[u] = (stager && vld[pl]) ? *(const uint*)(in_b + ci * (HW * HW) + hofs[pl]) : 0u;
                } else pf[u] = 0u;
            }
        }
        #pragma unroll
        for (int dd = 0; dd < 9; ++dd) {
            half8 bfA = *(const half8*)(wbA + (ch * 9 + dd) * 512 + wbase);
            half8 bfB = *(const half8*)(wbB + (ch * 9 + dd) * 512 + wbase);
            const int doff = ((dd / 3) * 22 + (dd % 3)) * 40;
            #pragma unroll
            for (int s = 0; s < 7; ++s) {
                if (wv + 4 * s < 25) {
                    half8 af = *(const half8*)(Ah + baseh[s] + doff);
                    accA[s] = __builtin_amdgcn_mfma_f32_16x16x32_f16(af, bfA, accA[s], 0, 0, 0);
                    accB[s] = __builtin_amdgcn_mfma_f32_16x16x32_f16(af, bfB, accB[s], 0, 0, 0);
                }
            }
        }
        if (ch + 1 < NCH) __syncthreads();
    }

    const int co = m16;
    if (co < COUT) {
        #pragma unroll
        for (int s = 0; s < 7; ++s) {
            int t = wv + 4 * s;
            if (t < 25) {
                int km0 = t * 16 + q4 * 4;
                size_t o = ((size_t)(b * COUT + co) * HW + ij) * HW + km0;
                union { ushort_t us[4]; uint2 u2; } pk;
                #pragma unroll
                for (int r = 0; r < 4; ++r) {
                    union { _Float16 h; ushort_t u16; } cv;
                    cv.h = (_Float16)fmaxf(accA[s][r], 0.f);
                    pk.us[r] = cv.u16;
                }
                *(uint2*)(outA + o) = pk.u2;
                #pragma unroll
                for (int r = 0; r < 4; ++r) {
                    union { _Float16 h; ushort_t u16; } cv;
                    cv.h = (_Float16)fmaxf(accB[s][r], 0.f);
                    pk.us[r] = cv.u16;
                }
                *(uint2*)(outB + o) = pk.u2;
            }
        }
    }
}

// ---------------------------------------------------------------------------
// Kernel 4b (v13): 2-ij conv + ReLU. One block computes output points
// (i, j0) and (i, j0+1): staged A-data (slots = ci*12 halo union) is SHARED,
// so each A-fragment ds_read feeds 2 MFMAs (per-ij weight tables), or for
// MERGED (COUT==1, L3) ONE MFMA with both ij's weights packed into N
// (n=0 -> ij0, n=1 -> ij1). Per-ij LDS reads drop 189->126; staging loads
// and barrier phases per ij drop 3->2. Same v8 barrier structure & LDS size.
// ---------------------------------------------------------------------------
template <int CIN, int COUT, bool MERGED, bool OUTF16>
__global__ __launch_bounds__(256) void conv4d_2ij(
        const ushort_t* __restrict__ inA, const ushort_t* __restrict__ inB,
        const ushort_t* __restrict__ wA1, const ushort_t* __restrict__ wA2,
        const ushort_t* __restrict__ wB1, const ushort_t* __restrict__ wB2,
        void* __restrict__ outA, void* __restrict__ outB) {
    constexpr int S2 = CIN * 12;
    constexpr int NCH = (S2 + 31) / 32;
    __shared__ __align__(16) ushort_t Ah[484 * 40];
    const int b = blockIdx.y, bx = blockIdx.x, z = blockIdx.z;
    const ushort_t* in = z ? inB : inA;
    const ushort_t* w1 = z ? wB1 : wA1;
    const ushort_t* w2 = z ? wB2 : wA2;
    void* outS = z ? outB : outA;
    const int i = bx / 10, jp = bx - (bx / 10) * 10;
    const int j0 = 2 * jp;
    const int ij0 = i * 20 + j0;
    const int tid = threadIdx.x, wv = tid >> 6, lane = tid & 63;
    const int m16 = lane & 15, q4 = lane >> 4;

    for (int p = tid; p < 484 * 20; p += 256) ((uint*)Ah)[p] = 0;

    int baseh[7];
    #pragma unroll
    for (int s = 0; s < 7; ++s) {
        int t = wv + 4 * s;
        if (t < 25) {
            int km = t * 16 + m16;
            int kk = km / 20, mm = km - kk * 20;
            baseh[s] = (kk * 22 + mm) * 40 + q4 * 8;
        } else baseh[s] = 0;
    }
    f32x4 acc1[7] = {};
    f32x4 acc2[7] = {};

    const bool stager = tid < 200;
    const int km1 = 2 * tid;
    const int r1 = stager ? ((km1 / 20 + 1) * 22 + (km1 % 20) + 1) : 0;
    int hofs[12]; bool vld[12];
    #pragma unroll
    for (int pl = 0; pl < 12; ++pl) {
        int di = pl >> 2, dj = pl & 3;
        int ii = i + di - 1, jj = j0 + dj - 1;
        vld[pl] = (unsigned)ii < 20u && (unsigned)jj < 20u;
        hofs[pl] = (ii * 20 + jj) * HW + km1;
    }
    const ushort_t* in_b = in + (size_t)b * CIN * HW * HW;
    const int wbase = m16 * 32 + q4 * 8;

    uint pf[32];
    #pragma unroll
    for (int u = 0; u < 32; ++u) {
        int slot = u;
        if (slot < S2) {
            int ci = slot / 12, pl = slot - ci * 12;
            pf[u] = (stager && vld[pl]) ? *(const uint*)(in_b + ci * (HW * HW) + hofs[pl]) : 0u;
        } else pf[u] = 0u;
    }
    __syncthreads();

    #pragma unroll
    for (int ch = 0; ch < NCH; ++ch) {
        if (stager) {
            #pragma unroll
            for (int g4 = 0; g4 < 8; ++g4) {
                uint lo0 = (pf[4 * g4] & 0xFFFFu) | (pf[4 * g4 + 1] << 16);
                uint lo1 = (pf[4 * g4 + 2] & 0xFFFFu) | (pf[4 * g4 + 3] << 16);
                uint hi0 = (pf[4 * g4] >> 16) | (pf[4 * g4 + 1] & 0xFFFF0000u);
                uint hi1 = (pf[4 * g4 + 2] >> 16) | (pf[4 * g4 + 3] & 0xFFFF0000u);
                uint2 wlo; wlo.x = lo0; wlo.y = lo1;
                uint2 whi; whi.x = hi0; whi.y = hi1;
                *(uint2*)&Ah[(size_t)r1 * 40 + 4 * g4] = wlo;
                *(uint2*)&Ah[(size_t)(r1 + 1) * 40 + 4 * g4] = whi;
            }
        }
        __syncthreads();
        if (ch + 1 < NCH) {
            #pragma unroll
            for (int u = 0; u < 32; ++u) {
                int slot = (ch + 1) * 32 + u;
                if (slot < S2) {
                    int ci = slot / 12, pl = slot - ci * 12;
                    pf[u] = (stager && vld[pl]) ? *(const uint*)(in_b + ci * (HW * HW) + hofs[pl]) : 0u;
                } else pf[u] = 0u;
            }
        }
        #pragma unroll
        for (int dd = 0; dd < 9; ++dd) {
            half8 bf1 = *(const half8*)(w1 + (ch * 9 + dd) * 512 + wbase);
            half8 bf2;
            if (!MERGED) bf2 = *(const half8*)(w2 + (ch * 9 + dd) * 512 + wbase);
            const int doff = ((dd / 3) * 22 + (dd % 3)) * 40;
            #pragma unroll
            for (int s = 0; s < 7; ++s) {
                if (wv + 4 * s < 25) {
                    half8 af = *(const half8*)(Ah + baseh[s] + doff);
                    acc1[s] = __builtin_amdgcn_mfma_f32_16x16x32_f16(af, bf1, acc1[s], 0, 0, 0);
                    if (!MERGED) acc2[s] = __builtin_amdgcn_mfma_f32_16x16x32_f16(af, bf2, acc2[s], 0, 0, 0);
                }
            }
        }
        if (ch + 1 < NCH) __syncthreads();
    }

    if (MERGED) {
        // n = m16 in {0,1} selects the ij of the pair; COUT == 1.
        if (m16 < 2) {
            const int ij = ij0 + m16;
            #pragma unroll
            for (int s = 0; s < 7; ++s) {
                int t = wv + 4 * s;
                if (t < 25) {
                    int km0 = t * 16 + q4 * 4;
                    size_t o = ((size_t)b * HW + ij) * HW + km0;
                    f32x4 ov;
                    #pragma unroll
                    for (int r = 0; r < 4; ++r) ov[r] = fmaxf(acc1[s][r], 0.f);
                    *(f32x4*)((float*)outS + o) = ov;
                }
            }
        }
    } else {
        const int co = m16;
        if (co < COUT) {
            #pragma unroll
            for (int s = 0; s < 7; ++s) {
                int t = wv + 4 * s;
                if (t < 25) {
                    int km0 = t * 16 + q4 * 4;
                    size_t o = ((size_t)(b * COUT + co) * HW + ij0) * HW + km0;
                    if (OUTF16) {
                        union { ushort_t us[4]; uint2 u2; } pk;
                        #pragma unroll
                        for (int r = 0; r < 4; ++r) {
                            union { _Float16 h; ushort_t u16; } cv;
                            cv.h = (_Float16)fmaxf(acc1[s][r], 0.f);
                            pk.us[r] = cv.u16;
                        }
                        *(uint2*)((ushort_t*)outS + o) = pk.u2;
                        #pragma unroll
                        for (int r = 0; r < 4; ++r) {
                            union { _Float16 h; ushort_t u16; } cv;
                            cv.h = (_Float16)fmaxf(acc2[s][r], 0.f);
                            pk.us[r] = cv.u16;
                        }
                        *(uint2*)((ushort_t*)outS + o + HW) = pk.u2;
                    } else {
                        f32x4 ov;
                        #pragma unroll
                        for (int r = 0; r < 4; ++r) ov[r] = fmaxf(acc1[s][r], 0.f);
                        *(f32x4*)((float*)outS + o) = ov;
                        #pragma unroll
                        for (int r = 0; r < 4; ++r) ov[r] = fmaxf(acc2[s][r], 0.f);
                        *(f32x4*)((float*)outS + o + HW) = ov;
                    }
                }
            }
        }
    }
}

// ---------------------------------------------------------------------------
// Kernel F: f_s -> f16 padded copy fsh[b][c][416] (s >= 400 zero).
// ---------------------------------------------------------------------------
__global__ __launch_bounds__(256) void fs_prep(const float* __restrict__ f_s,
                                               ushort_t* __restrict__ fsh) {
    int idx = blockIdx.x * 256 + threadIdx.x;
    if (idx >= NB * CH * 416) return;
    int s = idx % 416, bc = idx / 416;
    float v = (s < HW) ? f_s[(size_t)bc * HW + s] : 0.f;
    union { _Float16 h; ushort_t u; } cv; cv.h = (_Float16)v;
    fsh[idx] = cv.u;
}

// ---------------------------------------------------------------------------
// Kernel 5 (v3): softmax + attn.V via MFMA, summing the two L3 path outputs.
// ---------------------------------------------------------------------------
__global__ __launch_bounds__(256) void softmax_av_mfma2(const float* __restrict__ c4A,
                                                        const float* __restrict__ c4B,
                                                        const ushort_t* __restrict__ fsh,
                                                        float* __restrict__ att) {
    __shared__ ushort_t P[64 * 424];
    __shared__ float invl[64];
    const int b = blockIdx.z, qb = blockIdx.x * 64;
    const int tid = threadIdx.x, wv = tid >> 6, lane = tid & 63;
    const int m16 = lane & 15, q4 = lane >> 4;
    const int lane16 = lane & 15, rg4 = lane >> 4;

    // ---- phase 1: softmax of this wave's 16 rows, 4 rows at a time ----
    #pragma unroll 1
    for (int rg = 0; rg < 4; ++rg) {
        const int ql = wv * 16 + rg * 4 + rg4;
        int q = qb + ql; if (q > HW - 1) q = HW - 1;
        const float* rowA = c4A + ((size_t)b * HW + q) * HW;
        const float* rowB = c4B + ((size_t)b * HW + q) * HW;
        float4 v4[7];
        #pragma unroll
        for (int k4 = 0; k4 < 6; ++k4) {
            float4 a4 = *(const float4*)(rowA + 64 * k4 + lane16 * 4);
            float4 b4 = *(const float4*)(rowB + 64 * k4 + lane16 * 4);
            v4[k4] = make_float4(a4.x + b4.x, a4.y + b4.y, a4.z + b4.z, a4.w + b4.w);
        }
        if (lane16 < 4) {
            float4 a4 = *(const float4*)(rowA + 384 + lane16 * 4);
            float4 b4 = *(const float4*)(rowB + 384 + lane16 * 4);
            v4[6] = make_float4(a4.x + b4.x, a4.y + b4.y, a4.z + b4.z, a4.w + b4.w);
        } else {
            v4[6] = make_float4(-1e30f, -1e30f, -1e30f, -1e30f);
        }
        float mx = -1e30f;
        #pragma unroll
        for (int k4 = 0; k4 < 7; ++k4)
            mx = fmaxf(mx, fmaxf(fmaxf(v4[k4].x, v4[k4].y), fmaxf(v4[k4].z, v4[k4].w)));
        #pragma unroll
        for (int off = 8; off; off >>= 1) mx = fmaxf(mx, __shfl_xor(mx, off, 16));
        float sum = 0.f;
        #pragma unroll
        for (int k4 = 0; k4 < 7; ++k4) {
            if (k4 == 6 && lane16 >= 4) break;
            float e0 = __expf(TEMPF * (v4[k4].x - mx));
            float e1 = __expf(TEMPF * (v4[k4].y - mx));
            float e2 = __expf(TEMPF * (v4[k4].z - mx));
            float e3 = __expf(TEMPF * (v4[k4].w - mx));
            sum += e0 + e1 + e2 + e3;
            union { ushort_t us[4]; uint2 u2; } pk;
            union { _Float16 h; ushort_t u16; } cv;
            cv.h = (_Float16)e0; pk.us[0] = cv.u16;
            cv.h = (_Float16)e1; pk.us[1] = cv.u16;
            cv.h = (_Float16)e2; pk.us[2] = cv.u16;
            cv.h = (_Float16)e3; pk.us[3] = cv.u16;
            *(uint2*)&P[(size_t)ql * 424 + 64 * k4 + lane16 * 4] = pk.u2;
        }
        if (lane16 >= 4 && lane16 < 10) {
            uint2 z2; z2.x = 0; z2.y = 0;
            *(uint2*)&P[(size_t)ql * 424 + 384 + lane16 * 4] = z2;
        }
        #pragma unroll
        for (int off = 8; off; off >>= 1) sum += __shfl_xor(sum, off, 16);
        if (lane16 == 0) invl[ql] = 1.0f / sum;
    }

    // ---- phase 2: AV GEMM for this wave's 16 rows x 2 nt tiles ----
    half8 afr[13];
    #pragma unroll
    for (int ks = 0; ks < 13; ++ks)
        afr[ks] = *(const half8*)&P[(size_t)(wv * 16 + m16) * 424 + ks * 32 + q4 * 8];
    const ushort_t* fb = fsh + (size_t)b * CH * 416;
    #pragma unroll
    for (int ntl = 0; ntl < 2; ++ntl) {
        const int nt = blockIdx.y * 2 + ntl;
        const int c = nt * 16 + m16;
        const ushort_t* fc = fb + (size_t)c * 416 + q4 * 8;
        f32x4 acc = {};
        #pragma unroll
        for (int ks = 0; ks < 13; ++ks) {
            half8 bf = *(const half8*)(fc + ks * 32);
            acc = __builtin_amdgcn_mfma_f32_16x16x32_f16(afr[ks], bf, acc, 0, 0, 0);
        }
        #pragma unroll
        for (int r = 0; r < 4; ++r) {
            int ql = wv * 16 + q4 * 4 + r;
            int q = qb + ql;
            if (q < HW)
                att[((size_t)b * CH + c) * HW + q] = acc[r] * invl[ql];
        }
    }
}

// ---------------------------------------------------------------------------
// Kernel 6: fq = l2norm(f_q, ch) + 0.5 * l2norm(att_fq, ch)
// ---------------------------------------------------------------------------
__global__ __launch_bounds__(256) void final_fq(const float* __restrict__ f_q,
                                                const float* __restrict__ att,
                                                float* __restrict__ out_fq) {
    __shared__ float red[256];
    int b = blockIdx.y, q = blockIdx.x;
    int tid = threadIdx.x;
    size_t idx = (size_t)(b * CH + tid) * HW + q;
    float f = f_q[idx];
    float a = att[idx];
    red[tid] = f * f;
    __syncthreads();
    for (int s = 128; s > 0; s >>= 1) {
        if (tid < s) red[tid] += red[tid + s];
        __syncthreads();
    }
    float invf = 1.0f / fmaxf(sqrtf(red[0]), EPSF);
    __syncthreads();
    red[tid] = a * a;
    __syncthreads();
    for (int s = 128; s > 0; s >>= 1) {
        if (tid < s) red[tid] += red[tid + s];
        __syncthreads();
    }
    float inva = 1.0f / fmaxf(sqrtf(red[0]), EPSF);
    out_fq[idx] = f * invf + 0.5f * a * inva;
}

// ---------------------------------------------------------------------------
extern "C" void kernel_launch(void* const* d_in, const int* in_sizes, int n_in,
                              void* d_out, int out_size, void* d_ws, size_t ws_size,
                              hipStream_t stream) {
    const float* fq_feats = (const float*)d_in[0];
    const float* fs_feats = (const float*)d_in[1];
    const float* f_q      = (const float*)d_in[2];
    const float* f_s      = (const float*)d_in[3];
    const float* w1       = (const float*)d_in[4];
    const float* w2       = (const float*)d_in[5];
    const float* w3       = (const float*)d_in[6];
    float* out = (float*)d_out;              // fq at 0, att_fq at 204800

    float* ws      = (float*)d_ws;
    float* wbuf    = ws;                     // 115,200 fl: weight tables
    float* invn    = wbuf + 115200;          // 14,400
    float* corr    = invn + 14400;           // 2,880,000 fl region:
                                             //   [0 .. 1.44M) corr f16
                                             //   [1.44M .. 1.55M) fsh f16
                                             //   [1.60M .. 1.92M) c4A f32
                                             //   [1.92M .. 2.24M) c4B f32
    float* buf1    = corr + 2880000;         // 3,200,000 (partial2 / At / b1A+b1B)
    float* buf2    = buf1 + 3200000;         // 3,200,000 (Bt / b2A+b2B)
    float* att     = out + 204800;

    float* partial2 = buf1;
    ushort_t* corr_h = (ushort_t*)corr;
    ushort_t* fsh    = (ushort_t*)(corr + 1440000);
    float* c4A = corr + 1600000;
    float* c4B = corr + 1920000;
    ushort_t* At = (ushort_t*)buf1;
    ushort_t* Bt = (ushort_t*)buf2;
    ushort_t* b1A = (ushort_t*)buf1;
    ushort_t* b1B = b1A + 3200000;
    ushort_t* b2A = (ushort_t*)buf2;
    ushort_t* b2B = b2A + 3200000;

    // weight tables (halfs): L1 (1-ij, 3 chunks) 13824 each;
    // L2/L3 (2-ij, 4 chunks) 18432 each.
    ushort_t* wb0    = (ushort_t*)wbuf;
    ushort_t* wbL1A  = wb0;
    ushort_t* wbL1B  = wb0 + 13824;
    ushort_t* wbL2A0 = wb0 + 27648;
    ushort_t* wbL2A1 = wb0 + 46080;
    ushort_t* wbL2B0 = wb0 + 64512;
    ushort_t* wbL2B1 = wb0 + 82944;
    ushort_t* wbL3Am = wb0 + 101376;
    ushort_t* wbL3Bm = wb0 + 119808;   // end 138240 halfs < 230400

    norm_partial2<<<dim3(16, 18, 2), 256, 0, stream>>>(fq_feats, fs_feats, partial2);
    norm_finalize2<<<(2 * 18 * HW + 255) / 256, 256, 0, stream>>>(partial2, invn);

    wprep7<9, 10, false><<<54, 256, 0, stream>>>(w1, wbL1A);
    wprep7<9, 10, true ><<<54, 256, 0, stream>>>(w1, wbL1B);
    wprep12<10, 10, false, 0><<<72, 256, 0, stream>>>(w2, wbL2A0);
    wprep12<10, 10, false, 1><<<72, 256, 0, stream>>>(w2, wbL2A1);
    wprep12<10, 10, true,  0><<<72, 256, 0, stream>>>(w2, wbL2B0);
    wprep12<10, 10, true,  1><<<72, 256, 0, stream>>>(w2, wbL2B1);
    wprep12<10, 1, false, 2><<<72, 256, 0, stream>>>(w3, wbL3Am);
    wprep12<10, 1, true,  2><<<72, 256, 0, stream>>>(w3, wbL3Bm);
    fs_prep<<<(NB * CH * 416 + 255) / 256, 256, 0, stream>>>(f_s, fsh);

    for (int half = 0; half < 2; ++half) {
        int base = half * 9;
        transpose_f16<<<dim3(16, 7, 18), 256, 0, stream>>>(fq_feats, fs_feats, At, Bt, base);
        corr_gemm_mfma<<<dim3(7, 7, 9), 256, 0, stream>>>(At, Bt, invn, corr_h, base);
    }

    // L1: DUAL paths share A-reads (verified v8 structure), 800 blocks
    conv4d_l1<9, 10><<<dim3(400, NB, 1), 256, 0, stream>>>(
        corr_h, wbL1A, wbL1B, b1A, b1B);
    // L2: 2-ij blocks, per-ij B-tables (2 MFMA per A-read), 800 blocks
    conv4d_2ij<10, 10, false, true><<<dim3(200, NB, 2), 256, 0, stream>>>(
        b1A, b1B, wbL2A0, wbL2A1, wbL2B0, wbL2B1, b2A, b2B);
    // L3: 2-ij blocks, merged-N tables (1 MFMA per A-read computes both ij), f32 out
    conv4d_2ij<10, 1, true, false><<<dim3(200, NB, 2), 256, 0, stream>>>(
        b2A, b2B, wbL3Am, wbL3Am, wbL3Bm, wbL3Bm, c4A, c4B);

    softmax_av_mfma2<<<dim3(7, 8, NB), 256, 0, stream>>>(c4A, c4B, fsh, att);
    final_fq<<<dim3(400, NB), 256, 0, stream>>>(f_q, att, out);

    (void)in_sizes; (void)n_in; (void)out_size; (void)ws_size;
}

// Round 6
// 344.706 us; speedup vs baseline: 1.1178x; 1.0570x over previous
//
#include <hip/hip_runtime.h>
#include <math.h>
#include <stddef.h>

#define L9   9
#define NB   2
#define CF   1024
#define HW   400     // 20*20
#define CH   256
#define TEMPF 20.0f
#define EPSF  1e-12f

typedef _Float16 half8 __attribute__((ext_vector_type(8)));
typedef float f32x4 __attribute__((ext_vector_type(4)));
typedef unsigned short ushort_t;

// ---------------------------------------------------------------------------
// Kernel P (new): ALL prep work in ONE launch (replaces 6 wprep + fs_prep +
// ss zero-init). Each thread does up to 3 independent tiny jobs.
//   gid < 212992 : fs_prep element
//   gid < 14400  : zero ss accumulator (norm fused into transpose now)
//   gid < 110592 : weight-table element, job = gid/18432:
//     0: L1A w7(9,10,F)   1: L1B w7(9,10,T)
//     2: L2A w7(10,10,F)  3: L2B w7(10,10,T)   (13824 each, idx<13824)
//     4: L3Am w12-merged(10,1,F)  5: L3Bm w12-merged(10,1,T) (18432 each)
// ---------------------------------------------------------------------------
__global__ __launch_bounds__(256) void prep_all(const float* __restrict__ w1,
                                                const float* __restrict__ w2,
                                                const float* __restrict__ w3,
                                                const float* __restrict__ f_s,
                                                ushort_t* __restrict__ wb0,
                                                ushort_t* __restrict__ fsh,
                                                float* __restrict__ ssbuf) {
    int gid = blockIdx.x * 256 + threadIdx.x;
    if (gid < NB * CH * 416) {
        int s = gid % 416, bc = gid / 416;
        float v = (s < HW) ? f_s[(size_t)bc * HW + s] : 0.f;
        union { _Float16 h; ushort_t u; } cv; cv.h = (_Float16)v;
        fsh[gid] = cv.u;
    }
    if (gid < 14400) ssbuf[gid] = 0.f;
    if (gid < 6 * 18432) {
        int job = gid / 18432, idx = gid - job * 18432;
        int k = idx & 31, n = (idx >> 5) & 15, dd = (idx >> 9) % 9, ch = idx / 4608;
        int dk = dd / 3, dm = dd % 3;
        float v = 0.f;
        if (job < 4) {
            if (idx < 13824) {
                int CIN = (job < 2) ? 9 : 10;
                const float* wt = (job < 2) ? w1 : w2;
                bool swap = job & 1;
                int slot = ch * 32 + k;
                if (n < 10 && slot < CIN * 9) {
                    int ci = slot / 9, pl = slot - ci * 9;
                    int di = pl / 3, dj = pl % 3;
                    int widx = swap ? ((((n * CIN + ci) * 3 + dk) * 3 + dm) * 3 + di) * 3 + dj
                                    : ((((n * CIN + ci) * 3 + di) * 3 + dj) * 3 + dk) * 3 + dm;
                    v = wt[widx];
                }
                union { _Float16 h; ushort_t u; } cv; cv.h = (_Float16)v;
                wb0[job * 13824 + idx] = cv.u;
            }
        } else {
            bool swap = (job == 5);
            int slot = ch * 32 + k;
            if (slot < 120) {
                int ci = slot / 12, r = slot - ci * 12;
                int di = r >> 2, dj4 = r & 3;
                int e = dj4 - n;
                if (n < 2 && e >= 0 && e <= 2) {
                    int widx = swap ? (((ci * 3 + dk) * 3 + dm) * 3 + di) * 3 + e
                                    : (((ci * 3 + di) * 3 + e) * 3 + dk) * 3 + dm;
                    v = w3[widx];
                }
            }
            union { _Float16 h; ushort_t u; } cv; cv.h = (_Float16)v;
            wb0[55296 + (job - 4) * 18432 + idx] = cv.u;
        }
    }
}

// ---------------------------------------------------------------------------
// Kernel 3a (v2): transpose+convert WITH FUSED NORM PARTIALS.
// While the f32 tile is loaded, each thread accumulates sum-of-squares over
// its 16 c-rows; 4 partials per ij column combine in LDS and one atomicAdd
// per column accumulates ss[tsel*18+lb][ij]. Replaces the norm_partial2
// pass (second full 118MB read of fq/fs) entirely.
// ---------------------------------------------------------------------------
__global__ __launch_bounds__(256) void transpose_f16(const float* __restrict__ fq,
                                                     const float* __restrict__ fs,
                                                     ushort_t* __restrict__ At,
                                                     ushort_t* __restrict__ Bt,
                                                     float* __restrict__ ssbuf,
                                                     int lb_base) {
    __shared__ float tile[64][65];
    __shared__ float red4[4][64];
    int z = blockIdx.z;
    int tsel = z / 9, li = z - tsel * 9;
    int lb = lb_base + li;
    const float* src = (tsel ? fs : fq) + (size_t)lb * CF * HW;
    ushort_t* dst = (tsel ? Bt : At) + (size_t)li * HW * CF;
    int c0 = blockIdx.x * 64, ij0 = blockIdx.y * 64;
    int tid = threadIdx.x;
    int cl = tid >> 6;
    int col = tid & 63;
    float ssp = 0.f;
    #pragma unroll
    for (int rr = 0; rr < 16; ++rr) {
        int c_local = rr * 4 + cl;
        int ij = ij0 + col;
        float v = (ij < HW) ? src[(size_t)(c0 + c_local) * HW + ij] : 0.f;
        tile[c_local][col] = v;
        ssp = fmaf(v, v, ssp);
    }
    red4[cl][col] = ssp;
    __syncthreads();
    if (cl == 0) {
        int ij = ij0 + col;
        if (ij < HW) {
            float s4 = red4[0][col] + red4[1][col] + red4[2][col] + red4[3][col];
            atomicAdd(&ssbuf[(size_t)(tsel * 18 + lb) * HW + ij], s4);
        }
    }
    int cp = (tid & 31) * 2;
    int rowsel = tid >> 5;
    #pragma unroll
    for (int rr = 0; rr < 8; ++rr) {
        int ij_local = rr * 8 + rowsel;
        int ij = ij0 + ij_local;
        if (ij < HW) {
            union { _Float16 h; ushort_t u; } h0, h1;
            h0.h = (_Float16)tile[cp][ij_local];
            h1.h = (_Float16)tile[cp + 1][ij_local];
            ushort2 o; o.x = h0.u; o.y = h1.u;
            *(ushort2*)(dst + (size_t)ij * CF + c0 + cp) = o;
        }
    }
}

// ---------------------------------------------------------------------------
// Kernel 3b: MFMA fp16 correlation GEMM. Epilogue now computes inverse norms
// from the fused ss accumulator (1/max(sqrt(ss),eps)) instead of reading a
// precomputed invn table. Stream order guarantees ss completeness.
// ---------------------------------------------------------------------------
__global__ __launch_bounds__(256) void corr_gemm_mfma(const ushort_t* __restrict__ At,
                                                      const ushort_t* __restrict__ Bt,
                                                      const float* __restrict__ ssbuf,
                                                      ushort_t* __restrict__ corr,
                                                      int lb_base) {
    __shared__ ushort_t As[64][72];
    __shared__ ushort_t Bs[64][72];
    int li = blockIdx.z, lb = lb_base + li;
    int l = lb >> 1, b = lb & 1;
    int i0 = blockIdx.y * 64, j0 = blockIdx.x * 64;
    int tid = threadIdx.x, lane = tid & 63, w = tid >> 6;
    int mw = (w >> 1) * 32, nw = (w & 1) * 32;
    f32x4 acc[2][2] = {};
    const ushort_t* Abase = At + (size_t)li * HW * CF;
    const ushort_t* Bbase = Bt + (size_t)li * HW * CF;

    for (int kt = 0; kt < 16; ++kt) {
        int c0 = kt * 64;
        __syncthreads();
        #pragma unroll
        for (int p = 0; p < 2; ++p) {
            int idx = tid + p * 256;
            int row = idx >> 3, c8 = idx & 7;
            uint4 va = make_uint4(0, 0, 0, 0), vb = make_uint4(0, 0, 0, 0);
            if (i0 + row < HW) va = *(const uint4*)(Abase + (size_t)(i0 + row) * CF + c0 + c8 * 8);
            if (j0 + row < HW) vb = *(const uint4*)(Bbase + (size_t)(j0 + row) * CF + c0 + c8 * 8);
            *(uint4*)&As[row][c8 * 8] = va;
            *(uint4*)&Bs[row][c8 * 8] = vb;
        }
        __syncthreads();
        #pragma unroll
        for (int ks = 0; ks < 2; ++ks) {
            int k0 = ks * 32 + (lane >> 4) * 8;
            half8 a0 = *(const half8*)&As[mw + (lane & 15)][k0];
            half8 a1 = *(const half8*)&As[mw + 16 + (lane & 15)][k0];
            half8 b0 = *(const half8*)&Bs[nw + (lane & 15)][k0];
            half8 b1 = *(const half8*)&Bs[nw + 16 + (lane & 15)][k0];
            acc[0][0] = __builtin_amdgcn_mfma_f32_16x16x32_f16(a0, b0, acc[0][0], 0, 0, 0);
            acc[0][1] = __builtin_amdgcn_mfma_f32_16x16x32_f16(a0, b1, acc[0][1], 0, 0, 0);
            acc[1][0] = __builtin_amdgcn_mfma_f32_16x16x32_f16(a1, b0, acc[1][0], 0, 0, 0);
            acc[1][1] = __builtin_amdgcn_mfma_f32_16x16x32_f16(a1, b1, acc[1][1], 0, 0, 0);
        }
    }
    int obase = (b * 9 + l) * HW;
    #pragma unroll
    for (int ni = 0; ni < 2; ++ni) {
        int km = j0 + nw + ni * 16 + (lane & 15);
        if (km >= HW) continue;
        float ib = 1.0f / fmaxf(sqrtf(ssbuf[(size_t)(18 + lb) * HW + km]), EPSF);
        #pragma unroll
        for (int mi = 0; mi < 2; ++mi) {
            #pragma unroll
            for (int r = 0; r < 4; ++r) {
                int ij = i0 + mw + mi * 16 + (lane >> 4) * 4 + r;
                if (ij < HW) {
                    float ia = 1.0f / fmaxf(sqrtf(ssbuf[(size_t)lb * HW + ij]), EPSF);
                    union { _Float16 h; ushort_t u; } cv;
                    cv.h = (_Float16)(acc[mi][ni][r] * ia * ib);
                    corr[(size_t)(obase + ij) * HW + km] = cv.u;
                }
            }
        }
    }
}

// ---------------------------------------------------------------------------
// Kernel 4 (v8, the best-measured conv structure): 4D conv + ReLU, MFMA
// implicit GEMM, f16. 256 threads, linear km tile map, single-buffered,
// uint2 staging. DUAL shares one staging for both weight tables (L1);
// !DUAL uses grid-z to merge the two conv paths (L2).
// ---------------------------------------------------------------------------
template <int CIN, int COUT, bool DUAL, bool OUTF16>
__global__ __launch_bounds__(256) void conv4d_v8(const ushort_t* __restrict__ inA,
                                                 const ushort_t* __restrict__ inB,
                                                 const ushort_t* __restrict__ wbA,
                                                 const ushort_t* __restrict__ wbB,
                                                 void* __restrict__ outA,
                                                 void* __restrict__ outB) {
    constexpr int S = CIN * 9;
    constexpr int NCH = (S + 31) / 32;
    __shared__ __align__(16) ushort_t Ah[484 * 40];
    const int b = blockIdx.y, ij = blockIdx.x;
    const int z = blockIdx.z;
    const ushort_t* in = (DUAL || z == 0) ? inA : inB;
    const ushort_t* wbS = (DUAL || z == 0) ? wbA : wbB;
    void* outS = (DUAL || z == 0) ? outA : outB;
    const int i = ij / 20, j = ij - (ij / 20) * 20;
    const int tid = threadIdx.x, wv = tid >> 6, lane = tid & 63;
    const int m16 = lane & 15, q4 = lane >> 4;

    for (int p = tid; p < 484 * 20; p += 256) ((uint*)Ah)[p] = 0;

    int baseh[7];
    #pragma unroll
    for (int s = 0; s < 7; ++s) {
        int t = wv + 4 * s;
        if (t < 25) {
            int km = t * 16 + m16;
            int kk = km / 20, mm = km - kk * 20;
            baseh[s] = (kk * 22 + mm) * 40 + q4 * 8;
        } else baseh[s] = 0;
    }
    f32x4 accA[7] = {};
    f32x4 accB[7] = {};

    const bool stager = tid < 200;
    const int km1 = 2 * tid;
    const int r1 = stager ? ((km1 / 20 + 1) * 22 + (km1 % 20) + 1) : 0;
    int hofs[9]; bool vld[9];
    #pragma unroll
    for (int pl = 0; pl < 9; ++pl) {
        int ii = i + pl / 3 - 1, jj = j + pl % 3 - 1;
        vld[pl] = (unsigned)ii < 20u && (unsigned)jj < 20u;
        hofs[pl] = (ii * 20 + jj) * HW + km1;
    }
    const ushort_t* in_b = in + (size_t)b * CIN * HW * HW;
    const int wbase = m16 * 32 + q4 * 8;

    uint pf[32];
    #pragma unroll
    for (int u = 0; u < 32; ++u) {
        int slot = u;
        if (slot < S) {
            int ci = slot / 9, pl = slot - ci * 9;
            pf[u] = (stager && vld[pl]) ? *(const uint*)(in_b + ci * (HW * HW) + hofs[pl]) : 0u;
        } else pf[u] = 0u;
    }
    __syncthreads();

    #pragma unroll
    for (int ch = 0; ch < NCH; ++ch) {
        if (stager) {
            #pragma unroll
            for (int g4 = 0; g4 < 8; ++g4) {
                uint lo0 = (pf[4 * g4] & 0xFFFFu) | (pf[4 * g4 + 1] << 16);
                uint lo1 = (pf[4 * g4 + 2] & 0xFFFFu) | (pf[4 * g4 + 3] << 16);
                uint hi0 = (pf[4 * g4] >> 16) | (pf[4 * g4 + 1] & 0xFFFF0000u);
                uint hi1 = (pf[4 * g4 + 2] >> 16) | (pf[4 * g4 + 3] & 0xFFFF0000u);
                uint2 wlo; wlo.x = lo0; wlo.y = lo1;
                uint2 whi; whi.x = hi0; whi.y = hi1;
                *(uint2*)&Ah[(size_t)r1 * 40 + 4 * g4] = wlo;
                *(uint2*)&Ah[(size_t)(r1 + 1) * 40 + 4 * g4] = whi;
            }
        }
        __syncthreads();
        if (ch + 1 < NCH) {
            #pragma unroll
            for (int u = 0; u < 32; ++u) {
                int slot = (ch + 1) * 32 + u;
                if (slot < S) {
                    int ci = slot / 9, pl = slot - ci * 9;
                    pf[u] = (stager && vld[pl]) ? *(const uint*)(in_b + ci * (HW * HW) + hofs[pl]) : 0u;
                } else pf[u] = 0u;
            }
        }
        #pragma unroll
        for (int dd = 0; dd < 9; ++dd) {
            half8 bfA = *(const half8*)(wbS + (ch * 9 + dd) * 512 + wbase);
            half8 bfB;
            if (DUAL) bfB = *(const half8*)(wbB + (ch * 9 + dd) * 512 + wbase);
            const int doff = ((dd / 3) * 22 + (dd % 3)) * 40;
            #pragma unroll
            for (int s = 0; s < 7; ++s) {
                if (wv + 4 * s < 25) {
                    half8 af = *(const half8*)(Ah + baseh[s] + doff);
                    accA[s] = __builtin_amdgcn_mfma_f32_16x16x32_f16(af, bfA, accA[s], 0, 0, 0);
                    if (DUAL) accB[s] = __builtin_amdgcn_mfma_f32_16x16x32_f16(af, bfB, accB[s], 0, 0, 0);
                }
            }
        }
        if (ch + 1 < NCH) __syncthreads();
    }

    const int co = m16;
    if (co < COUT) {
        #pragma unroll
        for (int s = 0; s < 7; ++s) {
            int t = wv + 4 * s;
            if (t < 25) {
                int km0 = t * 16 + q4 * 4;
                size_t o = ((size_t)(b * COUT + co) * HW + ij) * HW + km0;
                if (OUTF16) {
                    union { ushort_t us[4]; uint2 u2; } pk;
                    #pragma unroll
                    for (int r = 0; r < 4; ++r) {
                        union { _Float16 h; ushort_t u16; } cv;
                        cv.h = (_Float16)fmaxf(accA[s][r], 0.f);
                        pk.us[r] = cv.u16;
                    }
                    *(uint2*)((ushort_t*)outS + o) = pk.u2;
                    if (DUAL) {
                        #pragma unroll
                        for (int r = 0; r < 4; ++r) {
                            union { _Float16 h; ushort_t u16; } cv;
                            cv.h = (_Float16)fmaxf(accB[s][r], 0.f);
                            pk.us[r] = cv.u16;
                        }
                        *(uint2*)((ushort_t*)outB + o) = pk.u2;
                    }
                } else {
                    f32x4 ov;
                    #pragma unroll
                    for (int r = 0; r < 4; ++r) ov[r] = fmaxf(accA[s][r], 0.f);
                    *(f32x4*)((float*)outS + o) = ov;
                }
            }
        }
    }
}

// ---------------------------------------------------------------------------
// Kernel 4b (L3 only, from R5): 2-ij conv, MERGED-N (cout=1: n=0 -> ij0,
// n=1 -> ij1) — one MFMA per A-read computes both outputs. f32 out.
// ---------------------------------------------------------------------------
template <int CIN>
__global__ __launch_bounds__(256) void conv4d_l3(
        const ushort_t* __restrict__ inA, const ushort_t* __restrict__ inB,
        const ushort_t* __restrict__ wAm, const ushort_t* __restrict__ wBm,
        float* __restrict__ outA, float* __restrict__ outB) {
    constexpr int S2 = CIN * 12;
    constexpr int NCH = (S2 + 31) / 32;
    __shared__ __align__(16) ushort_t Ah[484 * 40];
    const int b = blockIdx.y, bx = blockIdx.x, z = blockIdx.z;
    const ushort_t* in = z ? inB : inA;
    const ushort_t* w1 = z ? wBm : wAm;
    float* outS = z ? outB : outA;
    const int i = bx / 10, jp = bx - (bx / 10) * 10;
    const int j0 = 2 * jp;
    const int ij0 = i * 20 + j0;
    const int tid = threadIdx.x, wv = tid >> 6, lane = tid & 63;
    const int m16 = lane & 15, q4 = lane >> 4;

    for (int p = tid; p < 484 * 20; p += 256) ((uint*)Ah)[p] = 0;

    int baseh[7];
    #pragma unroll
    for (int s = 0; s < 7; ++s) {
        int t = wv + 4 * s;
        if (t < 25) {
            int km = t * 16 + m16;
            int kk = km / 20, mm = km - kk * 20;
            baseh[s] = (kk * 22 + mm) * 40 + q4 * 8;
        } else baseh[s] = 0;
    }
    f32x4 acc1[7] = {};

    const bool stager = tid < 200;
    const int km1 = 2 * tid;
    const int r1 = stager ? ((km1 / 20 + 1) * 22 + (km1 % 20) + 1) : 0;
    int hofs[12]; bool vld[12];
    #pragma unroll
    for (int pl = 0; pl < 12; ++pl) {
        int di = pl >> 2, dj = pl & 3;
        int ii = i + di - 1, jj = j0 + dj - 1;
        vld[pl] = (unsigned)ii < 20u && (unsigned)jj < 20u;
        hofs[pl] = (ii * 20 + jj) * HW + km1;
    }
    const ushort_t* in_b = in + (size_t)b * CIN * HW * HW;
    const int wbase = m16 * 32 + q4 * 8;

    uint pf[32];
    #pragma unroll
    for (int u = 0; u < 32; ++u) {
        int slot = u;
        if (slot < S2) {
            int ci = slot / 12, pl = slot - ci * 12;
            pf[u] = (stager && vld[pl]) ? *(const uint*)(in_b + ci * (HW * HW) + hofs[pl]) : 0u;
        } else pf[u] = 0u;
    }
    __syncthreads();

    #pragma unroll
    for (int ch = 0; ch < NCH; ++ch) {
        if (stager) {
            #pragma unroll
            for (int g4 = 0; g4 < 8; ++g4) {
                uint lo0 = (pf[4 * g4] & 0xFFFFu) | (pf[4 * g4 + 1] << 16);
                uint lo1 = (pf[4 * g4 + 2] & 0xFFFFu) | (pf[4 * g4 + 3] << 16);
                uint hi0 = (pf[4 * g4] >> 16) | (pf[4 * g4 + 1] & 0xFFFF0000u);
                uint hi1 = (pf[4 * g4 + 2] >> 16) | (pf[4 * g4 + 3] & 0xFFFF0000u);
                uint2 wlo; wlo.x = lo0; wlo.y = lo1;
                uint2 whi; whi.x = hi0; whi.y = hi1;
                *(uint2*)&Ah[(size_t)r1 * 40 + 4 * g4] = wlo;
                *(uint2*)&Ah[(size_t)(r1 + 1) * 40 + 4 * g4] = whi;
            }
        }
        __syncthreads();
        if (ch + 1 < NCH) {
            #pragma unroll
            for (int u = 0; u < 32; ++u) {
                int slot = (ch + 1) * 32 + u;
                if (slot < S2) {
                    int ci = slot / 12, pl = slot - ci * 12;
                    pf[u] = (stager && vld[pl]) ? *(const uint*)(in_b + ci * (HW * HW) + hofs[pl]) : 0u;
                } else pf[u] = 0u;
            }
        }
        #pragma unroll
        for (int dd = 0; dd < 9; ++dd) {
            half8 bf1 = *(const half8*)(w1 + (ch * 9 + dd) * 512 + wbase);
            const int doff = ((dd / 3) * 22 + (dd % 3)) * 40;
            #pragma unroll
            for (int s = 0; s < 7; ++s) {
                if (wv + 4 * s < 25) {
                    half8 af = *(const half8*)(Ah + baseh[s] + doff);
                    acc1[s] = __builtin_amdgcn_mfma_f32_16x16x32_f16(af, bf1, acc1[s], 0, 0, 0);
                }
            }
        }
        if (ch + 1 < NCH) __syncthreads();
    }

    if (m16 < 2) {
        const int ij = ij0 + m16;
        #pragma unroll
        for (int s = 0; s < 7; ++s) {
            int t = wv + 4 * s;
            if (t < 25) {
                int km0 = t * 16 + q4 * 4;
                size_t o = ((size_t)b * HW + ij) * HW + km0;
                f32x4 ov;
                #pragma unroll
                for (int r = 0; r < 4; ++r) ov[r] = fmaxf(acc1[s][r], 0.f);
                *(f32x4*)(outS + o) = ov;
            }
        }
    }
}

// ---------------------------------------------------------------------------
// Kernel 5 (v3): softmax + attn.V via MFMA, summing the two L3 path outputs.
// ---------------------------------------------------------------------------
__global__ __launch_bounds__(256) void softmax_av_mfma2(const float* __restrict__ c4A,
                                                        const float* __restrict__ c4B,
                                                        const ushort_t* __restrict__ fsh,
                                                        float* __restrict__ att) {
    __shared__ ushort_t P[64 * 424];
    __shared__ float invl[64];
    const int b = blockIdx.z, qb = blockIdx.x * 64;
    const int tid = threadIdx.x, wv = tid >> 6, lane = tid & 63;
    const int m16 = lane & 15, q4 = lane >> 4;
    const int lane16 = lane & 15, rg4 = lane >> 4;

    #pragma unroll 1
    for (int rg = 0; rg < 4; ++rg) {
        const int ql = wv * 16 + rg * 4 + rg4;
        int q = qb + ql; if (q > HW - 1) q = HW - 1;
        const float* rowA = c4A + ((size_t)b * HW + q) * HW;
        const float* rowB = c4B + ((size_t)b * HW + q) * HW;
        float4 v4[7];
        #pragma unroll
        for (int k4 = 0; k4 < 6; ++k4) {
            float4 a4 = *(const float4*)(rowA + 64 * k4 + lane16 * 4);
            float4 b4 = *(const float4*)(rowB + 64 * k4 + lane16 * 4);
            v4[k4] = make_float4(a4.x + b4.x, a4.y + b4.y, a4.z + b4.z, a4.w + b4.w);
        }
        if (lane16 < 4) {
            float4 a4 = *(const float4*)(rowA + 384 + lane16 * 4);
            float4 b4 = *(const float4*)(rowB + 384 + lane16 * 4);
            v4[6] = make_float4(a4.x + b4.x, a4.y + b4.y, a4.z + b4.z, a4.w + b4.w);
        } else {
            v4[6] = make_float4(-1e30f, -1e30f, -1e30f, -1e30f);
        }
        float mx = -1e30f;
        #pragma unroll
        for (int k4 = 0; k4 < 7; ++k4)
            mx = fmaxf(mx, fmaxf(fmaxf(v4[k4].x, v4[k4].y), fmaxf(v4[k4].z, v4[k4].w)));
        #pragma unroll
        for (int off = 8; off; off >>= 1) mx = fmaxf(mx, __shfl_xor(mx, off, 16));
        float sum = 0.f;
        #pragma unroll
        for (int k4 = 0; k4 < 7; ++k4) {
            if (k4 == 6 && lane16 >= 4) break;
            float e0 = __expf(TEMPF * (v4[k4].x - mx));
            float e1 = __expf(TEMPF * (v4[k4].y - mx));
            float e2 = __expf(TEMPF * (v4[k4].z - mx));
            float e3 = __expf(TEMPF * (v4[k4].w - mx));
            sum += e0 + e1 + e2 + e3;
            union { ushort_t us[4]; uint2 u2; } pk;
            union { _Float16 h; ushort_t u16; } cv;
            cv.h = (_Float16)e0; pk.us[0] = cv.u16;
            cv.h = (_Float16)e1; pk.us[1] = cv.u16;
            cv.h = (_Float16)e2; pk.us[2] = cv.u16;
            cv.h = (_Float16)e3; pk.us[3] = cv.u16;
            *(uint2*)&P[(size_t)ql * 424 + 64 * k4 + lane16 * 4] = pk.u2;
        }
        if (lane16 >= 4 && lane16 < 10) {
            uint2 z2; z2.x = 0; z2.y = 0;
            *(uint2*)&P[(size_t)ql * 424 + 384 + lane16 * 4] = z2;
        }
        #pragma unroll
        for (int off = 8; off; off >>= 1) sum += __shfl_xor(sum, off, 16);
        if (lane16 == 0) invl[ql] = 1.0f / sum;
    }

    half8 afr[13];
    #pragma unroll
    for (int ks = 0; ks < 13; ++ks)
        afr[ks] = *(const half8*)&P[(size_t)(wv * 16 + m16) * 424 + ks * 32 + q4 * 8];
    const ushort_t* fb = fsh + (size_t)b * CH * 416;
    #pragma unroll
    for (int ntl = 0; ntl < 2; ++ntl) {
        const int nt = blockIdx.y * 2 + ntl;
        const int c = nt * 16 + m16;
        const ushort_t* fc = fb + (size_t)c * 416 + q4 * 8;
        f32x4 acc = {};
        #pragma unroll
        for (int ks = 0; ks < 13; ++ks) {
            half8 bf = *(const half8*)(fc + ks * 32);
            acc = __builtin_amdgcn_mfma_f32_16x16x32_f16(afr[ks], bf, acc, 0, 0, 0);
        }
        #pragma unroll
        for (int r = 0; r < 4; ++r) {
            int ql = wv * 16 + q4 * 4 + r;
            int q = qb + ql;
            if (q < HW)
                att[((size_t)b * CH + c) * HW + q] = acc[r] * invl[ql];
        }
    }
}

// ---------------------------------------------------------------------------
// Kernel 6 (v2): fq = l2norm(f_q, ch) + 0.5 * l2norm(att_fq, ch).
// Shuffle-based double reduction (1 barrier instead of 16).
// ---------------------------------------------------------------------------
__global__ __launch_bounds__(256) void final_fq(const float* __restrict__ f_q,
                                                const float* __restrict__ att,
                                                float* __restrict__ out_fq) {
    __shared__ float2 red[4];
    int b = blockIdx.y, q = blockIdx.x;
    int tid = threadIdx.x, wv = tid >> 6, lane = tid & 63;
    size_t idx = (size_t)(b * CH + tid) * HW + q;
    float f = f_q[idx];
    float a = att[idx];
    float vf = f * f, va = a * a;
    #pragma unroll
    for (int off = 32; off; off >>= 1) {
        vf += __shfl_xor(vf, off);
        va += __shfl_xor(va, off);
    }
    if (lane == 0) red[wv] = make_float2(vf, va);
    __syncthreads();
    float sf = red[0].x + red[1].x + red[2].x + red[3].x;
    float sa = red[0].y + red[1].y + red[2].y + red[3].y;
    float invf = 1.0f / fmaxf(sqrtf(sf), EPSF);
    float inva = 1.0f / fmaxf(sqrtf(sa), EPSF);
    out_fq[idx] = f * invf + 0.5f * a * inva;
}

// ---------------------------------------------------------------------------
extern "C" void kernel_launch(void* const* d_in, const int* in_sizes, int n_in,
                              void* d_out, int out_size, void* d_ws, size_t ws_size,
                              hipStream_t stream) {
    const float* fq_feats = (const float*)d_in[0];
    const float* fs_feats = (const float*)d_in[1];
    const float* f_q      = (const float*)d_in[2];
    const float* f_s      = (const float*)d_in[3];
    const float* w1       = (const float*)d_in[4];
    const float* w2       = (const float*)d_in[5];
    const float* w3       = (const float*)d_in[6];
    float* out = (float*)d_out;              // fq at 0, att_fq at 204800

    float* ws      = (float*)d_ws;
    float* wbuf    = ws;                     // 115,200 fl: weight tables
    float* ssbuf   = wbuf + 115200;          // 14,400 fl: fused-norm ss
    float* corr    = ssbuf + 14400;          // 2,880,000 fl region:
                                             //   [0 .. 1.44M) corr f16
                                             //   [1.44M .. 1.55M) fsh f16
                                             //   [1.60M .. 1.92M) c4A f32
                                             //   [1.92M .. 2.24M) c4B f32
    float* buf1    = corr + 2880000;         // 3,200,000 (At / b1A+b1B)
    float* buf2    = buf1 + 3200000;         // 3,200,000 (Bt / b2A+b2B)
    float* att     = out + 204800;

    ushort_t* corr_h = (ushort_t*)corr;
    ushort_t* fsh    = (ushort_t*)(corr + 1440000);
    float* c4A = corr + 1600000;
    float* c4B = corr + 1920000;
    ushort_t* At = (ushort_t*)buf1;
    ushort_t* Bt = (ushort_t*)buf2;
    ushort_t* b1A = (ushort_t*)buf1;
    ushort_t* b1B = b1A + 3200000;
    ushort_t* b2A = (ushort_t*)buf2;
    ushort_t* b2B = b2A + 3200000;

    // weight tables (halfs): L1A 0, L1B 13824, L2A 27648, L2B 41472,
    // L3Am 55296, L3Bm 73728 (18432 each for L3)
    ushort_t* wb0   = (ushort_t*)wbuf;
    ushort_t* wbL1A = wb0;
    ushort_t* wbL1B = wb0 + 13824;
    ushort_t* wbL2A = wb0 + 27648;
    ushort_t* wbL2B = wb0 + 41472;
    ushort_t* wbL3Am = wb0 + 55296;
    ushort_t* wbL3Bm = wb0 + 73728;

    // ONE prep launch: all weight tables + fsh + ss zero
    prep_all<<<832, 256, 0, stream>>>(w1, w2, w3, f_s, wb0, fsh, ssbuf);

    for (int half = 0; half < 2; ++half) {
        int base = half * 9;
        transpose_f16<<<dim3(16, 7, 18), 256, 0, stream>>>(fq_feats, fs_feats, At, Bt, ssbuf, base);
        corr_gemm_mfma<<<dim3(7, 7, 9), 256, 0, stream>>>(At, Bt, ssbuf, corr_h, base);
    }

    // L1: both paths, one staging (DUAL), 800 blocks
    conv4d_v8<9, 10, true, true><<<dim3(400, NB, 1), 256, 0, stream>>>(
        corr_h, corr_h, wbL1A, wbL1B, b1A, b1B);
    // L2: paths merged via grid-z (best-measured structure), 1600 blocks
    conv4d_v8<10, 10, false, true><<<dim3(400, NB, 2), 256, 0, stream>>>(
        b1A, b1B, wbL2A, wbL2B, b2A, b2B);
    // L3: 2-ij merged-N blocks (1 MFMA per A-read for both ij), f32 out
    conv4d_l3<10><<<dim3(200, NB, 2), 256, 0, stream>>>(
        b2A, b2B, wbL3Am, wbL3Bm, c4A, c4B);

    softmax_av_mfma2<<<dim3(7, 8, NB), 256, 0, stream>>>(c4A, c4B, fsh, att);
    final_fq<<<dim3(400, NB), 256, 0, stream>>>(f_q, att, out);

    (void)in_sizes; (void)n_in; (void)out_size; (void)ws_size;
}

// Round 7
// 337.194 us; speedup vs baseline: 1.1427x; 1.0223x over previous
//
#include <hip/hip_runtime.h>
#include <math.h>
#include <stddef.h>

#define L9   9
#define NB   2
#define CF   1024
#define HW   400     // 20*20
#define CH   256
#define TEMPF 20.0f
#define EPSF  1e-12f

typedef _Float16 half8 __attribute__((ext_vector_type(8)));
typedef float f32x4 __attribute__((ext_vector_type(4)));
typedef unsigned short ushort_t;

// ---------------------------------------------------------------------------
// Kernel P: ALL prep work in ONE launch (weight tables + fsh + ss zero).
// ---------------------------------------------------------------------------
__global__ __launch_bounds__(256) void prep_all(const float* __restrict__ w1,
                                                const float* __restrict__ w2,
                                                const float* __restrict__ w3,
                                                const float* __restrict__ f_s,
                                                ushort_t* __restrict__ wb0,
                                                ushort_t* __restrict__ fsh,
                                                float* __restrict__ ssbuf) {
    int gid = blockIdx.x * 256 + threadIdx.x;
    if (gid < NB * CH * 416) {
        int s = gid % 416, bc = gid / 416;
        float v = (s < HW) ? f_s[(size_t)bc * HW + s] : 0.f;
        union { _Float16 h; ushort_t u; } cv; cv.h = (_Float16)v;
        fsh[gid] = cv.u;
    }
    if (gid < 14400) ssbuf[gid] = 0.f;
    if (gid < 6 * 18432) {
        int job = gid / 18432, idx = gid - job * 18432;
        int k = idx & 31, n = (idx >> 5) & 15, dd = (idx >> 9) % 9, ch = idx / 4608;
        int dk = dd / 3, dm = dd % 3;
        float v = 0.f;
        if (job < 4) {
            if (idx < 13824) {
                int CIN = (job < 2) ? 9 : 10;
                const float* wt = (job < 2) ? w1 : w2;
                bool swap = job & 1;
                int slot = ch * 32 + k;
                if (n < 10 && slot < CIN * 9) {
                    int ci = slot / 9, pl = slot - ci * 9;
                    int di = pl / 3, dj = pl % 3;
                    int widx = swap ? ((((n * CIN + ci) * 3 + dk) * 3 + dm) * 3 + di) * 3 + dj
                                    : ((((n * CIN + ci) * 3 + di) * 3 + dj) * 3 + dk) * 3 + dm;
                    v = wt[widx];
                }
                union { _Float16 h; ushort_t u; } cv; cv.h = (_Float16)v;
                wb0[job * 13824 + idx] = cv.u;
            }
        } else {
            bool swap = (job == 5);
            int slot = ch * 32 + k;
            if (slot < 120) {
                int ci = slot / 12, r = slot - ci * 12;
                int di = r >> 2, dj4 = r & 3;
                int e = dj4 - n;
                if (n < 2 && e >= 0 && e <= 2) {
                    int widx = swap ? (((ci * 3 + dk) * 3 + dm) * 3 + di) * 3 + e
                                    : (((ci * 3 + di) * 3 + e) * 3 + dk) * 3 + dm;
                    v = w3[widx];
                }
            }
            union { _Float16 h; ushort_t u; } cv; cv.h = (_Float16)v;
            wb0[55296 + (job - 4) * 18432 + idx] = cv.u;
        }
    }
}

// ---------------------------------------------------------------------------
// Kernel 3a (v2): transpose+convert WITH FUSED NORM PARTIALS.
// ---------------------------------------------------------------------------
__global__ __launch_bounds__(256) void transpose_f16(const float* __restrict__ fq,
                                                     const float* __restrict__ fs,
                                                     ushort_t* __restrict__ At,
                                                     ushort_t* __restrict__ Bt,
                                                     float* __restrict__ ssbuf,
                                                     int lb_base) {
    __shared__ float tile[64][65];
    __shared__ float red4[4][64];
    int z = blockIdx.z;
    int tsel = z / 9, li = z - tsel * 9;
    int lb = lb_base + li;
    const float* src = (tsel ? fs : fq) + (size_t)lb * CF * HW;
    ushort_t* dst = (tsel ? Bt : At) + (size_t)li * HW * CF;
    int c0 = blockIdx.x * 64, ij0 = blockIdx.y * 64;
    int tid = threadIdx.x;
    int cl = tid >> 6;
    int col = tid & 63;
    float ssp = 0.f;
    #pragma unroll
    for (int rr = 0; rr < 16; ++rr) {
        int c_local = rr * 4 + cl;
        int ij = ij0 + col;
        float v = (ij < HW) ? src[(size_t)(c0 + c_local) * HW + ij] : 0.f;
        tile[c_local][col] = v;
        ssp = fmaf(v, v, ssp);
    }
    red4[cl][col] = ssp;
    __syncthreads();
    if (cl == 0) {
        int ij = ij0 + col;
        if (ij < HW) {
            float s4 = red4[0][col] + red4[1][col] + red4[2][col] + red4[3][col];
            atomicAdd(&ssbuf[(size_t)(tsel * 18 + lb) * HW + ij], s4);
        }
    }
    int cp = (tid & 31) * 2;
    int rowsel = tid >> 5;
    #pragma unroll
    for (int rr = 0; rr < 8; ++rr) {
        int ij_local = rr * 8 + rowsel;
        int ij = ij0 + ij_local;
        if (ij < HW) {
            union { _Float16 h; ushort_t u; } h0, h1;
            h0.h = (_Float16)tile[cp][ij_local];
            h1.h = (_Float16)tile[cp + 1][ij_local];
            ushort2 o; o.x = h0.u; o.y = h1.u;
            *(ushort2*)(dst + (size_t)ij * CF + c0 + cp) = o;
        }
    }
}

// ---------------------------------------------------------------------------
// Kernel 3b: MFMA fp16 correlation GEMM; inverse norms in epilogue from ss.
// ---------------------------------------------------------------------------
__global__ __launch_bounds__(256) void corr_gemm_mfma(const ushort_t* __restrict__ At,
                                                      const ushort_t* __restrict__ Bt,
                                                      const float* __restrict__ ssbuf,
                                                      ushort_t* __restrict__ corr,
                                                      int lb_base) {
    __shared__ ushort_t As[64][72];
    __shared__ ushort_t Bs[64][72];
    int li = blockIdx.z, lb = lb_base + li;
    int l = lb >> 1, b = lb & 1;
    int i0 = blockIdx.y * 64, j0 = blockIdx.x * 64;
    int tid = threadIdx.x, lane = tid & 63, w = tid >> 6;
    int mw = (w >> 1) * 32, nw = (w & 1) * 32;
    f32x4 acc[2][2] = {};
    const ushort_t* Abase = At + (size_t)li * HW * CF;
    const ushort_t* Bbase = Bt + (size_t)li * HW * CF;

    for (int kt = 0; kt < 16; ++kt) {
        int c0 = kt * 64;
        __syncthreads();
        #pragma unroll
        for (int p = 0; p < 2; ++p) {
            int idx = tid + p * 256;
            int row = idx >> 3, c8 = idx & 7;
            uint4 va = make_uint4(0, 0, 0, 0), vb = make_uint4(0, 0, 0, 0);
            if (i0 + row < HW) va = *(const uint4*)(Abase + (size_t)(i0 + row) * CF + c0 + c8 * 8);
            if (j0 + row < HW) vb = *(const uint4*)(Bbase + (size_t)(j0 + row) * CF + c0 + c8 * 8);
            *(uint4*)&As[row][c8 * 8] = va;
            *(uint4*)&Bs[row][c8 * 8] = vb;
        }
        __syncthreads();
        #pragma unroll
        for (int ks = 0; ks < 2; ++ks) {
            int k0 = ks * 32 + (lane >> 4) * 8;
            half8 a0 = *(const half8*)&As[mw + (lane & 15)][k0];
            half8 a1 = *(const half8*)&As[mw + 16 + (lane & 15)][k0];
            half8 b0 = *(const half8*)&Bs[nw + (lane & 15)][k0];
            half8 b1 = *(const half8*)&Bs[nw + 16 + (lane & 15)][k0];
            acc[0][0] = __builtin_amdgcn_mfma_f32_16x16x32_f16(a0, b0, acc[0][0], 0, 0, 0);
            acc[0][1] = __builtin_amdgcn_mfma_f32_16x16x32_f16(a0, b1, acc[0][1], 0, 0, 0);
            acc[1][0] = __builtin_amdgcn_mfma_f32_16x16x32_f16(a1, b0, acc[1][0], 0, 0, 0);
            acc[1][1] = __builtin_amdgcn_mfma_f32_16x16x32_f16(a1, b1, acc[1][1], 0, 0, 0);
        }
    }
    int obase = (b * 9 + l) * HW;
    #pragma unroll
    for (int ni = 0; ni < 2; ++ni) {
        int km = j0 + nw + ni * 16 + (lane & 15);
        if (km >= HW) continue;
        float ib = 1.0f / fmaxf(sqrtf(ssbuf[(size_t)(18 + lb) * HW + km]), EPSF);
        #pragma unroll
        for (int mi = 0; mi < 2; ++mi) {
            #pragma unroll
            for (int r = 0; r < 4; ++r) {
                int ij = i0 + mw + mi * 16 + (lane >> 4) * 4 + r;
                if (ij < HW) {
                    float ia = 1.0f / fmaxf(sqrtf(ssbuf[(size_t)lb * HW + ij]), EPSF);
                    union { _Float16 h; ushort_t u; } cv;
                    cv.h = (_Float16)(acc[mi][ni][r] * ia * ib);
                    corr[(size_t)(obase + ij) * HW + km] = cv.u;
                }
            }
        }
    }
}

// ---------------------------------------------------------------------------
// Kernel 4 (v14): conv4d_v8 structure widened to 512 threads / 8 waves.
// R1's 512-thread attempt failed ONLY because __launch_bounds__(512,5)
// forced VGPR to 44 (< the 32 live pf[] regs -> spill). Here: (512,2),
// acc arrays 7->4 (t = (7-wv) + 8s; wave 7 = non-stager gets the 4-tile
// load), LDS unchanged 38.9KB -> still 4 blocks/CU but 8 waves each ->
// up to 32 waves/CU (VGPR-capped ~20-24) vs 16 today. Pure TLP experiment
// against the 62us latency floor; all pipes sit at 10-31% busy.
// ---------------------------------------------------------------------------
template <int CIN, int COUT, bool DUAL, bool OUTF16>
__global__ __launch_bounds__(512, 2) void conv4d_v14(const ushort_t* __restrict__ inA,
                                                     const ushort_t* __restrict__ inB,
                                                     const ushort_t* __restrict__ wbA,
                                                     const ushort_t* __restrict__ wbB,
                                                     void* __restrict__ outA,
                                                     void* __restrict__ outB) {
    constexpr int S = CIN * 9;
    constexpr int NCH = (S + 31) / 32;
    __shared__ __align__(16) ushort_t Ah[484 * 40];
    const int b = blockIdx.y, ij = blockIdx.x;
    const int z = blockIdx.z;
    const ushort_t* in = (DUAL || z == 0) ? inA : inB;
    const ushort_t* wbS = (DUAL || z == 0) ? wbA : wbB;
    void* outS = (DUAL || z == 0) ? outA : outB;
    const int i = ij / 20, j = ij - (ij / 20) * 20;
    const int tid = threadIdx.x, wv = tid >> 6, lane = tid & 63;
    const int m16 = lane & 15, q4 = lane >> 4;
    const int wt = 7 - wv;   // wave 7 (non-stager) owns the 4-tile group

    for (int p = tid; p < 484 * 20; p += 512) ((uint*)Ah)[p] = 0;

    int baseh[4];
    #pragma unroll
    for (int s = 0; s < 4; ++s) {
        int t = wt + 8 * s;
        if (t < 25) {
            int km = t * 16 + m16;
            int kk = km / 20, mm = km - kk * 20;
            baseh[s] = (kk * 22 + mm) * 40 + q4 * 8;
        } else baseh[s] = 0;
    }
    f32x4 accA[4] = {};
    f32x4 accB[4] = {};

    const bool stager = tid < 200;
    const int km1 = 2 * tid;
    const int r1 = stager ? ((km1 / 20 + 1) * 22 + (km1 % 20) + 1) : 0;
    int hofs[9]; bool vld[9];
    #pragma unroll
    for (int pl = 0; pl < 9; ++pl) {
        int ii = i + pl / 3 - 1, jj = j + pl % 3 - 1;
        vld[pl] = (unsigned)ii < 20u && (unsigned)jj < 20u;
        hofs[pl] = (ii * 20 + jj) * HW + km1;
    }
    const ushort_t* in_b = in + (size_t)b * CIN * HW * HW;
    const int wbase = m16 * 32 + q4 * 8;

    uint pf[32];
    #pragma unroll
    for (int u = 0; u < 32; ++u) {
        int slot = u;
        if (slot < S) {
            int ci = slot / 9, pl = slot - ci * 9;
            pf[u] = (stager && vld[pl]) ? *(const uint*)(in_b + ci * (HW * HW) + hofs[pl]) : 0u;
        } else pf[u] = 0u;
    }
    __syncthreads();

    #pragma unroll
    for (int ch = 0; ch < NCH; ++ch) {
        if (stager) {
            #pragma unroll
            for (int g4 = 0; g4 < 8; ++g4) {
                uint lo0 = (pf[4 * g4] & 0xFFFFu) | (pf[4 * g4 + 1] << 16);
                uint lo1 = (pf[4 * g4 + 2] & 0xFFFFu) | (pf[4 * g4 + 3] << 16);
                uint hi0 = (pf[4 * g4] >> 16) | (pf[4 * g4 + 1] & 0xFFFF0000u);
                uint hi1 = (pf[4 * g4 + 2] >> 16) | (pf[4 * g4 + 3] & 0xFFFF0000u);
                uint2 wlo; wlo.x = lo0; wlo.y = lo1;
                uint2 whi; whi.x = hi0; whi.y = hi1;
                *(uint2*)&Ah[(size_t)r1 * 40 + 4 * g4] = wlo;
                *(uint2*)&Ah[(size_t)(r1 + 1) * 40 + 4 * g4] = whi;
            }
        }
        __syncthreads();
        if (ch + 1 < NCH) {
            #pragma unroll
            for (int u = 0; u < 32; ++u) {
                int slot = (ch + 1) * 32 + u;
                if (slot < S) {
                    int ci = slot / 9, pl = slot - ci * 9;
                    pf[u] = (stager && vld[pl]) ? *(const uint*)(in_b + ci * (HW * HW) + hofs[pl]) : 0u;
                } else pf[u] = 0u;
            }
        }
        #pragma unroll
        for (int dd = 0; dd < 9; ++dd) {
            half8 bfA = *(const half8*)(wbS + (ch * 9 + dd) * 512 + wbase);
            half8 bfB;
            if (DUAL) bfB = *(const half8*)(wbB + (ch * 9 + dd) * 512 + wbase);
            const int doff = ((dd / 3) * 22 + (dd % 3)) * 40;
            #pragma unroll
            for (int s = 0; s < 4; ++s) {
                if (wt + 8 * s < 25) {
                    half8 af = *(const half8*)(Ah + baseh[s] + doff);
                    accA[s] = __builtin_amdgcn_mfma_f32_16x16x32_f16(af, bfA, accA[s], 0, 0, 0);
                    if (DUAL) accB[s] = __builtin_amdgcn_mfma_f32_16x16x32_f16(af, bfB, accB[s], 0, 0, 0);
                }
            }
        }
        if (ch + 1 < NCH) __syncthreads();
    }

    const int co = m16;
    if (co < COUT) {
        #pragma unroll
        for (int s = 0; s < 4; ++s) {
            int t = wt + 8 * s;
            if (t < 25) {
                int km0 = t * 16 + q4 * 4;
                size_t o = ((size_t)(b * COUT + co) * HW + ij) * HW + km0;
                if (OUTF16) {
                    union { ushort_t us[4]; uint2 u2; } pk;
                    #pragma unroll
                    for (int r = 0; r < 4; ++r) {
                        union { _Float16 h; ushort_t u16; } cv;
                        cv.h = (_Float16)fmaxf(accA[s][r], 0.f);
                        pk.us[r] = cv.u16;
                    }
                    *(uint2*)((ushort_t*)outS + o) = pk.u2;
                    if (DUAL) {
                        #pragma unroll
                        for (int r = 0; r < 4; ++r) {
                            union { _Float16 h; ushort_t u16; } cv;
                            cv.h = (_Float16)fmaxf(accB[s][r], 0.f);
                            pk.us[r] = cv.u16;
                        }
                        *(uint2*)((ushort_t*)outB + o) = pk.u2;
                    }
                } else {
                    f32x4 ov;
                    #pragma unroll
                    for (int r = 0; r < 4; ++r) ov[r] = fmaxf(accA[s][r], 0.f);
                    *(f32x4*)((float*)outS + o) = ov;
                }
            }
        }
    }
}

// ---------------------------------------------------------------------------
// Kernel 4b (L3, v14): 2-ij merged-N conv, widened to 512 threads likewise.
// ---------------------------------------------------------------------------
template <int CIN>
__global__ __launch_bounds__(512, 2) void conv4d_l3(
        const ushort_t* __restrict__ inA, const ushort_t* __restrict__ inB,
        const ushort_t* __restrict__ wAm, const ushort_t* __restrict__ wBm,
        float* __restrict__ outA, float* __restrict__ outB) {
    constexpr int S2 = CIN * 12;
    constexpr int NCH = (S2 + 31) / 32;
    __shared__ __align__(16) ushort_t Ah[484 * 40];
    const int b = blockIdx.y, bx = blockIdx.x, z = blockIdx.z;
    const ushort_t* in = z ? inB : inA;
    const ushort_t* w1 = z ? wBm : wAm;
    float* outS = z ? outB : outA;
    const int i = bx / 10, jp = bx - (bx / 10) * 10;
    const int j0 = 2 * jp;
    const int ij0 = i * 20 + j0;
    const int tid = threadIdx.x, wv = tid >> 6, lane = tid & 63;
    const int m16 = lane & 15, q4 = lane >> 4;
    const int wt = 7 - wv;

    for (int p = tid; p < 484 * 20; p += 512) ((uint*)Ah)[p] = 0;

    int baseh[4];
    #pragma unroll
    for (int s = 0; s < 4; ++s) {
        int t = wt + 8 * s;
        if (t < 25) {
            int km = t * 16 + m16;
            int kk = km / 20, mm = km - kk * 20;
            baseh[s] = (kk * 22 + mm) * 40 + q4 * 8;
        } else baseh[s] = 0;
    }
    f32x4 acc1[4] = {};

    const bool stager = tid < 200;
    const int km1 = 2 * tid;
    const int r1 = stager ? ((km1 / 20 + 1) * 22 + (km1 % 20) + 1) : 0;
    int hofs[12]; bool vld[12];
    #pragma unroll
    for (int pl = 0; pl < 12; ++pl) {
        int di = pl >> 2, dj = pl & 3;
        int ii = i + di - 1, jj = j0 + dj - 1;
        vld[pl] = (unsigned)ii < 20u && (unsigned)jj < 20u;
        hofs[pl] = (ii * 20 + jj) * HW + km1;
    }
    const ushort_t* in_b = in + (size_t)b * CIN * HW * HW;
    const int wbase = m16 * 32 + q4 * 8;

    uint pf[32];
    #pragma unroll
    for (int u = 0; u < 32; ++u) {
        int slot = u;
        if (slot < S2) {
            int ci = slot / 12, pl = slot - ci * 12;
            pf[u] = (stager && vld[pl]) ? *(const uint*)(in_b + ci * (HW * HW) + hofs[pl]) : 0u;
        } else pf[u] = 0u;
    }
    __syncthreads();

    #pragma unroll
    for (int ch = 0; ch < NCH; ++ch) {
        if (stager) {
            #pragma unroll
            for (int g4 = 0; g4 < 8; ++g4) {
                uint lo0 = (pf[4 * g4] & 0xFFFFu) | (pf[4 * g4 + 1] << 16);
                uint lo1 = (pf[4 * g4 + 2] & 0xFFFFu) | (pf[4 * g4 + 3] << 16);
                uint hi0 = (pf[4 * g4] >> 16) | (pf[4 * g4 + 1] & 0xFFFF0000u);
                uint hi1 = (pf[4 * g4 + 2] >> 16) | (pf[4 * g4 + 3] & 0xFFFF0000u);
                uint2 wlo; wlo.x = lo0; wlo.y = lo1;
                uint2 whi; whi.x = hi0; whi.y = hi1;
                *(uint2*)&Ah[(size_t)r1 * 40 + 4 * g4] = wlo;
                *(uint2*)&Ah[(size_t)(r1 + 1) * 40 + 4 * g4] = whi;
            }
        }
        __syncthreads();
        if (ch + 1 < NCH) {
            #pragma unroll
            for (int u = 0; u < 32; ++u) {
                int slot = (ch + 1) * 32 + u;
                if (slot < S2) {
                    int ci = slot / 12, pl = slot - ci * 12;
                    pf[u] = (stager && vld[pl]) ? *(const uint*)(in_b + ci * (HW * HW) + hofs[pl]) : 0u;
                } else pf[u] = 0u;
            }
        }
        #pragma unroll
        for (int dd = 0; dd < 9; ++dd) {
            half8 bf1 = *(const half8*)(w1 + (ch * 9 + dd) * 512 + wbase);
            const int doff = ((dd / 3) * 22 + (dd % 3)) * 40;
            #pragma unroll
            for (int s = 0; s < 4; ++s) {
                if (wt + 8 * s < 25) {
                    half8 af = *(const half8*)(Ah + baseh[s] + doff);
                    acc1[s] = __builtin_amdgcn_mfma_f32_16x16x32_f16(af, bf1, acc1[s], 0, 0, 0);
                }
            }
        }
        if (ch + 1 < NCH) __syncthreads();
    }

    if (m16 < 2) {
        const int ij = ij0 + m16;
        #pragma unroll
        for (int s = 0; s < 4; ++s) {
            int t = wt + 8 * s;
            if (t < 25) {
                int km0 = t * 16 + q4 * 4;
                size_t o = ((size_t)b * HW + ij) * HW + km0;
                f32x4 ov;
                #pragma unroll
                for (int r = 0; r < 4; ++r) ov[r] = fmaxf(acc1[s][r], 0.f);
                *(f32x4*)(outS + o) = ov;
            }
        }
    }
}

// ---------------------------------------------------------------------------
// Kernel 5 (v3): softmax + attn.V via MFMA, summing the two L3 path outputs.
// ---------------------------------------------------------------------------
__global__ __launch_bounds__(256) void softmax_av_mfma2(const float* __restrict__ c4A,
                                                        const float* __restrict__ c4B,
                                                        const ushort_t* __restrict__ fsh,
                                                        float* __restrict__ att) {
    __shared__ ushort_t P[64 * 424];
    __shared__ float invl[64];
    const int b = blockIdx.z, qb = blockIdx.x * 64;
    const int tid = threadIdx.x, wv = tid >> 6, lane = tid & 63;
    const int m16 = lane & 15, q4 = lane >> 4;
    const int lane16 = lane & 15, rg4 = lane >> 4;

    #pragma unroll 1
    for (int rg = 0; rg < 4; ++rg) {
        const int ql = wv * 16 + rg * 4 + rg4;
        int q = qb + ql; if (q > HW - 1) q = HW - 1;
        const float* rowA = c4A + ((size_t)b * HW + q) * HW;
        const float* rowB = c4B + ((size_t)b * HW + q) * HW;
        float4 v4[7];
        #pragma unroll
        for (int k4 = 0; k4 < 6; ++k4) {
            float4 a4 = *(const float4*)(rowA + 64 * k4 + lane16 * 4);
            float4 b4 = *(const float4*)(rowB + 64 * k4 + lane16 * 4);
            v4[k4] = make_float4(a4.x + b4.x, a4.y + b4.y, a4.z + b4.z, a4.w + b4.w);
        }
        if (lane16 < 4) {
            float4 a4 = *(const float4*)(rowA + 384 + lane16 * 4);
            float4 b4 = *(const float4*)(rowB + 384 + lane16 * 4);
            v4[6] = make_float4(a4.x + b4.x, a4.y + b4.y, a4.z + b4.z, a4.w + b4.w);
        } else {
            v4[6] = make_float4(-1e30f, -1e30f, -1e30f, -1e30f);
        }
        float mx = -1e30f;
        #pragma unroll
        for (int k4 = 0; k4 < 7; ++k4)
            mx = fmaxf(mx, fmaxf(fmaxf(v4[k4].x, v4[k4].y), fmaxf(v4[k4].z, v4[k4].w)));
        #pragma unroll
        for (int off = 8; off; off >>= 1) mx = fmaxf(mx, __shfl_xor(mx, off, 16));
        float sum = 0.f;
        #pragma unroll
        for (int k4 = 0; k4 < 7; ++k4) {
            if (k4 == 6 && lane16 >= 4) break;
            float e0 = __expf(TEMPF * (v4[k4].x - mx));
            float e1 = __expf(TEMPF * (v4[k4].y - mx));
            float e2 = __expf(TEMPF * (v4[k4].z - mx));
            float e3 = __expf(TEMPF * (v4[k4].w - mx));
            sum += e0 + e1 + e2 + e3;
            union { ushort_t us[4]; uint2 u2; } pk;
            union { _Float16 h; ushort_t u16; } cv;
            cv.h = (_Float16)e0; pk.us[0] = cv.u16;
            cv.h = (_Float16)e1; pk.us[1] = cv.u16;
            cv.h = (_Float16)e2; pk.us[2] = cv.u16;
            cv.h = (_Float16)e3; pk.us[3] = cv.u16;
            *(uint2*)&P[(size_t)ql * 424 + 64 * k4 + lane16 * 4] = pk.u2;
        }
        if (lane16 >= 4 && lane16 < 10) {
            uint2 z2; z2.x = 0; z2.y = 0;
            *(uint2*)&P[(size_t)ql * 424 + 384 + lane16 * 4] = z2;
        }
        #pragma unroll
        for (int off = 8; off; off >>= 1) sum += __shfl_xor(sum, off, 16);
        if (lane16 == 0) invl[ql] = 1.0f / sum;
    }

    half8 afr[13];
    #pragma unroll
    for (int ks = 0; ks < 13; ++ks)
        afr[ks] = *(const half8*)&P[(size_t)(wv * 16 + m16) * 424 + ks * 32 + q4 * 8];
    const ushort_t* fb = fsh + (size_t)b * CH * 416;
    #pragma unroll
    for (int ntl = 0; ntl < 2; ++ntl) {
        const int nt = blockIdx.y * 2 + ntl;
        const int c = nt * 16 + m16;
        const ushort_t* fc = fb + (size_t)c * 416 + q4 * 8;
        f32x4 acc = {};
        #pragma unroll
        for (int ks = 0; ks < 13; ++ks) {
            half8 bf = *(const half8*)(fc + ks * 32);
            acc = __builtin_amdgcn_mfma_f32_16x16x32_f16(afr[ks], bf, acc, 0, 0, 0);
        }
        #pragma unroll
        for (int r = 0; r < 4; ++r) {
            int ql = wv * 16 + q4 * 4 + r;
            int q = qb + ql;
            if (q < HW)
                att[((size_t)b * CH + c) * HW + q] = acc[r] * invl[ql];
        }
    }
}

// ---------------------------------------------------------------------------
// Kernel 6 (v2): fq = l2norm(f_q, ch) + 0.5 * l2norm(att_fq, ch).
// ---------------------------------------------------------------------------
__global__ __launch_bounds__(256) void final_fq(const float* __restrict__ f_q,
                                                const float* __restrict__ att,
                                                float* __restrict__ out_fq) {
    __shared__ float2 red[4];
    int b = blockIdx.y, q = blockIdx.x;
    int tid = threadIdx.x, wv = tid >> 6, lane = tid & 63;
    size_t idx = (size_t)(b * CH + tid) * HW + q;
    float f = f_q[idx];
    float a = att[idx];
    float vf = f * f, va = a * a;
    #pragma unroll
    for (int off = 32; off; off >>= 1) {
        vf += __shfl_xor(vf, off);
        va += __shfl_xor(va, off);
    }
    if (lane == 0) red[wv] = make_float2(vf, va);
    __syncthreads();
    float sf = red[0].x + red[1].x + red[2].x + red[3].x;
    float sa = red[0].y + red[1].y + red[2].y + red[3].y;
    float invf = 1.0f / fmaxf(sqrtf(sf), EPSF);
    float inva = 1.0f / fmaxf(sqrtf(sa), EPSF);
    out_fq[idx] = f * invf + 0.5f * a * inva;
}

// ---------------------------------------------------------------------------
extern "C" void kernel_launch(void* const* d_in, const int* in_sizes, int n_in,
                              void* d_out, int out_size, void* d_ws, size_t ws_size,
                              hipStream_t stream) {
    const float* fq_feats = (const float*)d_in[0];
    const float* fs_feats = (const float*)d_in[1];
    const float* f_q      = (const float*)d_in[2];
    const float* f_s      = (const float*)d_in[3];
    const float* w1       = (const float*)d_in[4];
    const float* w2       = (const float*)d_in[5];
    const float* w3       = (const float*)d_in[6];
    float* out = (float*)d_out;              // fq at 0, att_fq at 204800

    float* ws      = (float*)d_ws;
    float* wbuf    = ws;                     // 115,200 fl: weight tables
    float* ssbuf   = wbuf + 115200;          // 14,400 fl: fused-norm ss
    float* corr    = ssbuf + 14400;          // 2,880,000 fl region
    float* buf1    = corr + 2880000;         // 3,200,000 (At / b1A+b1B)
    float* buf2    = buf1 + 3200000;         // 3,200,000 (Bt / b2A+b2B)
    float* att     = out + 204800;

    ushort_t* corr_h = (ushort_t*)corr;
    ushort_t* fsh    = (ushort_t*)(corr + 1440000);
    float* c4A = corr + 1600000;
    float* c4B = corr + 1920000;
    ushort_t* At = (ushort_t*)buf1;
    ushort_t* Bt = (ushort_t*)buf2;
    ushort_t* b1A = (ushort_t*)buf1;
    ushort_t* b1B = b1A + 3200000;
    ushort_t* b2A = (ushort_t*)buf2;
    ushort_t* b2B = b2A + 3200000;

    ushort_t* wb0   = (ushort_t*)wbuf;
    ushort_t* wbL1A = wb0;
    ushort_t* wbL1B = wb0 + 13824;
    ushort_t* wbL2A = wb0 + 27648;
    ushort_t* wbL2B = wb0 + 41472;
    ushort_t* wbL3Am = wb0 + 55296;
    ushort_t* wbL3Bm = wb0 + 73728;

    prep_all<<<832, 256, 0, stream>>>(w1, w2, w3, f_s, wb0, fsh, ssbuf);

    for (int half = 0; half < 2; ++half) {
        int base = half * 9;
        transpose_f16<<<dim3(16, 7, 18), 256, 0, stream>>>(fq_feats, fs_feats, At, Bt, ssbuf, base);
        corr_gemm_mfma<<<dim3(7, 7, 9), 256, 0, stream>>>(At, Bt, ssbuf, corr_h, base);
    }

    // L1: both paths, one staging (DUAL), 800 blocks x 512 threads
    conv4d_v14<9, 10, true, true><<<dim3(400, NB, 1), 512, 0, stream>>>(
        corr_h, corr_h, wbL1A, wbL1B, b1A, b1B);
    // L2: paths merged via grid-z, 1600 blocks x 512 threads
    conv4d_v14<10, 10, false, true><<<dim3(400, NB, 2), 512, 0, stream>>>(
        b1A, b1B, wbL2A, wbL2B, b2A, b2B);
    // L3: 2-ij merged-N blocks, 800 blocks x 512 threads
    conv4d_l3<10><<<dim3(200, NB, 2), 512, 0, stream>>>(
        b2A, b2B, wbL3Am, wbL3Bm, c4A, c4B);

    softmax_av_mfma2<<<dim3(7, 8, NB), 256, 0, stream>>>(c4A, c4B, fsh, att);
    final_fq<<<dim3(400, NB), 256, 0, stream>>>(f_q, att, out);

    (void)in_sizes; (void)n_in; (void)out_size; (void)ws_size;
}

// Round 8
// 332.176 us; speedup vs baseline: 1.1599x; 1.0151x over previous
//
#include <hip/hip_runtime.h>
#include <math.h>
#include <stddef.h>

#define L9   9
#define NB   2
#define CF   1024
#define HW   400     // 20*20
#define CH   256
#define TEMPF 20.0f
#define EPSF  1e-12f

typedef _Float16 half8 __attribute__((ext_vector_type(8)));
typedef float f32x4 __attribute__((ext_vector_type(4)));
typedef unsigned short ushort_t;

// Zero only the 84 halo rows of the 22x22 (pitch-40-half) A-tile.
// Interior rows are fully rewritten by stagers every chunk.
#define HALO_ZERO(NT)                                                          \
    for (int h = threadIdx.x; h < 84 * 20; h += (NT)) {                        \
        int rs = h / 20, c = h - rs * 20;                                      \
        int row = rs < 22 ? rs                                                 \
                : rs < 44 ? 440 + rs                                           \
                : rs < 64 ? (rs - 43) * 22                                     \
                          : (rs - 63) * 22 + 21;                               \
        ((uint*)Ah)[row * 20 + c] = 0;                                         \
    }

// ---------------------------------------------------------------------------
// Kernel P: ALL prep work in ONE launch (weight tables + fsh + ss zero).
// ---------------------------------------------------------------------------
__global__ __launch_bounds__(256) void prep_all(const float* __restrict__ w1,
                                                const float* __restrict__ w2,
                                                const float* __restrict__ w3,
                                                const float* __restrict__ f_s,
                                                ushort_t* __restrict__ wb0,
                                                ushort_t* __restrict__ fsh,
                                                float* __restrict__ ssbuf) {
    int gid = blockIdx.x * 256 + threadIdx.x;
    if (gid < NB * CH * 416) {
        int s = gid % 416, bc = gid / 416;
        float v = (s < HW) ? f_s[(size_t)bc * HW + s] : 0.f;
        union { _Float16 h; ushort_t u; } cv; cv.h = (_Float16)v;
        fsh[gid] = cv.u;
    }
    if (gid < 14400) ssbuf[gid] = 0.f;
    if (gid < 6 * 18432) {
        int job = gid / 18432, idx = gid - job * 18432;
        int k = idx & 31, n = (idx >> 5) & 15, dd = (idx >> 9) % 9, ch = idx / 4608;
        int dk = dd / 3, dm = dd % 3;
        float v = 0.f;
        if (job < 4) {
            if (idx < 13824) {
                int CIN = (job < 2) ? 9 : 10;
                const float* wt = (job < 2) ? w1 : w2;
                bool swap = job & 1;
                int slot = ch * 32 + k;
                if (n < 10 && slot < CIN * 9) {
                    int ci = slot / 9, pl = slot - ci * 9;
                    int di = pl / 3, dj = pl % 3;
                    int widx = swap ? ((((n * CIN + ci) * 3 + dk) * 3 + dm) * 3 + di) * 3 + dj
                                    : ((((n * CIN + ci) * 3 + di) * 3 + dj) * 3 + dk) * 3 + dm;
                    v = wt[widx];
                }
                union { _Float16 h; ushort_t u; } cv; cv.h = (_Float16)v;
                wb0[job * 13824 + idx] = cv.u;
            }
        } else {
            bool swap = (job == 5);
            int slot = ch * 32 + k;
            if (slot < 120) {
                int ci = slot / 12, r = slot - ci * 12;
                int di = r >> 2, dj4 = r & 3;
                int e = dj4 - n;
                if (n < 2 && e >= 0 && e <= 2) {
                    int widx = swap ? (((ci * 3 + dk) * 3 + dm) * 3 + di) * 3 + e
                                    : (((ci * 3 + di) * 3 + e) * 3 + dk) * 3 + dm;
                    v = w3[widx];
                }
            }
            union { _Float16 h; ushort_t u; } cv; cv.h = (_Float16)v;
            wb0[55296 + (job - 4) * 18432 + idx] = cv.u;
        }
    }
}

// ---------------------------------------------------------------------------
// Kernel 3a (v2): transpose+convert WITH FUSED NORM PARTIALS.
// ---------------------------------------------------------------------------
__global__ __launch_bounds__(256) void transpose_f16(const float* __restrict__ fq,
                                                     const float* __restrict__ fs,
                                                     ushort_t* __restrict__ At,
                                                     ushort_t* __restrict__ Bt,
                                                     float* __restrict__ ssbuf,
                                                     int lb_base) {
    __shared__ float tile[64][65];
    __shared__ float red4[4][64];
    int z = blockIdx.z;
    int tsel = z / 9, li = z - tsel * 9;
    int lb = lb_base + li;
    const float* src = (tsel ? fs : fq) + (size_t)lb * CF * HW;
    ushort_t* dst = (tsel ? Bt : At) + (size_t)li * HW * CF;
    int c0 = blockIdx.x * 64, ij0 = blockIdx.y * 64;
    int tid = threadIdx.x;
    int cl = tid >> 6;
    int col = tid & 63;
    float ssp = 0.f;
    #pragma unroll
    for (int rr = 0; rr < 16; ++rr) {
        int c_local = rr * 4 + cl;
        int ij = ij0 + col;
        float v = (ij < HW) ? src[(size_t)(c0 + c_local) * HW + ij] : 0.f;
        tile[c_local][col] = v;
        ssp = fmaf(v, v, ssp);
    }
    red4[cl][col] = ssp;
    __syncthreads();
    if (cl == 0) {
        int ij = ij0 + col;
        if (ij < HW) {
            float s4 = red4[0][col] + red4[1][col] + red4[2][col] + red4[3][col];
            atomicAdd(&ssbuf[(size_t)(tsel * 18 + lb) * HW + ij], s4);
        }
    }
    int cp = (tid & 31) * 2;
    int rowsel = tid >> 5;
    #pragma unroll
    for (int rr = 0; rr < 8; ++rr) {
        int ij_local = rr * 8 + rowsel;
        int ij = ij0 + ij_local;
        if (ij < HW) {
            union { _Float16 h; ushort_t u; } h0, h1;
            h0.h = (_Float16)tile[cp][ij_local];
            h1.h = (_Float16)tile[cp + 1][ij_local];
            ushort2 o; o.x = h0.u; o.y = h1.u;
            *(ushort2*)(dst + (size_t)ij * CF + c0 + cp) = o;
        }
    }
}

// ---------------------------------------------------------------------------
// Kernel 3b: MFMA fp16 correlation GEMM; inverse norms in epilogue from ss.
// ---------------------------------------------------------------------------
__global__ __launch_bounds__(256) void corr_gemm_mfma(const ushort_t* __restrict__ At,
                                                      const ushort_t* __restrict__ Bt,
                                                      const float* __restrict__ ssbuf,
                                                      ushort_t* __restrict__ corr,
                                                      int lb_base) {
    __shared__ ushort_t As[64][72];
    __shared__ ushort_t Bs[64][72];
    int li = blockIdx.z, lb = lb_base + li;
    int l = lb >> 1, b = lb & 1;
    int i0 = blockIdx.y * 64, j0 = blockIdx.x * 64;
    int tid = threadIdx.x, lane = tid & 63, w = tid >> 6;
    int mw = (w >> 1) * 32, nw = (w & 1) * 32;
    f32x4 acc[2][2] = {};
    const ushort_t* Abase = At + (size_t)li * HW * CF;
    const ushort_t* Bbase = Bt + (size_t)li * HW * CF;

    for (int kt = 0; kt < 16; ++kt) {
        int c0 = kt * 64;
        __syncthreads();
        #pragma unroll
        for (int p = 0; p < 2; ++p) {
            int idx = tid + p * 256;
            int row = idx >> 3, c8 = idx & 7;
            uint4 va = make_uint4(0, 0, 0, 0), vb = make_uint4(0, 0, 0, 0);
            if (i0 + row < HW) va = *(const uint4*)(Abase + (size_t)(i0 + row) * CF + c0 + c8 * 8);
            if (j0 + row < HW) vb = *(const uint4*)(Bbase + (size_t)(j0 + row) * CF + c0 + c8 * 8);
            *(uint4*)&As[row][c8 * 8] = va;
            *(uint4*)&Bs[row][c8 * 8] = vb;
        }
        __syncthreads();
        #pragma unroll
        for (int ks = 0; ks < 2; ++ks) {
            int k0 = ks * 32 + (lane >> 4) * 8;
            half8 a0 = *(const half8*)&As[mw + (lane & 15)][k0];
            half8 a1 = *(const half8*)&As[mw + 16 + (lane & 15)][k0];
            half8 b0 = *(const half8*)&Bs[nw + (lane & 15)][k0];
            half8 b1 = *(const half8*)&Bs[nw + 16 + (lane & 15)][k0];
            acc[0][0] = __builtin_amdgcn_mfma_f32_16x16x32_f16(a0, b0, acc[0][0], 0, 0, 0);
            acc[0][1] = __builtin_amdgcn_mfma_f32_16x16x32_f16(a0, b1, acc[0][1], 0, 0, 0);
            acc[1][0] = __builtin_amdgcn_mfma_f32_16x16x32_f16(a1, b0, acc[1][0], 0, 0, 0);
            acc[1][1] = __builtin_amdgcn_mfma_f32_16x16x32_f16(a1, b1, acc[1][1], 0, 0, 0);
        }
    }
    int obase = (b * 9 + l) * HW;
    #pragma unroll
    for (int ni = 0; ni < 2; ++ni) {
        int km = j0 + nw + ni * 16 + (lane & 15);
        if (km >= HW) continue;
        float ib = 1.0f / fmaxf(sqrtf(ssbuf[(size_t)(18 + lb) * HW + km]), EPSF);
        #pragma unroll
        for (int mi = 0; mi < 2; ++mi) {
            #pragma unroll
            for (int r = 0; r < 4; ++r) {
                int ij = i0 + mw + mi * 16 + (lane >> 4) * 4 + r;
                if (ij < HW) {
                    float ia = 1.0f / fmaxf(sqrtf(ssbuf[(size_t)lb * HW + ij]), EPSF);
                    union { _Float16 h; ushort_t u; } cv;
                    cv.h = (_Float16)(acc[mi][ni][r] * ia * ib);
                    corr[(size_t)(obase + ij) * HW + km] = cv.u;
                }
            }
        }
    }
}

// ---------------------------------------------------------------------------
// Kernel 4 (v8h): 256-thread conv, proven 62us structure + halo-only zero.
// Used for L2 (1600 blocks: block-rich regime where 256t spill-free wins).
// ---------------------------------------------------------------------------
template <int CIN, int COUT, bool DUAL, bool OUTF16>
__global__ __launch_bounds__(256) void conv4d_v8h(const ushort_t* __restrict__ inA,
                                                  const ushort_t* __restrict__ inB,
                                                  const ushort_t* __restrict__ wbA,
                                                  const ushort_t* __restrict__ wbB,
                                                  void* __restrict__ outA,
                                                  void* __restrict__ outB) {
    constexpr int S = CIN * 9;
    constexpr int NCH = (S + 31) / 32;
    __shared__ __align__(16) ushort_t Ah[484 * 40];
    const int b = blockIdx.y, ij = blockIdx.x;
    const int z = blockIdx.z;
    const ushort_t* in = (DUAL || z == 0) ? inA : inB;
    const ushort_t* wbS = (DUAL || z == 0) ? wbA : wbB;
    void* outS = (DUAL || z == 0) ? outA : outB;
    const int i = ij / 20, j = ij - (ij / 20) * 20;
    const int tid = threadIdx.x, wv = tid >> 6, lane = tid & 63;
    const int m16 = lane & 15, q4 = lane >> 4;

    HALO_ZERO(256)

    int baseh[7];
    #pragma unroll
    for (int s = 0; s < 7; ++s) {
        int t = wv + 4 * s;
        if (t < 25) {
            int km = t * 16 + m16;
            int kk = km / 20, mm = km - kk * 20;
            baseh[s] = (kk * 22 + mm) * 40 + q4 * 8;
        } else baseh[s] = 0;
    }
    f32x4 accA[7] = {};
    f32x4 accB[7] = {};

    const bool stager = tid < 200;
    const int km1 = 2 * tid;
    const int r1 = stager ? ((km1 / 20 + 1) * 22 + (km1 % 20) + 1) : 0;
    int hofs[9]; bool vld[9];
    #pragma unroll
    for (int pl = 0; pl < 9; ++pl) {
        int ii = i + pl / 3 - 1, jj = j + pl % 3 - 1;
        vld[pl] = (unsigned)ii < 20u && (unsigned)jj < 20u;
        hofs[pl] = (ii * 20 + jj) * HW + km1;
    }
    const ushort_t* in_b = in + (size_t)b * CIN * HW * HW;
    const int wbase = m16 * 32 + q4 * 8;

    uint pf[32];
    #pragma unroll
    for (int u = 0; u < 32; ++u) {
        int slot = u;
        if (slot < S) {
            int ci = slot / 9, pl = slot - ci * 9;
            pf[u] = (stager && vld[pl]) ? *(const uint*)(in_b + ci * (HW * HW) + hofs[pl]) : 0u;
        } else pf[u] = 0u;
    }
    __syncthreads();

    #pragma unroll
    for (int ch = 0; ch < NCH; ++ch) {
        if (stager) {
            #pragma unroll
            for (int g4 = 0; g4 < 8; ++g4) {
                uint lo0 = (pf[4 * g4] & 0xFFFFu) | (pf[4 * g4 + 1] << 16);
                uint lo1 = (pf[4 * g4 + 2] & 0xFFFFu) | (pf[4 * g4 + 3] << 16);
                uint hi0 = (pf[4 * g4] >> 16) | (pf[4 * g4 + 1] & 0xFFFF0000u);
                uint hi1 = (pf[4 * g4 + 2] >> 16) | (pf[4 * g4 + 3] & 0xFFFF0000u);
                uint2 wlo; wlo.x = lo0; wlo.y = lo1;
                uint2 whi; whi.x = hi0; whi.y = hi1;
                *(uint2*)&Ah[(size_t)r1 * 40 + 4 * g4] = wlo;
                *(uint2*)&Ah[(size_t)(r1 + 1) * 40 + 4 * g4] = whi;
            }
        }
        __syncthreads();
        if (ch + 1 < NCH) {
            #pragma unroll
            for (int u = 0; u < 32; ++u) {
                int slot = (ch + 1) * 32 + u;
                if (slot < S) {
                    int ci = slot / 9, pl = slot - ci * 9;
                    pf[u] = (stager && vld[pl]) ? *(const uint*)(in_b + ci * (HW * HW) + hofs[pl]) : 0u;
                } else pf[u] = 0u;
            }
        }
        #pragma unroll
        for (int dd = 0; dd < 9; ++dd) {
            half8 bfA = *(const half8*)(wbS + (ch * 9 + dd) * 512 + wbase);
            half8 bfB;
            if (DUAL) bfB = *(const half8*)(wbB + (ch * 9 + dd) * 512 + wbase);
            const int doff = ((dd / 3) * 22 + (dd % 3)) * 40;
            #pragma unroll
            for (int s = 0; s < 7; ++s) {
                if (wv + 4 * s < 25) {
                    half8 af = *(const half8*)(Ah + baseh[s] + doff);
                    accA[s] = __builtin_amdgcn_mfma_f32_16x16x32_f16(af, bfA, accA[s], 0, 0, 0);
                    if (DUAL) accB[s] = __builtin_amdgcn_mfma_f32_16x16x32_f16(af, bfB, accB[s], 0, 0, 0);
                }
            }
        }
        if (ch + 1 < NCH) __syncthreads();
    }

    const int co = m16;
    if (co < COUT) {
        #pragma unroll
        for (int s = 0; s < 7; ++s) {
            int t = wv + 4 * s;
            if (t < 25) {
                int km0 = t * 16 + q4 * 4;
                size_t o = ((size_t)(b * COUT + co) * HW + ij) * HW + km0;
                if (OUTF16) {
                    union { ushort_t us[4]; uint2 u2; } pk;
                    #pragma unroll
                    for (int r = 0; r < 4; ++r) {
                        union { _Float16 h; ushort_t u16; } cv;
                        cv.h = (_Float16)fmaxf(accA[s][r], 0.f);
                        pk.us[r] = cv.u16;
                    }
                    *(uint2*)((ushort_t*)outS + o) = pk.u2;
                    if (DUAL) {
                        #pragma unroll
                        for (int r = 0; r < 4; ++r) {
                            union { _Float16 h; ushort_t u16; } cv;
                            cv.h = (_Float16)fmaxf(accB[s][r], 0.f);
                            pk.us[r] = cv.u16;
                        }
                        *(uint2*)((ushort_t*)outB + o) = pk.u2;
                    }
                } else {
                    f32x4 ov;
                    #pragma unroll
                    for (int r = 0; r < 4; ++r) ov[r] = fmaxf(accA[s][r], 0.f);
                    *(f32x4*)((float*)outS + o) = ov;
                }
            }
        }
    }
}

// ---------------------------------------------------------------------------
// Kernel 4 (v14h): 512-thread conv for the block-poor dispatches (L1: 800
// blocks). 8 waves/block doubles waves/CU where block count limits TLP.
// ---------------------------------------------------------------------------
template <int CIN, int COUT, bool DUAL, bool OUTF16>
__global__ __launch_bounds__(512, 2) void conv4d_v14h(const ushort_t* __restrict__ inA,
                                                      const ushort_t* __restrict__ inB,
                                                      const ushort_t* __restrict__ wbA,
                                                      const ushort_t* __restrict__ wbB,
                                                      void* __restrict__ outA,
                                                      void* __restrict__ outB) {
    constexpr int S = CIN * 9;
    constexpr int NCH = (S + 31) / 32;
    __shared__ __align__(16) ushort_t Ah[484 * 40];
    const int b = blockIdx.y, ij = blockIdx.x;
    const int z = blockIdx.z;
    const ushort_t* in = (DUAL || z == 0) ? inA : inB;
    const ushort_t* wbS = (DUAL || z == 0) ? wbA : wbB;
    void* outS = (DUAL || z == 0) ? outA : outB;
    const int i = ij / 20, j = ij - (ij / 20) * 20;
    const int tid = threadIdx.x, wv = tid >> 6, lane = tid & 63;
    const int m16 = lane & 15, q4 = lane >> 4;
    const int wt = 7 - wv;

    HALO_ZERO(512)

    int baseh[4];
    #pragma unroll
    for (int s = 0; s < 4; ++s) {
        int t = wt + 8 * s;
        if (t < 25) {
            int km = t * 16 + m16;
            int kk = km / 20, mm = km - kk * 20;
            baseh[s] = (kk * 22 + mm) * 40 + q4 * 8;
        } else baseh[s] = 0;
    }
    f32x4 accA[4] = {};
    f32x4 accB[4] = {};

    const bool stager = tid < 200;
    const int km1 = 2 * tid;
    const int r1 = stager ? ((km1 / 20 + 1) * 22 + (km1 % 20) + 1) : 0;
    int hofs[9]; bool vld[9];
    #pragma unroll
    for (int pl = 0; pl < 9; ++pl) {
        int ii = i + pl / 3 - 1, jj = j + pl % 3 - 1;
        vld[pl] = (unsigned)ii < 20u && (unsigned)jj < 20u;
        hofs[pl] = (ii * 20 + jj) * HW + km1;
    }
    const ushort_t* in_b = in + (size_t)b * CIN * HW * HW;
    const int wbase = m16 * 32 + q4 * 8;

    uint pf[32];
    #pragma unroll
    for (int u = 0; u < 32; ++u) {
        int slot = u;
        if (slot < S) {
            int ci = slot / 9, pl = slot - ci * 9;
            pf[u] = (stager && vld[pl]) ? *(const uint*)(in_b + ci * (HW * HW) + hofs[pl]) : 0u;
        } else pf[u] = 0u;
    }
    __syncthreads();

    #pragma unroll
    for (int ch = 0; ch < NCH; ++ch) {
        if (stager) {
            #pragma unroll
            for (int g4 = 0; g4 < 8; ++g4) {
                uint lo0 = (pf[4 * g4] & 0xFFFFu) | (pf[4 * g4 + 1] << 16);
                uint lo1 = (pf[4 * g4 + 2] & 0xFFFFu) | (pf[4 * g4 + 3] << 16);
                uint hi0 = (pf[4 * g4] >> 16) | (pf[4 * g4 + 1] & 0xFFFF0000u);
                uint hi1 = (pf[4 * g4 + 2] >> 16) | (pf[4 * g4 + 3] & 0xFFFF0000u);
                uint2 wlo; wlo.x = lo0; wlo.y = lo1;
                uint2 whi; whi.x = hi0; whi.y = hi1;
                *(uint2*)&Ah[(size_t)r1 * 40 + 4 * g4] = wlo;
                *(uint2*)&Ah[(size_t)(r1 + 1) * 40 + 4 * g4] = whi;
            }
        }
        __syncthreads();
        if (ch + 1 < NCH) {
            #pragma unroll
            for (int u = 0; u < 32; ++u) {
                int slot = (ch + 1) * 32 + u;
                if (slot < S) {
                    int ci = slot / 9, pl = slot - ci * 9;
                    pf[u] = (stager && vld[pl]) ? *(const uint*)(in_b + ci * (HW * HW) + hofs[pl]) : 0u;
                } else pf[u] = 0u;
            }
        }
        #pragma unroll
        for (int dd = 0; dd < 9; ++dd) {
            half8 bfA = *(const half8*)(wbS + (ch * 9 + dd) * 512 + wbase);
            half8 bfB;
            if (DUAL) bfB = *(const half8*)(wbB + (ch * 9 + dd) * 512 + wbase);
            const int doff = ((dd / 3) * 22 + (dd % 3)) * 40;
            #pragma unroll
            for (int s = 0; s < 4; ++s) {
                if (wt + 8 * s < 25) {
                    half8 af = *(const half8*)(Ah + baseh[s] + doff);
                    accA[s] = __builtin_amdgcn_mfma_f32_16x16x32_f16(af, bfA, accA[s], 0, 0, 0);
                    if (DUAL) accB[s] = __builtin_amdgcn_mfma_f32_16x16x32_f16(af, bfB, accB[s], 0, 0, 0);
                }
            }
        }
        if (ch + 1 < NCH) __syncthreads();
    }

    const int co = m16;
    if (co < COUT) {
        #pragma unroll
        for (int s = 0; s < 4; ++s) {
            int t = wt + 8 * s;
            if (t < 25) {
                int km0 = t * 16 + q4 * 4;
                size_t o = ((size_t)(b * COUT + co) * HW + ij) * HW + km0;
                if (OUTF16) {
                    union { ushort_t us[4]; uint2 u2; } pk;
                    #pragma unroll
                    for (int r = 0; r < 4; ++r) {
                        union { _Float16 h; ushort_t u16; } cv;
                        cv.h = (_Float16)fmaxf(accA[s][r], 0.f);
                        pk.us[r] = cv.u16;
                    }
                    *(uint2*)((ushort_t*)outS + o) = pk.u2;
                    if (DUAL) {
                        #pragma unroll
                        for (int r = 0; r < 4; ++r) {
                            union { _Float16 h; ushort_t u16; } cv;
                            cv.h = (_Float16)fmaxf(accB[s][r], 0.f);
                            pk.us[r] = cv.u16;
                        }
                        *(uint2*)((ushort_t*)outB + o) = pk.u2;
                    }
                } else {
                    f32x4 ov;
                    #pragma unroll
                    for (int r = 0; r < 4; ++r) ov[r] = fmaxf(accA[s][r], 0.f);
                    *(f32x4*)((float*)outS + o) = ov;
                }
            }
        }
    }
}

// ---------------------------------------------------------------------------
// Kernel 4b (L3): 2-ij merged-N conv, 512 threads (800-block dispatch).
// ---------------------------------------------------------------------------
template <int CIN>
__global__ __launch_bounds__(512, 2) void conv4d_l3(
        const ushort_t* __restrict__ inA, const ushort_t* __restrict__ inB,
        const ushort_t* __restrict__ wAm, const ushort_t* __restrict__ wBm,
        float* __restrict__ outA, float* __restrict__ outB) {
    constexpr int S2 = CIN * 12;
    constexpr int NCH = (S2 + 31) / 32;
    __shared__ __align__(16) ushort_t Ah[484 * 40];
    const int b = blockIdx.y, bx = blockIdx.x, z = blockIdx.z;
    const ushort_t* in = z ? inB : inA;
    const ushort_t* w1 = z ? wBm : wAm;
    float* outS = z ? outB : outA;
    const int i = bx / 10, jp = bx - (bx / 10) * 10;
    const int j0 = 2 * jp;
    const int ij0 = i * 20 + j0;
    const int tid = threadIdx.x, wv = tid >> 6, lane = tid & 63;
    const int m16 = lane & 15, q4 = lane >> 4;
    const int wt = 7 - wv;

    HALO_ZERO(512)

    int baseh[4];
    #pragma unroll
    for (int s = 0; s < 4; ++s) {
        int t = wt + 8 * s;
        if (t < 25) {
            int km = t * 16 + m16;
            int kk = km / 20, mm = km - kk * 20;
            baseh[s] = (kk * 22 + mm) * 40 + q4 * 8;
        } else baseh[s] = 0;
    }
    f32x4 acc1[4] = {};

    const bool stager = tid < 200;
    const int km1 = 2 * tid;
    const int r1 = stager ? ((km1 / 20 + 1) * 22 + (km1 % 20) + 1) : 0;
    int hofs[12]; bool vld[12];
    #pragma unroll
    for (int pl = 0; pl < 12; ++pl) {
        int di = pl >> 2, dj = pl & 3;
        int ii = i + di - 1, jj = j0 + dj - 1;
        vld[pl] = (unsigned)ii < 20u && (unsigned)jj < 20u;
        hofs[pl] = (ii * 20 + jj) * HW + km1;
    }
    const ushort_t* in_b = in + (size_t)b * CIN * HW * HW;
    const int wbase = m16 * 32 + q4 * 8;

    uint pf[32];
    #pragma unroll
    for (int u = 0; u < 32; ++u) {
        int slot = u;
        if (slot < S2) {
            int ci = slot / 12, pl = slot - ci * 12;
            pf[u] = (stager && vld[pl]) ? *(const uint*)(in_b + ci * (HW * HW) + hofs[pl]) : 0u;
        } else pf[u] = 0u;
    }
    __syncthreads();

    #pragma unroll
    for (int ch = 0; ch < NCH; ++ch) {
        if (stager) {
            #pragma unroll
            for (int g4 = 0; g4 < 8; ++g4) {
                uint lo0 = (pf[4 * g4] & 0xFFFFu) | (pf[4 * g4 + 1] << 16);
                uint lo1 = (pf[4 * g4 + 2] & 0xFFFFu) | (pf[4 * g4 + 3] << 16);
                uint hi0 = (pf[4 * g4] >> 16) | (pf[4 * g4 + 1] & 0xFFFF0000u);
                uint hi1 = (pf[4 * g4 + 2] >> 16) | (pf[4 * g4 + 3] & 0xFFFF0000u);
                uint2 wlo; wlo.x = lo0; wlo.y = lo1;
                uint2 whi; whi.x = hi0; whi.y = hi1;
                *(uint2*)&Ah[(size_t)r1 * 40 + 4 * g4] = wlo;
                *(uint2*)&Ah[(size_t)(r1 + 1) * 40 + 4 * g4] = whi;
            }
        }
        __syncthreads();
        if (ch + 1 < NCH) {
            #pragma unroll
            for (int u = 0; u < 32; ++u) {
                int slot = (ch + 1) * 32 + u;
                if (slot < S2) {
                    int ci = slot / 12, pl = slot - ci * 12;
                    pf[u] = (stager && vld[pl]) ? *(const uint*)(in_b + ci * (HW * HW) + hofs[pl]) : 0u;
                } else pf[u] = 0u;
            }
        }
        #pragma unroll
        for (int dd = 0; dd < 9; ++dd) {
            half8 bf1 = *(const half8*)(w1 + (ch * 9 + dd) * 512 + wbase);
            const int doff = ((dd / 3) * 22 + (dd % 3)) * 40;
            #pragma unroll
            for (int s = 0; s < 4; ++s) {
                if (wt + 8 * s < 25) {
                    half8 af = *(const half8*)(Ah + baseh[s] + doff);
                    acc1[s] = __builtin_amdgcn_mfma_f32_16x16x32_f16(af, bf1, acc1[s], 0, 0, 0);
                }
            }
        }
        if (ch + 1 < NCH) __syncthreads();
    }

    if (m16 < 2) {
        const int ij = ij0 + m16;
        #pragma unroll
        for (int s = 0; s < 4; ++s) {
            int t = wt + 8 * s;
            if (t < 25) {
                int km0 = t * 16 + q4 * 4;
                size_t o = ((size_t)b * HW + ij) * HW + km0;
                f32x4 ov;
                #pragma unroll
                for (int r = 0; r < 4; ++r) ov[r] = fmaxf(acc1[s][r], 0.f);
                *(f32x4*)(outS + o) = ov;
            }
        }
    }
}

// ---------------------------------------------------------------------------
// Kernel 5 (v3): softmax + attn.V via MFMA, summing the two L3 path outputs.
// ---------------------------------------------------------------------------
__global__ __launch_bounds__(256) void softmax_av_mfma2(const float* __restrict__ c4A,
                                                        const float* __restrict__ c4B,
                                                        const ushort_t* __restrict__ fsh,
                                                        float* __restrict__ att) {
    __shared__ ushort_t P[64 * 424];
    __shared__ float invl[64];
    const int b = blockIdx.z, qb = blockIdx.x * 64;
    const int tid = threadIdx.x, wv = tid >> 6, lane = tid & 63;
    const int m16 = lane & 15, q4 = lane >> 4;
    const int lane16 = lane & 15, rg4 = lane >> 4;

    #pragma unroll 1
    for (int rg = 0; rg < 4; ++rg) {
        const int ql = wv * 16 + rg * 4 + rg4;
        int q = qb + ql; if (q > HW - 1) q = HW - 1;
        const float* rowA = c4A + ((size_t)b * HW + q) * HW;
        const float* rowB = c4B + ((size_t)b * HW + q) * HW;
        float4 v4[7];
        #pragma unroll
        for (int k4 = 0; k4 < 6; ++k4) {
            float4 a4 = *(const float4*)(rowA + 64 * k4 + lane16 * 4);
            float4 b4 = *(const float4*)(rowB + 64 * k4 + lane16 * 4);
            v4[k4] = make_float4(a4.x + b4.x, a4.y + b4.y, a4.z + b4.z, a4.w + b4.w);
        }
        if (lane16 < 4) {
            float4 a4 = *(const float4*)(rowA + 384 + lane16 * 4);
            float4 b4 = *(const float4*)(rowB + 384 + lane16 * 4);
            v4[6] = make_float4(a4.x + b4.x, a4.y + b4.y, a4.z + b4.z, a4.w + b4.w);
        } else {
            v4[6] = make_float4(-1e30f, -1e30f, -1e30f, -1e30f);
        }
        float mx = -1e30f;
        #pragma unroll
        for (int k4 = 0; k4 < 7; ++k4)
            mx = fmaxf(mx, fmaxf(fmaxf(v4[k4].x, v4[k4].y), fmaxf(v4[k4].z, v4[k4].w)));
        #pragma unroll
        for (int off = 8; off; off >>= 1) mx = fmaxf(mx, __shfl_xor(mx, off, 16));
        float sum = 0.f;
        #pragma unroll
        for (int k4 = 0; k4 < 7; ++k4) {
            if (k4 == 6 && lane16 >= 4) break;
            float e0 = __expf(TEMPF * (v4[k4].x - mx));
            float e1 = __expf(TEMPF * (v4[k4].y - mx));
            float e2 = __expf(TEMPF * (v4[k4].z - mx));
            float e3 = __expf(TEMPF * (v4[k4].w - mx));
            sum += e0 + e1 + e2 + e3;
            union { ushort_t us[4]; uint2 u2; } pk;
            union { _Float16 h; ushort_t u16; } cv;
            cv.h = (_Float16)e0; pk.us[0] = cv.u16;
            cv.h = (_Float16)e1; pk.us[1] = cv.u16;
            cv.h = (_Float16)e2; pk.us[2] = cv.u16;
            cv.h = (_Float16)e3; pk.us[3] = cv.u16;
            *(uint2*)&P[(size_t)ql * 424 + 64 * k4 + lane16 * 4] = pk.u2;
        }
        if (lane16 >= 4 && lane16 < 10) {
            uint2 z2; z2.x = 0; z2.y = 0;
            *(uint2*)&P[(size_t)ql * 424 + 384 + lane16 * 4] = z2;
        }
        #pragma unroll
        for (int off = 8; off; off >>= 1) sum += __shfl_xor(sum, off, 16);
        if (lane16 == 0) invl[ql] = 1.0f / sum;
    }

    half8 afr[13];
    #pragma unroll
    for (int ks = 0; ks < 13; ++ks)
        afr[ks] = *(const half8*)&P[(size_t)(wv * 16 + m16) * 424 + ks * 32 + q4 * 8];
    const ushort_t* fb = fsh + (size_t)b * CH * 416;
    #pragma unroll
    for (int ntl = 0; ntl < 2; ++ntl) {
        const int nt = blockIdx.y * 2 + ntl;
        const int c = nt * 16 + m16;
        const ushort_t* fc = fb + (size_t)c * 416 + q4 * 8;
        f32x4 acc = {};
        #pragma unroll
        for (int ks = 0; ks < 13; ++ks) {
            half8 bf = *(const half8*)(fc + ks * 32);
            acc = __builtin_amdgcn_mfma_f32_16x16x32_f16(afr[ks], bf, acc, 0, 0, 0);
        }
        #pragma unroll
        for (int r = 0; r < 4; ++r) {
            int ql = wv * 16 + q4 * 4 + r;
            int q = qb + ql;
            if (q < HW)
                att[((size_t)b * CH + c) * HW + q] = acc[r] * invl[ql];
        }
    }
}

// ---------------------------------------------------------------------------
// Kernel 6 (v2): fq = l2norm(f_q, ch) + 0.5 * l2norm(att_fq, ch).
// ---------------------------------------------------------------------------
__global__ __launch_bounds__(256) void final_fq(const float* __restrict__ f_q,
                                                const float* __restrict__ att,
                                                float* __restrict__ out_fq) {
    __shared__ float2 red[4];
    int b = blockIdx.y, q = blockIdx.x;
    int tid = threadIdx.x, wv = tid >> 6, lane = tid & 63;
    size_t idx = (size_t)(b * CH + tid) * HW + q;
    float f = f_q[idx];
    float a = att[idx];
    float vf = f * f, va = a * a;
    #pragma unroll
    for (int off = 32; off; off >>= 1) {
        vf += __shfl_xor(vf, off);
        va += __shfl_xor(va, off);
    }
    if (lane == 0) red[wv] = make_float2(vf, va);
    __syncthreads();
    float sf = red[0].x + red[1].x + red[2].x + red[3].x;
    float sa = red[0].y + red[1].y + red[2].y + red[3].y;
    float invf = 1.0f / fmaxf(sqrtf(sf), EPSF);
    float inva = 1.0f / fmaxf(sqrtf(sa), EPSF);
    out_fq[idx] = f * invf + 0.5f * a * inva;
}

// ---------------------------------------------------------------------------
extern "C" void kernel_launch(void* const* d_in, const int* in_sizes, int n_in,
                              void* d_out, int out_size, void* d_ws, size_t ws_size,
                              hipStream_t stream) {
    const float* fq_feats = (const float*)d_in[0];
    const float* fs_feats = (const float*)d_in[1];
    const float* f_q      = (const float*)d_in[2];
    const float* f_s      = (const float*)d_in[3];
    const float* w1       = (const float*)d_in[4];
    const float* w2       = (const float*)d_in[5];
    const float* w3       = (const float*)d_in[6];
    float* out = (float*)d_out;              // fq at 0, att_fq at 204800

    float* ws      = (float*)d_ws;
    float* wbuf    = ws;                     // 115,200 fl: weight tables
    float* ssbuf   = wbuf + 115200;          // 14,400 fl: fused-norm ss
    float* corr    = ssbuf + 14400;          // 2,880,000 fl region
    float* buf1    = corr + 2880000;         // 3,200,000 (At / b1A+b1B)
    float* buf2    = buf1 + 3200000;         // 3,200,000 (Bt / b2A+b2B)
    float* att     = out + 204800;

    ushort_t* corr_h = (ushort_t*)corr;
    ushort_t* fsh    = (ushort_t*)(corr + 1440000);
    float* c4A = corr + 1600000;
    float* c4B = corr + 1920000;
    ushort_t* At = (ushort_t*)buf1;
    ushort_t* Bt = (ushort_t*)buf2;
    ushort_t* b1A = (ushort_t*)buf1;
    ushort_t* b1B = b1A + 3200000;
    ushort_t* b2A = (ushort_t*)buf2;
    ushort_t* b2B = b2A + 3200000;

    ushort_t* wb0   = (ushort_t*)wbuf;
    ushort_t* wbL1A = wb0;
    ushort_t* wbL1B = wb0 + 13824;
    ushort_t* wbL2A = wb0 + 27648;
    ushort_t* wbL2B = wb0 + 41472;
    ushort_t* wbL3Am = wb0 + 55296;
    ushort_t* wbL3Bm = wb0 + 73728;

    prep_all<<<832, 256, 0, stream>>>(w1, w2, w3, f_s, wb0, fsh, ssbuf);

    for (int half = 0; half < 2; ++half) {
        int base = half * 9;
        transpose_f16<<<dim3(16, 7, 18), 256, 0, stream>>>(fq_feats, fs_feats, At, Bt, ssbuf, base);
        corr_gemm_mfma<<<dim3(7, 7, 9), 256, 0, stream>>>(At, Bt, ssbuf, corr_h, base);
    }

    // L1: 800 blocks (block-poor) -> 512 threads
    conv4d_v14h<9, 10, true, true><<<dim3(400, NB, 1), 512, 0, stream>>>(
        corr_h, corr_h, wbL1A, wbL1B, b1A, b1B);
    // L2: 1600 blocks (block-rich) -> 256 threads, proven v8 structure
    conv4d_v8h<10, 10, false, true><<<dim3(400, NB, 2), 256, 0, stream>>>(
        b1A, b1B, wbL2A, wbL2B, b2A, b2B);
    // L3: 800 blocks 2-ij merged-N -> 512 threads
    conv4d_l3<10><<<dim3(200, NB, 2), 512, 0, stream>>>(
        b2A, b2B, wbL3Am, wbL3Bm, c4A, c4B);

    softmax_av_mfma2<<<dim3(7, 8, NB), 256, 0, stream>>>(c4A, c4B, fsh, att);
    final_fq<<<dim3(400, NB), 256, 0, stream>>>(f_q, att, out);

    (void)in_sizes; (void)n_in; (void)out_size; (void)ws_size;
}

// Round 9
// 331.229 us; speedup vs baseline: 1.1633x; 1.0029x over previous
//
#include <hip/hip_runtime.h>
#include <math.h>
#include <stddef.h>

#define L9   9
#define NB   2
#define CF   1024
#define HW   400     // 20*20
#define CH   256
#define TEMPF 20.0f
#define EPSF  1e-12f

typedef _Float16 half8 __attribute__((ext_vector_type(8)));
typedef float f32x4 __attribute__((ext_vector_type(4)));
typedef unsigned short ushort_t;

// Zero only the 84 halo rows of the 22x22 (pitch-40-half) A-tile.
#define HALO_ZERO(NT)                                                          \
    for (int h = threadIdx.x; h < 84 * 20; h += (NT)) {                        \
        int rs = h / 20, c = h - rs * 20;                                      \
        int row = rs < 22 ? rs                                                 \
                : rs < 44 ? 440 + rs                                           \
                : rs < 64 ? (rs - 43) * 22                                     \
                          : (rs - 63) * 22 + 21;                               \
        ((uint*)Ah)[row * 20 + c] = 0;                                         \
    }

// ---------------------------------------------------------------------------
// Kernel P: ALL prep work in ONE launch (weight tables + fsh + ss zero).
// ---------------------------------------------------------------------------
__global__ __launch_bounds__(256) void prep_all(const float* __restrict__ w1,
                                                const float* __restrict__ w2,
                                                const float* __restrict__ w3,
                                                const float* __restrict__ f_s,
                                                ushort_t* __restrict__ wb0,
                                                ushort_t* __restrict__ fsh,
                                                float* __restrict__ ssbuf) {
    int gid = blockIdx.x * 256 + threadIdx.x;
    if (gid < NB * CH * 416) {
        int s = gid % 416, bc = gid / 416;
        float v = (s < HW) ? f_s[(size_t)bc * HW + s] : 0.f;
        union { _Float16 h; ushort_t u; } cv; cv.h = (_Float16)v;
        fsh[gid] = cv.u;
    }
    if (gid < 14400) ssbuf[gid] = 0.f;
    if (gid < 6 * 18432) {
        int job = gid / 18432, idx = gid - job * 18432;
        int k = idx & 31, n = (idx >> 5) & 15, dd = (idx >> 9) % 9, ch = idx / 4608;
        int dk = dd / 3, dm = dd % 3;
        float v = 0.f;
        if (job < 4) {
            if (idx < 13824) {
                int CIN = (job < 2) ? 9 : 10;
                const float* wt = (job < 2) ? w1 : w2;
                bool swap = job & 1;
                int slot = ch * 32 + k;
                if (n < 10 && slot < CIN * 9) {
                    int ci = slot / 9, pl = slot - ci * 9;
                    int di = pl / 3, dj = pl % 3;
                    int widx = swap ? ((((n * CIN + ci) * 3 + dk) * 3 + dm) * 3 + di) * 3 + dj
                                    : ((((n * CIN + ci) * 3 + di) * 3 + dj) * 3 + dk) * 3 + dm;
                    v = wt[widx];
                }
                union { _Float16 h; ushort_t u; } cv; cv.h = (_Float16)v;
                wb0[job * 13824 + idx] = cv.u;
            }
        } else {
            bool swap = (job == 5);
            int slot = ch * 32 + k;
            if (slot < 120) {
                int ci = slot / 12, r = slot - ci * 12;
                int di = r >> 2, dj4 = r & 3;
                int e = dj4 - n;
                if (n < 2 && e >= 0 && e <= 2) {
                    int widx = swap ? (((ci * 3 + dk) * 3 + dm) * 3 + di) * 3 + e
                                    : (((ci * 3 + di) * 3 + e) * 3 + dk) * 3 + dm;
                    v = w3[widx];
                }
            }
            union { _Float16 h; ushort_t u; } cv; cv.h = (_Float16)v;
            wb0[55296 + (job - 4) * 18432 + idx] = cv.u;
        }
    }
}

// ---------------------------------------------------------------------------
// Kernel 3a (v2): transpose+convert WITH FUSED NORM PARTIALS.
// ---------------------------------------------------------------------------
__global__ __launch_bounds__(256) void transpose_f16(const float* __restrict__ fq,
                                                     const float* __restrict__ fs,
                                                     ushort_t* __restrict__ At,
                                                     ushort_t* __restrict__ Bt,
                                                     float* __restrict__ ssbuf,
                                                     int lb_base) {
    __shared__ float tile[64][65];
    __shared__ float red4[4][64];
    int z = blockIdx.z;
    int tsel = z / 9, li = z - tsel * 9;
    int lb = lb_base + li;
    const float* src = (tsel ? fs : fq) + (size_t)lb * CF * HW;
    ushort_t* dst = (tsel ? Bt : At) + (size_t)li * HW * CF;
    int c0 = blockIdx.x * 64, ij0 = blockIdx.y * 64;
    int tid = threadIdx.x;
    int cl = tid >> 6;
    int col = tid & 63;
    float ssp = 0.f;
    #pragma unroll
    for (int rr = 0; rr < 16; ++rr) {
        int c_local = rr * 4 + cl;
        int ij = ij0 + col;
        float v = (ij < HW) ? src[(size_t)(c0 + c_local) * HW + ij] : 0.f;
        tile[c_local][col] = v;
        ssp = fmaf(v, v, ssp);
    }
    red4[cl][col] = ssp;
    __syncthreads();
    if (cl == 0) {
        int ij = ij0 + col;
        if (ij < HW) {
            float s4 = red4[0][col] + red4[1][col] + red4[2][col] + red4[3][col];
            atomicAdd(&ssbuf[(size_t)(tsel * 18 + lb) * HW + ij], s4);
        }
    }
    int cp = (tid & 31) * 2;
    int rowsel = tid >> 5;
    #pragma unroll
    for (int rr = 0; rr < 8; ++rr) {
        int ij_local = rr * 8 + rowsel;
        int ij = ij0 + ij_local;
        if (ij < HW) {
            union { _Float16 h; ushort_t u; } h0, h1;
            h0.h = (_Float16)tile[cp][ij_local];
            h1.h = (_Float16)tile[cp + 1][ij_local];
            ushort2 o; o.x = h0.u; o.y = h1.u;
            *(ushort2*)(dst + (size_t)ij * CF + c0 + cp) = o;
        }
    }
}

// ---------------------------------------------------------------------------
// Kernel 3b (v2): MFMA fp16 correlation GEMM, M-SPLIT 32x64 tiles.
// 441 blocks (1.7/CU) -> 819 blocks (3.2/CU): half the CUs previously held
// one block with zero wave-level latency hiding across 32 barrier phases.
// Wave = 16x32 output (mw = (w>>1)*16, nw = (w&1)*32, acc 2x f32x4).
// ---------------------------------------------------------------------------
__global__ __launch_bounds__(256) void corr_gemm_mfma(const ushort_t* __restrict__ At,
                                                      const ushort_t* __restrict__ Bt,
                                                      const float* __restrict__ ssbuf,
                                                      ushort_t* __restrict__ corr,
                                                      int lb_base) {
    __shared__ ushort_t As[32][72];
    __shared__ ushort_t Bs[64][72];
    int li = blockIdx.z, lb = lb_base + li;
    int l = lb >> 1, b = lb & 1;
    int i0 = blockIdx.y * 32, j0 = blockIdx.x * 64;
    int tid = threadIdx.x, lane = tid & 63, w = tid >> 6;
    int mw = (w >> 1) * 16, nw = (w & 1) * 32;
    f32x4 acc[2] = {};
    const ushort_t* Abase = At + (size_t)li * HW * CF;
    const ushort_t* Bbase = Bt + (size_t)li * HW * CF;

    for (int kt = 0; kt < 16; ++kt) {
        int c0 = kt * 64;
        __syncthreads();
        {
            int row = tid >> 3, c8 = tid & 7;
            uint4 va = make_uint4(0, 0, 0, 0);
            if (i0 + row < HW) va = *(const uint4*)(Abase + (size_t)(i0 + row) * CF + c0 + c8 * 8);
            *(uint4*)&As[row][c8 * 8] = va;
        }
        #pragma unroll
        for (int p = 0; p < 2; ++p) {
            int idx = tid + p * 256;
            int row = idx >> 3, c8 = idx & 7;
            uint4 vb = make_uint4(0, 0, 0, 0);
            if (j0 + row < HW) vb = *(const uint4*)(Bbase + (size_t)(j0 + row) * CF + c0 + c8 * 8);
            *(uint4*)&Bs[row][c8 * 8] = vb;
        }
        __syncthreads();
        #pragma unroll
        for (int ks = 0; ks < 2; ++ks) {
            int k0 = ks * 32 + (lane >> 4) * 8;
            half8 a0 = *(const half8*)&As[mw + (lane & 15)][k0];
            half8 b0 = *(const half8*)&Bs[nw + (lane & 15)][k0];
            half8 b1 = *(const half8*)&Bs[nw + 16 + (lane & 15)][k0];
            acc[0] = __builtin_amdgcn_mfma_f32_16x16x32_f16(a0, b0, acc[0], 0, 0, 0);
            acc[1] = __builtin_amdgcn_mfma_f32_16x16x32_f16(a0, b1, acc[1], 0, 0, 0);
        }
    }
    int obase = (b * 9 + l) * HW;
    #pragma unroll
    for (int ni = 0; ni < 2; ++ni) {
        int km = j0 + nw + ni * 16 + (lane & 15);
        if (km >= HW) continue;
        float ib = 1.0f / fmaxf(sqrtf(ssbuf[(size_t)(18 + lb) * HW + km]), EPSF);
        #pragma unroll
        for (int r = 0; r < 4; ++r) {
            int ij = i0 + mw + (lane >> 4) * 4 + r;
            if (ij < HW) {
                float ia = 1.0f / fmaxf(sqrtf(ssbuf[(size_t)lb * HW + ij]), EPSF);
                union { _Float16 h; ushort_t u; } cv;
                cv.h = (_Float16)(acc[ni][r] * ia * ib);
                corr[(size_t)(obase + ij) * HW + km] = cv.u;
            }
        }
    }
}

// ---------------------------------------------------------------------------
// Kernel 4 (v8h): 256-thread conv (L2, 1600-block regime).
// ---------------------------------------------------------------------------
template <int CIN, int COUT, bool DUAL, bool OUTF16>
__global__ __launch_bounds__(256) void conv4d_v8h(const ushort_t* __restrict__ inA,
                                                  const ushort_t* __restrict__ inB,
                                                  const ushort_t* __restrict__ wbA,
                                                  const ushort_t* __restrict__ wbB,
                                                  void* __restrict__ outA,
                                                  void* __restrict__ outB) {
    constexpr int S = CIN * 9;
    constexpr int NCH = (S + 31) / 32;
    __shared__ __align__(16) ushort_t Ah[484 * 40];
    const int b = blockIdx.y, ij = blockIdx.x;
    const int z = blockIdx.z;
    const ushort_t* in = (DUAL || z == 0) ? inA : inB;
    const ushort_t* wbS = (DUAL || z == 0) ? wbA : wbB;
    void* outS = (DUAL || z == 0) ? outA : outB;
    const int i = ij / 20, j = ij - (ij / 20) * 20;
    const int tid = threadIdx.x, wv = tid >> 6, lane = tid & 63;
    const int m16 = lane & 15, q4 = lane >> 4;

    HALO_ZERO(256)

    int baseh[7];
    #pragma unroll
    for (int s = 0; s < 7; ++s) {
        int t = wv + 4 * s;
        if (t < 25) {
            int km = t * 16 + m16;
            int kk = km / 20, mm = km - kk * 20;
            baseh[s] = (kk * 22 + mm) * 40 + q4 * 8;
        } else baseh[s] = 0;
    }
    f32x4 accA[7] = {};
    f32x4 accB[7] = {};

    const bool stager = tid < 200;
    const int km1 = 2 * tid;
    const int r1 = stager ? ((km1 / 20 + 1) * 22 + (km1 % 20) + 1) : 0;
    int hofs[9]; bool vld[9];
    #pragma unroll
    for (int pl = 0; pl < 9; ++pl) {
        int ii = i + pl / 3 - 1, jj = j + pl % 3 - 1;
        vld[pl] = (unsigned)ii < 20u && (unsigned)jj < 20u;
        hofs[pl] = (ii * 20 + jj) * HW + km1;
    }
    const ushort_t* in_b = in + (size_t)b * CIN * HW * HW;
    const int wbase = m16 * 32 + q4 * 8;

    uint pf[32];
    #pragma unroll
    for (int u = 0; u < 32; ++u) {
        int slot = u;
        if (slot < S) {
            int ci = slot / 9, pl = slot - ci * 9;
            pf[u] = (stager && vld[pl]) ? *(const uint*)(in_b + ci * (HW * HW) + hofs[pl]) : 0u;
        } else pf[u] = 0u;
    }
    __syncthreads();

    #pragma unroll
    for (int ch = 0; ch < NCH; ++ch) {
        if (stager) {
            #pragma unroll
            for (int g4 = 0; g4 < 8; ++g4) {
                uint lo0 = (pf[4 * g4] & 0xFFFFu) | (pf[4 * g4 + 1] << 16);
                uint lo1 = (pf[4 * g4 + 2] & 0xFFFFu) | (pf[4 * g4 + 3] << 16);
                uint hi0 = (pf[4 * g4] >> 16) | (pf[4 * g4 + 1] & 0xFFFF0000u);
                uint hi1 = (pf[4 * g4 + 2] >> 16) | (pf[4 * g4 + 3] & 0xFFFF0000u);
                uint2 wlo; wlo.x = lo0; wlo.y = lo1;
                uint2 whi; whi.x = hi0; whi.y = hi1;
                *(uint2*)&Ah[(size_t)r1 * 40 + 4 * g4] = wlo;
                *(uint2*)&Ah[(size_t)(r1 + 1) * 40 + 4 * g4] = whi;
            }
        }
        __syncthreads();
        if (ch + 1 < NCH) {
            #pragma unroll
            for (int u = 0; u < 32; ++u) {
                int slot = (ch + 1) * 32 + u;
                if (slot < S) {
                    int ci = slot / 9, pl = slot - ci * 9;
                    pf[u] = (stager && vld[pl]) ? *(const uint*)(in_b + ci * (HW * HW) + hofs[pl]) : 0u;
                } else pf[u] = 0u;
            }
        }
        #pragma unroll
        for (int dd = 0; dd < 9; ++dd) {
            half8 bfA = *(const half8*)(wbS + (ch * 9 + dd) * 512 + wbase);
            half8 bfB;
            if (DUAL) bfB = *(const half8*)(wbB + (ch * 9 + dd) * 512 + wbase);
            const int doff = ((dd / 3) * 22 + (dd % 3)) * 40;
            #pragma unroll
            for (int s = 0; s < 7; ++s) {
                if (wv + 4 * s < 25) {
                    half8 af = *(const half8*)(Ah + baseh[s] + doff);
                    accA[s] = __builtin_amdgcn_mfma_f32_16x16x32_f16(af, bfA, accA[s], 0, 0, 0);
                    if (DUAL) accB[s] = __builtin_amdgcn_mfma_f32_16x16x32_f16(af, bfB, accB[s], 0, 0, 0);
                }
            }
        }
        if (ch + 1 < NCH) __syncthreads();
    }

    const int co = m16;
    if (co < COUT) {
        #pragma unroll
        for (int s = 0; s < 7; ++s) {
            int t = wv + 4 * s;
            if (t < 25) {
                int km0 = t * 16 + q4 * 4;
                size_t o = ((size_t)(b * COUT + co) * HW + ij) * HW + km0;
                if (OUTF16) {
                    union { ushort_t us[4]; uint2 u2; } pk;
                    #pragma unroll
                    for (int r = 0; r < 4; ++r) {
                        union { _Float16 h; ushort_t u16; } cv;
                        cv.h = (_Float16)fmaxf(accA[s][r], 0.f);
                        pk.us[r] = cv.u16;
                    }
                    *(uint2*)((ushort_t*)outS + o) = pk.u2;
                    if (DUAL) {
                        #pragma unroll
                        for (int r = 0; r < 4; ++r) {
                            union { _Float16 h; ushort_t u16; } cv;
                            cv.h = (_Float16)fmaxf(accB[s][r], 0.f);
                            pk.us[r] = cv.u16;
                        }
                        *(uint2*)((ushort_t*)outB + o) = pk.u2;
                    }
                } else {
                    f32x4 ov;
                    #pragma unroll
                    for (int r = 0; r < 4; ++r) ov[r] = fmaxf(accA[s][r], 0.f);
                    *(f32x4*)((float*)outS + o) = ov;
                }
            }
        }
    }
}

// ---------------------------------------------------------------------------
// Kernel 4 (v14h): 512-thread conv for block-poor dispatches (L1: 800 blocks).
// ---------------------------------------------------------------------------
template <int CIN, int COUT, bool DUAL, bool OUTF16>
__global__ __launch_bounds__(512, 2) void conv4d_v14h(const ushort_t* __restrict__ inA,
                                                      const ushort_t* __restrict__ inB,
                                                      const ushort_t* __restrict__ wbA,
                                                      const ushort_t* __restrict__ wbB,
                                                      void* __restrict__ outA,
                                                      void* __restrict__ outB) {
    constexpr int S = CIN * 9;
    constexpr int NCH = (S + 31) / 32;
    __shared__ __align__(16) ushort_t Ah[484 * 40];
    const int b = blockIdx.y, ij = blockIdx.x;
    const int z = blockIdx.z;
    const ushort_t* in = (DUAL || z == 0) ? inA : inB;
    const ushort_t* wbS = (DUAL || z == 0) ? wbA : wbB;
    void* outS = (DUAL || z == 0) ? outA : outB;
    const int i = ij / 20, j = ij - (ij / 20) * 20;
    const int tid = threadIdx.x, wv = tid >> 6, lane = tid & 63;
    const int m16 = lane & 15, q4 = lane >> 4;
    const int wt = 7 - wv;

    HALO_ZERO(512)

    int baseh[4];
    #pragma unroll
    for (int s = 0; s < 4; ++s) {
        int t = wt + 8 * s;
        if (t < 25) {
            int km = t * 16 + m16;
            int kk = km / 20, mm = km - kk * 20;
            baseh[s] = (kk * 22 + mm) * 40 + q4 * 8;
        } else baseh[s] = 0;
    }
    f32x4 accA[4] = {};
    f32x4 accB[4] = {};

    const bool stager = tid < 200;
    const int km1 = 2 * tid;
    const int r1 = stager ? ((km1 / 20 + 1) * 22 + (km1 % 20) + 1) : 0;
    int hofs[9]; bool vld[9];
    #pragma unroll
    for (int pl = 0; pl < 9; ++pl) {
        int ii = i + pl / 3 - 1, jj = j + pl % 3 - 1;
        vld[pl] = (unsigned)ii < 20u && (unsigned)jj < 20u;
        hofs[pl] = (ii * 20 + jj) * HW + km1;
    }
    const ushort_t* in_b = in + (size_t)b * CIN * HW * HW;
    const int wbase = m16 * 32 + q4 * 8;

    uint pf[32];
    #pragma unroll
    for (int u = 0; u < 32; ++u) {
        int slot = u;
        if (slot < S) {
            int ci = slot / 9, pl = slot - ci * 9;
            pf[u] = (stager && vld[pl]) ? *(const uint*)(in_b + ci * (HW * HW) + hofs[pl]) : 0u;
        } else pf[u] = 0u;
    }
    __syncthreads();

    #pragma unroll
    for (int ch = 0; ch < NCH; ++ch) {
        if (stager) {
            #pragma unroll
            for (int g4 = 0; g4 < 8; ++g4) {
                uint lo0 = (pf[4 * g4] & 0xFFFFu) | (pf[4 * g4 + 1] << 16);
                uint lo1 = (pf[4 * g4 + 2] & 0xFFFFu) | (pf[4 * g4 + 3] << 16);
                uint hi0 = (pf[4 * g4] >> 16) | (pf[4 * g4 + 1] & 0xFFFF0000u);
                uint hi1 = (pf[4 * g4 + 2] >> 16) | (pf[4 * g4 + 3] & 0xFFFF0000u);
                uint2 wlo; wlo.x = lo0; wlo.y = lo1;
                uint2 whi; whi.x = hi0; whi.y = hi1;
                *(uint2*)&Ah[(size_t)r1 * 40 + 4 * g4] = wlo;
                *(uint2*)&Ah[(size_t)(r1 + 1) * 40 + 4 * g4] = whi;
            }
        }
        __syncthreads();
        if (ch + 1 < NCH) {
            #pragma unroll
            for (int u = 0; u < 32; ++u) {
                int slot = (ch + 1) * 32 + u;
                if (slot < S) {
                    int ci = slot / 9, pl = slot - ci * 9;
                    pf[u] = (stager && vld[pl]) ? *(const uint*)(in_b + ci * (HW * HW) + hofs[pl]) : 0u;
                } else pf[u] = 0u;
            }
        }
        #pragma unroll
        for (int dd = 0; dd < 9; ++dd) {
            half8 bfA = *(const half8*)(wbS + (ch * 9 + dd) * 512 + wbase);
            half8 bfB;
            if (DUAL) bfB = *(const half8*)(wbB + (ch * 9 + dd) * 512 + wbase);
            const int doff = ((dd / 3) * 22 + (dd % 3)) * 40;
            #pragma unroll
            for (int s = 0; s < 4; ++s) {
                if (wt + 8 * s < 25) {
                    half8 af = *(const half8*)(Ah + baseh[s] + doff);
                    accA[s] = __builtin_amdgcn_mfma_f32_16x16x32_f16(af, bfA, accA[s], 0, 0, 0);
                    if (DUAL) accB[s] = __builtin_amdgcn_mfma_f32_16x16x32_f16(af, bfB, accB[s], 0, 0, 0);
                }
            }
        }
        if (ch + 1 < NCH) __syncthreads();
    }

    const int co = m16;
    if (co < COUT) {
        #pragma unroll
        for (int s = 0; s < 4; ++s) {
            int t = wt + 8 * s;
            if (t < 25) {
                int km0 = t * 16 + q4 * 4;
                size_t o = ((size_t)(b * COUT + co) * HW + ij) * HW + km0;
                if (OUTF16) {
                    union { ushort_t us[4]; uint2 u2; } pk;
                    #pragma unroll
                    for (int r = 0; r < 4; ++r) {
                        union { _Float16 h; ushort_t u16; } cv;
                        cv.h = (_Float16)fmaxf(accA[s][r], 0.f);
                        pk.us[r] = cv.u16;
                    }
                    *(uint2*)((ushort_t*)outS + o) = pk.u2;
                    if (DUAL) {
                        #pragma unroll
                        for (int r = 0; r < 4; ++r) {
                            union { _Float16 h; ushort_t u16; } cv;
                            cv.h = (_Float16)fmaxf(accB[s][r], 0.f);
                            pk.us[r] = cv.u16;
                        }
                        *(uint2*)((ushort_t*)outB + o) = pk.u2;
                    }
                } else {
                    f32x4 ov;
                    #pragma unroll
                    for (int r = 0; r < 4; ++r) ov[r] = fmaxf(accA[s][r], 0.f);
                    *(f32x4*)((float*)outS + o) = ov;
                }
            }
        }
    }
}

// ---------------------------------------------------------------------------
// Kernel 4b (L3): 2-ij merged-N conv, 512 threads (800-block dispatch).
// ---------------------------------------------------------------------------
template <int CIN>
__global__ __launch_bounds__(512, 2) void conv4d_l3(
        const ushort_t* __restrict__ inA, const ushort_t* __restrict__ inB,
        const ushort_t* __restrict__ wAm, const ushort_t* __restrict__ wBm,
        float* __restrict__ outA, float* __restrict__ outB) {
    constexpr int S2 = CIN * 12;
    constexpr int NCH = (S2 + 31) / 32;
    __shared__ __align__(16) ushort_t Ah[484 * 40];
    const int b = blockIdx.y, bx = blockIdx.x, z = blockIdx.z;
    const ushort_t* in = z ? inB : inA;
    const ushort_t* w1 = z ? wBm : wAm;
    float* outS = z ? outB : outA;
    const int i = bx / 10, jp = bx - (bx / 10) * 10;
    const int j0 = 2 * jp;
    const int ij0 = i * 20 + j0;
    const int tid = threadIdx.x, wv = tid >> 6, lane = tid & 63;
    const int m16 = lane & 15, q4 = lane >> 4;
    const int wt = 7 - wv;

    HALO_ZERO(512)

    int baseh[4];
    #pragma unroll
    for (int s = 0; s < 4; ++s) {
        int t = wt + 8 * s;
        if (t < 25) {
            int km = t * 16 + m16;
            int kk = km / 20, mm = km - kk * 20;
            baseh[s] = (kk * 22 + mm) * 40 + q4 * 8;
        } else baseh[s] = 0;
    }
    f32x4 acc1[4] = {};

    const bool stager = tid < 200;
    const int km1 = 2 * tid;
    const int r1 = stager ? ((km1 / 20 + 1) * 22 + (km1 % 20) + 1) : 0;
    int hofs[12]; bool vld[12];
    #pragma unroll
    for (int pl = 0; pl < 12; ++pl) {
        int di = pl >> 2, dj = pl & 3;
        int ii = i + di - 1, jj = j0 + dj - 1;
        vld[pl] = (unsigned)ii < 20u && (unsigned)jj < 20u;
        hofs[pl] = (ii * 20 + jj) * HW + km1;
    }
    const ushort_t* in_b = in + (size_t)b * CIN * HW * HW;
    const int wbase = m16 * 32 + q4 * 8;

    uint pf[32];
    #pragma unroll
    for (int u = 0; u < 32; ++u) {
        int slot = u;
        if (slot < S2) {
            int ci = slot / 12, pl = slot - ci * 12;
            pf[u] = (stager && vld[pl]) ? *(const uint*)(in_b + ci * (HW * HW) + hofs[pl]) : 0u;
        } else pf[u] = 0u;
    }
    __syncthreads();

    #pragma unroll
    for (int ch = 0; ch < NCH; ++ch) {
        if (stager) {
            #pragma unroll
            for (int g4 = 0; g4 < 8; ++g4) {
                uint lo0 = (pf[4 * g4] & 0xFFFFu) | (pf[4 * g4 + 1] << 16);
                uint lo1 = (pf[4 * g4 + 2] & 0xFFFFu) | (pf[4 * g4 + 3] << 16);
                uint hi0 = (pf[4 * g4] >> 16) | (pf[4 * g4 + 1] & 0xFFFF0000u);
                uint hi1 = (pf[4 * g4 + 2] >> 16) | (pf[4 * g4 + 3] & 0xFFFF0000u);
                uint2 wlo; wlo.x = lo0; wlo.y = lo1;
                uint2 whi; whi.x = hi0; whi.y = hi1;
                *(uint2*)&Ah[(size_t)r1 * 40 + 4 * g4] = wlo;
                *(uint2*)&Ah[(size_t)(r1 + 1) * 40 + 4 * g4] = whi;
            }
        }
        __syncthreads();
        if (ch + 1 < NCH) {
            #pragma unroll
            for (int u = 0; u < 32; ++u) {
                int slot = (ch + 1) * 32 + u;
                if (slot < S2) {
                    int ci = slot / 12, pl = slot - ci * 12;
                    pf[u] = (stager && vld[pl]) ? *(const uint*)(in_b + ci * (HW * HW) + hofs[pl]) : 0u;
                } else pf[u] = 0u;
            }
        }
        #pragma unroll
        for (int dd = 0; dd < 9; ++dd) {
            half8 bf1 = *(const half8*)(w1 + (ch * 9 + dd) * 512 + wbase);
            const int doff = ((dd / 3) * 22 + (dd % 3)) * 40;
            #pragma unroll
            for (int s = 0; s < 4; ++s) {
                if (wt + 8 * s < 25) {
                    half8 af = *(const half8*)(Ah + baseh[s] + doff);
                    acc1[s] = __builtin_amdgcn_mfma_f32_16x16x32_f16(af, bf1, acc1[s], 0, 0, 0);
                }
            }
        }
        if (ch + 1 < NCH) __syncthreads();
    }

    if (m16 < 2) {
        const int ij = ij0 + m16;
        #pragma unroll
        for (int s = 0; s < 4; ++s) {
            int t = wt + 8 * s;
            if (t < 25) {
                int km0 = t * 16 + q4 * 4;
                size_t o = ((size_t)b * HW + ij) * HW + km0;
                f32x4 ov;
                #pragma unroll
                for (int r = 0; r < 4; ++r) ov[r] = fmaxf(acc1[s][r], 0.f);
                *(f32x4*)(outS + o) = ov;
            }
        }
    }
}

// ---------------------------------------------------------------------------
// Kernel 5 (v4): softmax + attn.V, Q-SPLIT to 32 rows/block.
// 112 blocks (0.44/CU, 57% of GPU idle) -> 208 blocks. Each wave: 8 softmax
// rows (2 rg groups), then one (m-tile, nt) AV MFMA tile. P-LDS 27KB.
// ---------------------------------------------------------------------------
__global__ __launch_bounds__(256) void softmax_av_mfma3(const float* __restrict__ c4A,
                                                        const float* __restrict__ c4B,
                                                        const ushort_t* __restrict__ fsh,
                                                        float* __restrict__ att) {
    __shared__ ushort_t P[32 * 424];
    __shared__ float invl[32];
    const int b = blockIdx.z, qb = blockIdx.x * 32;
    const int tid = threadIdx.x, wv = tid >> 6, lane = tid & 63;
    const int m16 = lane & 15, q4 = lane >> 4;
    const int lane16 = lane & 15, rg4 = lane >> 4;

    #pragma unroll 1
    for (int rg = 0; rg < 2; ++rg) {
        const int ql = wv * 8 + rg * 4 + rg4;
        int q = qb + ql; if (q > HW - 1) q = HW - 1;
        const float* rowA = c4A + ((size_t)b * HW + q) * HW;
        const float* rowB = c4B + ((size_t)b * HW + q) * HW;
        float4 v4[7];
        #pragma unroll
        for (int k4 = 0; k4 < 6; ++k4) {
            float4 a4 = *(const float4*)(rowA + 64 * k4 + lane16 * 4);
            float4 b4 = *(const float4*)(rowB + 64 * k4 + lane16 * 4);
            v4[k4] = make_float4(a4.x + b4.x, a4.y + b4.y, a4.z + b4.z, a4.w + b4.w);
        }
        if (lane16 < 4) {
            float4 a4 = *(const float4*)(rowA + 384 + lane16 * 4);
            float4 b4 = *(const float4*)(rowB + 384 + lane16 * 4);
            v4[6] = make_float4(a4.x + b4.x, a4.y + b4.y, a4.z + b4.z, a4.w + b4.w);
        } else {
            v4[6] = make_float4(-1e30f, -1e30f, -1e30f, -1e30f);
        }
        float mx = -1e30f;
        #pragma unroll
        for (int k4 = 0; k4 < 7; ++k4)
            mx = fmaxf(mx, fmaxf(fmaxf(v4[k4].x, v4[k4].y), fmaxf(v4[k4].z, v4[k4].w)));
        #pragma unroll
        for (int off = 8; off; off >>= 1) mx = fmaxf(mx, __shfl_xor(mx, off, 16));
        float sum = 0.f;
        #pragma unroll
        for (int k4 = 0; k4 < 7; ++k4) {
            if (k4 == 6 && lane16 >= 4) break;
            float e0 = __expf(TEMPF * (v4[k4].x - mx));
            float e1 = __expf(TEMPF * (v4[k4].y - mx));
            float e2 = __expf(TEMPF * (v4[k4].z - mx));
            float e3 = __expf(TEMPF * (v4[k4].w - mx));
            sum += e0 + e1 + e2 + e3;
            union { ushort_t us[4]; uint2 u2; } pk;
            union { _Float16 h; ushort_t u16; } cv;
            cv.h = (_Float16)e0; pk.us[0] = cv.u16;
            cv.h = (_Float16)e1; pk.us[1] = cv.u16;
            cv.h = (_Float16)e2; pk.us[2] = cv.u16;
            cv.h = (_Float16)e3; pk.us[3] = cv.u16;
            *(uint2*)&P[(size_t)ql * 424 + 64 * k4 + lane16 * 4] = pk.u2;
        }
        if (lane16 >= 4 && lane16 < 10) {
            uint2 z2; z2.x = 0; z2.y = 0;
            *(uint2*)&P[(size_t)ql * 424 + 384 + lane16 * 4] = z2;
        }
        #pragma unroll
        for (int off = 8; off; off >>= 1) sum += __shfl_xor(sum, off, 16);
        if (lane16 == 0) invl[ql] = 1.0f / sum;
    }
    __syncthreads();

    const int mtile = wv & 1, ntl = wv >> 1;
    half8 afr[13];
    #pragma unroll
    for (int ks = 0; ks < 13; ++ks)
        afr[ks] = *(const half8*)&P[(size_t)(mtile * 16 + m16) * 424 + ks * 32 + q4 * 8];
    const ushort_t* fb = fsh + (size_t)b * CH * 416;
    const int nt = blockIdx.y * 2 + ntl;
    const int c = nt * 16 + m16;
    const ushort_t* fc = fb + (size_t)c * 416 + q4 * 8;
    f32x4 acc = {};
    #pragma unroll
    for (int ks = 0; ks < 13; ++ks) {
        half8 bf = *(const half8*)(fc + ks * 32);
        acc = __builtin_amdgcn_mfma_f32_16x16x32_f16(afr[ks], bf, acc, 0, 0, 0);
    }
    #pragma unroll
    for (int r = 0; r < 4; ++r) {
        int ql = mtile * 16 + q4 * 4 + r;
        int q = qb + ql;
        if (q < HW)
            att[((size_t)b * CH + c) * HW + q] = acc[r] * invl[ql];
    }
}

// ---------------------------------------------------------------------------
// Kernel 6 (v2): fq = l2norm(f_q, ch) + 0.5 * l2norm(att_fq, ch).
// ---------------------------------------------------------------------------
__global__ __launch_bounds__(256) void final_fq(const float* __restrict__ f_q,
                                                const float* __restrict__ att,
                                                float* __restrict__ out_fq) {
    __shared__ float2 red[4];
    int b = blockIdx.y, q = blockIdx.x;
    int tid = threadIdx.x, wv = tid >> 6, lane = tid & 63;
    size_t idx = (size_t)(b * CH + tid) * HW + q;
    float f = f_q[idx];
    float a = att[idx];
    float vf = f * f, va = a * a;
    #pragma unroll
    for (int off = 32; off; off >>= 1) {
        vf += __shfl_xor(vf, off);
        va += __shfl_xor(va, off);
    }
    if (lane == 0) red[wv] = make_float2(vf, va);
    __syncthreads();
    float sf = red[0].x + red[1].x + red[2].x + red[3].x;
    float sa = red[0].y + red[1].y + red[2].y + red[3].y;
    float invf = 1.0f / fmaxf(sqrtf(sf), EPSF);
    float inva = 1.0f / fmaxf(sqrtf(sa), EPSF);
    out_fq[idx] = f * invf + 0.5f * a * inva;
}

// ---------------------------------------------------------------------------
extern "C" void kernel_launch(void* const* d_in, const int* in_sizes, int n_in,
                              void* d_out, int out_size, void* d_ws, size_t ws_size,
                              hipStream_t stream) {
    const float* fq_feats = (const float*)d_in[0];
    const float* fs_feats = (const float*)d_in[1];
    const float* f_q      = (const float*)d_in[2];
    const float* f_s      = (const float*)d_in[3];
    const float* w1       = (const float*)d_in[4];
    const float* w2       = (const float*)d_in[5];
    const float* w3       = (const float*)d_in[6];
    float* out = (float*)d_out;              // fq at 0, att_fq at 204800

    float* ws      = (float*)d_ws;
    float* wbuf    = ws;                     // 115,200 fl: weight tables
    float* ssbuf   = wbuf + 115200;          // 14,400 fl: fused-norm ss
    float* corr    = ssbuf + 14400;          // 2,880,000 fl region
    float* buf1    = corr + 2880000;         // 3,200,000 (At / b1A+b1B)
    float* buf2    = buf1 + 3200000;         // 3,200,000 (Bt / b2A+b2B)
    float* att     = out + 204800;

    ushort_t* corr_h = (ushort_t*)corr;
    ushort_t* fsh    = (ushort_t*)(corr + 1440000);
    float* c4A = corr + 1600000;
    float* c4B = corr + 1920000;
    ushort_t* At = (ushort_t*)buf1;
    ushort_t* Bt = (ushort_t*)buf2;
    ushort_t* b1A = (ushort_t*)buf1;
    ushort_t* b1B = b1A + 3200000;
    ushort_t* b2A = (ushort_t*)buf2;
    ushort_t* b2B = b2A + 3200000;

    ushort_t* wb0   = (ushort_t*)wbuf;
    ushort_t* wbL1A = wb0;
    ushort_t* wbL1B = wb0 + 13824;
    ushort_t* wbL2A = wb0 + 27648;
    ushort_t* wbL2B = wb0 + 41472;
    ushort_t* wbL3Am = wb0 + 55296;
    ushort_t* wbL3Bm = wb0 + 73728;

    prep_all<<<832, 256, 0, stream>>>(w1, w2, w3, f_s, wb0, fsh, ssbuf);

    for (int half = 0; half < 2; ++half) {
        int base = half * 9;
        transpose_f16<<<dim3(16, 7, 18), 256, 0, stream>>>(fq_feats, fs_feats, At, Bt, ssbuf, base);
        corr_gemm_mfma<<<dim3(7, 13, 9), 256, 0, stream>>>(At, Bt, ssbuf, corr_h, base);
    }

    // L1: 800 blocks (block-poor) -> 512 threads
    conv4d_v14h<9, 10, true, true><<<dim3(400, NB, 1), 512, 0, stream>>>(
        corr_h, corr_h, wbL1A, wbL1B, b1A, b1B);
    // L2: 1600 blocks (block-rich) -> 256 threads, proven v8 structure
    conv4d_v8h<10, 10, false, true><<<dim3(400, NB, 2), 256, 0, stream>>>(
        b1A, b1B, wbL2A, wbL2B, b2A, b2B);
    // L3: 800 blocks 2-ij merged-N -> 512 threads
    conv4d_l3<10><<<dim3(200, NB, 2), 512, 0, stream>>>(
        b2A, b2B, wbL3Am, wbL3Bm, c4A, c4B);

    softmax_av_mfma3<<<dim3(13, 8, NB), 256, 0, stream>>>(c4A, c4B, fsh, att);
    final_fq<<<dim3(400, NB), 256, 0, stream>>>(f_q, att, out);

    (void)in_sizes; (void)n_in; (void)out_size; (void)ws_size;
}

// Round 10
// 329.102 us; speedup vs baseline: 1.1708x; 1.0065x over previous
//
#include <hip/hip_runtime.h>
#include <math.h>
#include <stddef.h>

#define L9   9
#define NB   2
#define CF   1024
#define HW   400     // 20*20
#define CH   256
#define TEMPF 20.0f
#define EPSF  1e-12f

typedef _Float16 half8 __attribute__((ext_vector_type(8)));
typedef float f32x4 __attribute__((ext_vector_type(4)));
typedef unsigned short ushort_t;

// Zero only the 84 halo rows of the 22x22 (pitch-40-half) A-tile.
#define HALO_ZERO(NT)                                                          \
    for (int h = threadIdx.x; h < 84 * 20; h += (NT)) {                        \
        int rs = h / 20, c = h - rs * 20;                                      \
        int row = rs < 22 ? rs                                                 \
                : rs < 44 ? 440 + rs                                           \
                : rs < 64 ? (rs - 43) * 22                                     \
                          : (rs - 63) * 22 + 21;                               \
        ((uint*)Ah)[row * 20 + c] = 0;                                         \
    }

// ---------------------------------------------------------------------------
// Kernel P: ALL prep work in ONE launch (weight tables + fsh + ss zero).
// ---------------------------------------------------------------------------
__global__ __launch_bounds__(256) void prep_all(const float* __restrict__ w1,
                                                const float* __restrict__ w2,
                                                const float* __restrict__ w3,
                                                const float* __restrict__ f_s,
                                                ushort_t* __restrict__ wb0,
                                                ushort_t* __restrict__ fsh,
                                                float* __restrict__ ssbuf) {
    int gid = blockIdx.x * 256 + threadIdx.x;
    if (gid < NB * CH * 416) {
        int s = gid % 416, bc = gid / 416;
        float v = (s < HW) ? f_s[(size_t)bc * HW + s] : 0.f;
        union { _Float16 h; ushort_t u; } cv; cv.h = (_Float16)v;
        fsh[gid] = cv.u;
    }
    if (gid < 14400) ssbuf[gid] = 0.f;
    if (gid < 6 * 18432) {
        int job = gid / 18432, idx = gid - job * 18432;
        int k = idx & 31, n = (idx >> 5) & 15, dd = (idx >> 9) % 9, ch = idx / 4608;
        int dk = dd / 3, dm = dd % 3;
        float v = 0.f;
        if (job < 4) {
            if (idx < 13824) {
                int CIN = (job < 2) ? 9 : 10;
                const float* wt = (job < 2) ? w1 : w2;
                bool swap = job & 1;
                int slot = ch * 32 + k;
                if (n < 10 && slot < CIN * 9) {
                    int ci = slot / 9, pl = slot - ci * 9;
                    int di = pl / 3, dj = pl % 3;
                    int widx = swap ? ((((n * CIN + ci) * 3 + dk) * 3 + dm) * 3 + di) * 3 + dj
                                    : ((((n * CIN + ci) * 3 + di) * 3 + dj) * 3 + dk) * 3 + dm;
                    v = wt[widx];
                }
                union { _Float16 h; ushort_t u; } cv; cv.h = (_Float16)v;
                wb0[job * 13824 + idx] = cv.u;
            }
        } else {
            bool swap = (job == 5);
            int slot = ch * 32 + k;
            if (slot < 120) {
                int ci = slot / 12, r = slot - ci * 12;
                int di = r >> 2, dj4 = r & 3;
                int e = dj4 - n;
                if (n < 2 && e >= 0 && e <= 2) {
                    int widx = swap ? (((ci * 3 + dk) * 3 + dm) * 3 + di) * 3 + e
                                    : (((ci * 3 + di) * 3 + e) * 3 + dk) * 3 + dm;
                    v = w3[widx];
                }
            }
            union { _Float16 h; ushort_t u; } cv; cv.h = (_Float16)v;
            wb0[55296 + (job - 4) * 18432 + idx] = cv.u;
        }
    }
}

// ---------------------------------------------------------------------------
// Kernel 3a (v2): transpose+convert WITH FUSED NORM PARTIALS.
// ---------------------------------------------------------------------------
__global__ __launch_bounds__(256) void transpose_f16(const float* __restrict__ fq,
                                                     const float* __restrict__ fs,
                                                     ushort_t* __restrict__ At,
                                                     ushort_t* __restrict__ Bt,
                                                     float* __restrict__ ssbuf,
                                                     int lb_base) {
    __shared__ float tile[64][65];
    __shared__ float red4[4][64];
    int z = blockIdx.z;
    int tsel = z / 9, li = z - tsel * 9;
    int lb = lb_base + li;
    const float* src = (tsel ? fs : fq) + (size_t)lb * CF * HW;
    ushort_t* dst = (tsel ? Bt : At) + (size_t)li * HW * CF;
    int c0 = blockIdx.x * 64, ij0 = blockIdx.y * 64;
    int tid = threadIdx.x;
    int cl = tid >> 6;
    int col = tid & 63;
    float ssp = 0.f;
    #pragma unroll
    for (int rr = 0; rr < 16; ++rr) {
        int c_local = rr * 4 + cl;
        int ij = ij0 + col;
        float v = (ij < HW) ? src[(size_t)(c0 + c_local) * HW + ij] : 0.f;
        tile[c_local][col] = v;
        ssp = fmaf(v, v, ssp);
    }
    red4[cl][col] = ssp;
    __syncthreads();
    if (cl == 0) {
        int ij = ij0 + col;
        if (ij < HW) {
            float s4 = red4[0][col] + red4[1][col] + red4[2][col] + red4[3][col];
            atomicAdd(&ssbuf[(size_t)(tsel * 18 + lb) * HW + ij], s4);
        }
    }
    int cp = (tid & 31) * 2;
    int rowsel = tid >> 5;
    #pragma unroll
    for (int rr = 0; rr < 8; ++rr) {
        int ij_local = rr * 8 + rowsel;
        int ij = ij0 + ij_local;
        if (ij < HW) {
            union { _Float16 h; ushort_t u; } h0, h1;
            h0.h = (_Float16)tile[cp][ij_local];
            h1.h = (_Float16)tile[cp + 1][ij_local];
            ushort2 o; o.x = h0.u; o.y = h1.u;
            *(ushort2*)(dst + (size_t)ij * CF + c0 + cp) = o;
        }
    }
}

// ---------------------------------------------------------------------------
// Kernel 3b (v2): MFMA fp16 correlation GEMM, M-SPLIT 32x64 tiles.
// ---------------------------------------------------------------------------
__global__ __launch_bounds__(256) void corr_gemm_mfma(const ushort_t* __restrict__ At,
                                                      const ushort_t* __restrict__ Bt,
                                                      const float* __restrict__ ssbuf,
                                                      ushort_t* __restrict__ corr,
                                                      int lb_base) {
    __shared__ ushort_t As[32][72];
    __shared__ ushort_t Bs[64][72];
    int li = blockIdx.z, lb = lb_base + li;
    int l = lb >> 1, b = lb & 1;
    int i0 = blockIdx.y * 32, j0 = blockIdx.x * 64;
    int tid = threadIdx.x, lane = tid & 63, w = tid >> 6;
    int mw = (w >> 1) * 16, nw = (w & 1) * 32;
    f32x4 acc[2] = {};
    const ushort_t* Abase = At + (size_t)li * HW * CF;
    const ushort_t* Bbase = Bt + (size_t)li * HW * CF;

    for (int kt = 0; kt < 16; ++kt) {
        int c0 = kt * 64;
        __syncthreads();
        {
            int row = tid >> 3, c8 = tid & 7;
            uint4 va = make_uint4(0, 0, 0, 0);
            if (i0 + row < HW) va = *(const uint4*)(Abase + (size_t)(i0 + row) * CF + c0 + c8 * 8);
            *(uint4*)&As[row][c8 * 8] = va;
        }
        #pragma unroll
        for (int p = 0; p < 2; ++p) {
            int idx = tid + p * 256;
            int row = idx >> 3, c8 = idx & 7;
            uint4 vb = make_uint4(0, 0, 0, 0);
            if (j0 + row < HW) vb = *(const uint4*)(Bbase + (size_t)(j0 + row) * CF + c0 + c8 * 8);
            *(uint4*)&Bs[row][c8 * 8] = vb;
        }
        __syncthreads();
        #pragma unroll
        for (int ks = 0; ks < 2; ++ks) {
            int k0 = ks * 32 + (lane >> 4) * 8;
            half8 a0 = *(const half8*)&As[mw + (lane & 15)][k0];
            half8 b0 = *(const half8*)&Bs[nw + (lane & 15)][k0];
            half8 b1 = *(const half8*)&Bs[nw + 16 + (lane & 15)][k0];
            acc[0] = __builtin_amdgcn_mfma_f32_16x16x32_f16(a0, b0, acc[0], 0, 0, 0);
            acc[1] = __builtin_amdgcn_mfma_f32_16x16x32_f16(a0, b1, acc[1], 0, 0, 0);
        }
    }
    int obase = (b * 9 + l) * HW;
    #pragma unroll
    for (int ni = 0; ni < 2; ++ni) {
        int km = j0 + nw + ni * 16 + (lane & 15);
        if (km >= HW) continue;
        float ib = 1.0f / fmaxf(sqrtf(ssbuf[(size_t)(18 + lb) * HW + km]), EPSF);
        #pragma unroll
        for (int r = 0; r < 4; ++r) {
            int ij = i0 + mw + (lane >> 4) * 4 + r;
            if (ij < HW) {
                float ia = 1.0f / fmaxf(sqrtf(ssbuf[(size_t)lb * HW + ij]), EPSF);
                union { _Float16 h; ushort_t u; } cv;
                cv.h = (_Float16)(acc[ni][r] * ia * ib);
                corr[(size_t)(obase + ij) * HW + km] = cv.u;
            }
        }
    }
}

// ---------------------------------------------------------------------------
// Kernel 4 (v8h): 256-thread conv (L2, 1600-block regime).
// ---------------------------------------------------------------------------
template <int CIN, int COUT, bool DUAL, bool OUTF16>
__global__ __launch_bounds__(256) void conv4d_v8h(const ushort_t* __restrict__ inA,
                                                  const ushort_t* __restrict__ inB,
                                                  const ushort_t* __restrict__ wbA,
                                                  const ushort_t* __restrict__ wbB,
                                                  void* __restrict__ outA,
                                                  void* __restrict__ outB) {
    constexpr int S = CIN * 9;
    constexpr int NCH = (S + 31) / 32;
    __shared__ __align__(16) ushort_t Ah[484 * 40];
    const int b = blockIdx.y, ij = blockIdx.x;
    const int z = blockIdx.z;
    const ushort_t* in = (DUAL || z == 0) ? inA : inB;
    const ushort_t* wbS = (DUAL || z == 0) ? wbA : wbB;
    void* outS = (DUAL || z == 0) ? outA : outB;
    const int i = ij / 20, j = ij - (ij / 20) * 20;
    const int tid = threadIdx.x, wv = tid >> 6, lane = tid & 63;
    const int m16 = lane & 15, q4 = lane >> 4;

    HALO_ZERO(256)

    int baseh[7];
    #pragma unroll
    for (int s = 0; s < 7; ++s) {
        int t = wv + 4 * s;
        if (t < 25) {
            int km = t * 16 + m16;
            int kk = km / 20, mm = km - kk * 20;
            baseh[s] = (kk * 22 + mm) * 40 + q4 * 8;
        } else baseh[s] = 0;
    }
    f32x4 accA[7] = {};
    f32x4 accB[7] = {};

    const bool stager = tid < 200;
    const int km1 = 2 * tid;
    const int r1 = stager ? ((km1 / 20 + 1) * 22 + (km1 % 20) + 1) : 0;
    int hofs[9]; bool vld[9];
    #pragma unroll
    for (int pl = 0; pl < 9; ++pl) {
        int ii = i + pl / 3 - 1, jj = j + pl % 3 - 1;
        vld[pl] = (unsigned)ii < 20u && (unsigned)jj < 20u;
        hofs[pl] = (ii * 20 + jj) * HW + km1;
    }
    const ushort_t* in_b = in + (size_t)b * CIN * HW * HW;
    const int wbase = m16 * 32 + q4 * 8;

    uint pf[32];
    #pragma unroll
    for (int u = 0; u < 32; ++u) {
        int slot = u;
        if (slot < S) {
            int ci = slot / 9, pl = slot - ci * 9;
            pf[u] = (stager && vld[pl]) ? *(const uint*)(in_b + ci * (HW * HW) + hofs[pl]) : 0u;
        } else pf[u] = 0u;
    }
    __syncthreads();

    #pragma unroll
    for (int ch = 0; ch < NCH; ++ch) {
        if (stager) {
            #pragma unroll
            for (int g4 = 0; g4 < 8; ++g4) {
                uint lo0 = (pf[4 * g4] & 0xFFFFu) | (pf[4 * g4 + 1] << 16);
                uint lo1 = (pf[4 * g4 + 2] & 0xFFFFu) | (pf[4 * g4 + 3] << 16);
                uint hi0 = (pf[4 * g4] >> 16) | (pf[4 * g4 + 1] & 0xFFFF0000u);
                uint hi1 = (pf[4 * g4 + 2] >> 16) | (pf[4 * g4 + 3] & 0xFFFF0000u);
                uint2 wlo; wlo.x = lo0; wlo.y = lo1;
                uint2 whi; whi.x = hi0; whi.y = hi1;
                *(uint2*)&Ah[(size_t)r1 * 40 + 4 * g4] = wlo;
                *(uint2*)&Ah[(size_t)(r1 + 1) * 40 + 4 * g4] = whi;
            }
        }
        __syncthreads();
        if (ch + 1 < NCH) {
            #pragma unroll
            for (int u = 0; u < 32; ++u) {
                int slot = (ch + 1) * 32 + u;
                if (slot < S) {
                    int ci = slot / 9, pl = slot - ci * 9;
                    pf[u] = (stager && vld[pl]) ? *(const uint*)(in_b + ci * (HW * HW) + hofs[pl]) : 0u;
                } else pf[u] = 0u;
            }
        }
        #pragma unroll
        for (int dd = 0; dd < 9; ++dd) {
            half8 bfA = *(const half8*)(wbS + (ch * 9 + dd) * 512 + wbase);
            half8 bfB;
            if (DUAL) bfB = *(const half8*)(wbB + (ch * 9 + dd) * 512 + wbase);
            const int doff = ((dd / 3) * 22 + (dd % 3)) * 40;
            #pragma unroll
            for (int s = 0; s < 7; ++s) {
                if (wv + 4 * s < 25) {
                    half8 af = *(const half8*)(Ah + baseh[s] + doff);
                    accA[s] = __builtin_amdgcn_mfma_f32_16x16x32_f16(af, bfA, accA[s], 0, 0, 0);
                    if (DUAL) accB[s] = __builtin_amdgcn_mfma_f32_16x16x32_f16(af, bfB, accB[s], 0, 0, 0);
                }
            }
        }
        if (ch + 1 < NCH) __syncthreads();
    }

    const int co = m16;
    if (co < COUT) {
        #pragma unroll
        for (int s = 0; s < 7; ++s) {
            int t = wv + 4 * s;
            if (t < 25) {
                int km0 = t * 16 + q4 * 4;
                size_t o = ((size_t)(b * COUT + co) * HW + ij) * HW + km0;
                if (OUTF16) {
                    union { ushort_t us[4]; uint2 u2; } pk;
                    #pragma unroll
                    for (int r = 0; r < 4; ++r) {
                        union { _Float16 h; ushort_t u16; } cv;
                        cv.h = (_Float16)fmaxf(accA[s][r], 0.f);
                        pk.us[r] = cv.u16;
                    }
                    *(uint2*)((ushort_t*)outS + o) = pk.u2;
                    if (DUAL) {
                        #pragma unroll
                        for (int r = 0; r < 4; ++r) {
                            union { _Float16 h; ushort_t u16; } cv;
                            cv.h = (_Float16)fmaxf(accB[s][r], 0.f);
                            pk.us[r] = cv.u16;
                        }
                        *(uint2*)((ushort_t*)outB + o) = pk.u2;
                    }
                } else {
                    f32x4 ov;
                    #pragma unroll
                    for (int r = 0; r < 4; ++r) ov[r] = fmaxf(accA[s][r], 0.f);
                    *(f32x4*)((float*)outS + o) = ov;
                }
            }
        }
    }
}

// ---------------------------------------------------------------------------
// Kernel 4 (v14h): 512-thread conv for block-poor dispatches (L1: 800 blocks).
// ---------------------------------------------------------------------------
template <int CIN, int COUT, bool DUAL, bool OUTF16>
__global__ __launch_bounds__(512, 2) void conv4d_v14h(const ushort_t* __restrict__ inA,
                                                      const ushort_t* __restrict__ inB,
                                                      const ushort_t* __restrict__ wbA,
                                                      const ushort_t* __restrict__ wbB,
                                                      void* __restrict__ outA,
                                                      void* __restrict__ outB) {
    constexpr int S = CIN * 9;
    constexpr int NCH = (S + 31) / 32;
    __shared__ __align__(16) ushort_t Ah[484 * 40];
    const int b = blockIdx.y, ij = blockIdx.x;
    const int z = blockIdx.z;
    const ushort_t* in = (DUAL || z == 0) ? inA : inB;
    const ushort_t* wbS = (DUAL || z == 0) ? wbA : wbB;
    void* outS = (DUAL || z == 0) ? outA : outB;
    const int i = ij / 20, j = ij - (ij / 20) * 20;
    const int tid = threadIdx.x, wv = tid >> 6, lane = tid & 63;
    const int m16 = lane & 15, q4 = lane >> 4;
    const int wt = 7 - wv;

    HALO_ZERO(512)

    int baseh[4];
    #pragma unroll
    for (int s = 0; s < 4; ++s) {
        int t = wt + 8 * s;
        if (t < 25) {
            int km = t * 16 + m16;
            int kk = km / 20, mm = km - kk * 20;
            baseh[s] = (kk * 22 + mm) * 40 + q4 * 8;
        } else baseh[s] = 0;
    }
    f32x4 accA[4] = {};
    f32x4 accB[4] = {};

    const bool stager = tid < 200;
    const int km1 = 2 * tid;
    const int r1 = stager ? ((km1 / 20 + 1) * 22 + (km1 % 20) + 1) : 0;
    int hofs[9]; bool vld[9];
    #pragma unroll
    for (int pl = 0; pl < 9; ++pl) {
        int ii = i + pl / 3 - 1, jj = j + pl % 3 - 1;
        vld[pl] = (unsigned)ii < 20u && (unsigned)jj < 20u;
        hofs[pl] = (ii * 20 + jj) * HW + km1;
    }
    const ushort_t* in_b = in + (size_t)b * CIN * HW * HW;
    const int wbase = m16 * 32 + q4 * 8;

    uint pf[32];
    #pragma unroll
    for (int u = 0; u < 32; ++u) {
        int slot = u;
        if (slot < S) {
            int ci = slot / 9, pl = slot - ci * 9;
            pf[u] = (stager && vld[pl]) ? *(const uint*)(in_b + ci * (HW * HW) + hofs[pl]) : 0u;
        } else pf[u] = 0u;
    }
    __syncthreads();

    #pragma unroll
    for (int ch = 0; ch < NCH; ++ch) {
        if (stager) {
            #pragma unroll
            for (int g4 = 0; g4 < 8; ++g4) {
                uint lo0 = (pf[4 * g4] & 0xFFFFu) | (pf[4 * g4 + 1] << 16);
                uint lo1 = (pf[4 * g4 + 2] & 0xFFFFu) | (pf[4 * g4 + 3] << 16);
                uint hi0 = (pf[4 * g4] >> 16) | (pf[4 * g4 + 1] & 0xFFFF0000u);
                uint hi1 = (pf[4 * g4 + 2] >> 16) | (pf[4 * g4 + 3] & 0xFFFF0000u);
                uint2 wlo; wlo.x = lo0; wlo.y = lo1;
                uint2 whi; whi.x = hi0; whi.y = hi1;
                *(uint2*)&Ah[(size_t)r1 * 40 + 4 * g4] = wlo;
                *(uint2*)&Ah[(size_t)(r1 + 1) * 40 + 4 * g4] = whi;
            }
        }
        __syncthreads();
        if (ch + 1 < NCH) {
            #pragma unroll
            for (int u = 0; u < 32; ++u) {
                int slot = (ch + 1) * 32 + u;
                if (slot < S) {
                    int ci = slot / 9, pl = slot - ci * 9;
                    pf[u] = (stager && vld[pl]) ? *(const uint*)(in_b + ci * (HW * HW) + hofs[pl]) : 0u;
                } else pf[u] = 0u;
            }
        }
        #pragma unroll
        for (int dd = 0; dd < 9; ++dd) {
            half8 bfA = *(const half8*)(wbS + (ch * 9 + dd) * 512 + wbase);
            half8 bfB;
            if (DUAL) bfB = *(const half8*)(wbB + (ch * 9 + dd) * 512 + wbase);
            const int doff = ((dd / 3) * 22 + (dd % 3)) * 40;
            #pragma unroll
            for (int s = 0; s < 4; ++s) {
                if (wt + 8 * s < 25) {
                    half8 af = *(const half8*)(Ah + baseh[s] + doff);
                    accA[s] = __builtin_amdgcn_mfma_f32_16x16x32_f16(af, bfA, accA[s], 0, 0, 0);
                    if (DUAL) accB[s] = __builtin_amdgcn_mfma_f32_16x16x32_f16(af, bfB, accB[s], 0, 0, 0);
                }
            }
        }
        if (ch + 1 < NCH) __syncthreads();
    }

    const int co = m16;
    if (co < COUT) {
        #pragma unroll
        for (int s = 0; s < 4; ++s) {
            int t = wt + 8 * s;
            if (t < 25) {
                int km0 = t * 16 + q4 * 4;
                size_t o = ((size_t)(b * COUT + co) * HW + ij) * HW + km0;
                if (OUTF16) {
                    union { ushort_t us[4]; uint2 u2; } pk;
                    #pragma unroll
                    for (int r = 0; r < 4; ++r) {
                        union { _Float16 h; ushort_t u16; } cv;
                        cv.h = (_Float16)fmaxf(accA[s][r], 0.f);
                        pk.us[r] = cv.u16;
                    }
                    *(uint2*)((ushort_t*)outS + o) = pk.u2;
                    if (DUAL) {
                        #pragma unroll
                        for (int r = 0; r < 4; ++r) {
                            union { _Float16 h; ushort_t u16; } cv;
                            cv.h = (_Float16)fmaxf(accB[s][r], 0.f);
                            pk.us[r] = cv.u16;
                        }
                        *(uint2*)((ushort_t*)outB + o) = pk.u2;
                    }
                } else {
                    f32x4 ov;
                    #pragma unroll
                    for (int r = 0; r < 4; ++r) ov[r] = fmaxf(accA[s][r], 0.f);
                    *(f32x4*)((float*)outS + o) = ov;
                }
            }
        }
    }
}

// ---------------------------------------------------------------------------
// Kernel 4b (L3 FUSED, v15): 2-ij merged-N conv over BOTH paths + in-block
// row softmax + attention.V MFMA. Each block owns output rows q = ij0, ij0+1
// completely (all 400 km, both conv paths), so the softmax+AV that used to
// take a 5.12MB c4 round-trip + separate dispatch happens in-block:
//   path A conv -> acc[0]; path B conv -> acc[1] (sequential staging, same
//   LDS tile); rows[q][km] = relu(A)+relu(B) in LDS; 2 waves do the 400-wide
//   softmax via 64-lane shfl reduce -> P[q][.] f16 (+zero pad to 416);
//   AV via mfma(A=fsh c-rows, B=P cols): C[m=c][n=q], cols n>=2 discarded
//   (garbage P rows 2..15 never pollute kept outputs; fsh zero-pad kills
//   k>=400 but P pad is zeroed anyway to avoid 0*NaN).
// ---------------------------------------------------------------------------
template <int CIN>
__global__ __launch_bounds__(512, 2) void conv4d_l3f(
        const ushort_t* __restrict__ b2A, const ushort_t* __restrict__ b2B,
        const ushort_t* __restrict__ wAm, const ushort_t* __restrict__ wBm,
        const ushort_t* __restrict__ fsh, float* __restrict__ att) {
    constexpr int S2 = CIN * 12;
    constexpr int NCH = (S2 + 31) / 32;
    __shared__ __align__(16) ushort_t Ah[484 * 40];
    __shared__ float rows[2][400];
    __shared__ __align__(16) ushort_t P[16][416];   // only rows 0,1 written
    __shared__ float invl[2];
    const int b = blockIdx.y, bx = blockIdx.x;
    const int i = bx / 10, jp = bx - (bx / 10) * 10;
    const int j0 = 2 * jp;
    const int ij0 = i * 20 + j0;
    const int tid = threadIdx.x, wv = tid >> 6, lane = tid & 63;
    const int m16 = lane & 15, q4 = lane >> 4;
    const int wt = 7 - wv;

    HALO_ZERO(512)

    int baseh[4];
    #pragma unroll
    for (int s = 0; s < 4; ++s) {
        int t = wt + 8 * s;
        if (t < 25) {
            int km = t * 16 + m16;
            int kk = km / 20, mm = km - kk * 20;
            baseh[s] = (kk * 22 + mm) * 40 + q4 * 8;
        } else baseh[s] = 0;
    }
    f32x4 acc[2][4] = {};

    const bool stager = tid < 200;
    const int km1 = 2 * tid;
    const int r1 = stager ? ((km1 / 20 + 1) * 22 + (km1 % 20) + 1) : 0;
    int hofs[12]; bool vld[12];
    #pragma unroll
    for (int pl = 0; pl < 12; ++pl) {
        int di = pl >> 2, dj = pl & 3;
        int ii = i + di - 1, jj = j0 + dj - 1;
        vld[pl] = (unsigned)ii < 20u && (unsigned)jj < 20u;
        hofs[pl] = (ii * 20 + jj) * HW + km1;
    }
    const int wbase = m16 * 32 + q4 * 8;
    uint pf[32];

    #pragma unroll
    for (int p = 0; p < 2; ++p) {
        const ushort_t* in_b = (p ? b2B : b2A) + (size_t)b * CIN * HW * HW;
        const ushort_t* wm = p ? wBm : wAm;
        #pragma unroll
        for (int u = 0; u < 32; ++u) {
            int slot = u;
            if (slot < S2) {
                int ci = slot / 12, pl = slot - ci * 12;
                pf[u] = (stager && vld[pl]) ? *(const uint*)(in_b + ci * (HW * HW) + hofs[pl]) : 0u;
            } else pf[u] = 0u;
        }
        __syncthreads();   // p=0: halo-zero done; p=1: path-A MFMA done

        #pragma unroll
        for (int ch = 0; ch < NCH; ++ch) {
            if (stager) {
                #pragma unroll
                for (int g4 = 0; g4 < 8; ++g4) {
                    uint lo0 = (pf[4 * g4] & 0xFFFFu) | (pf[4 * g4 + 1] << 16);
                    uint lo1 = (pf[4 * g4 + 2] & 0xFFFFu) | (pf[4 * g4 + 3] << 16);
                    uint hi0 = (pf[4 * g4] >> 16) | (pf[4 * g4 + 1] & 0xFFFF0000u);
                    uint hi1 = (pf[4 * g4 + 2] >> 16) | (pf[4 * g4 + 3] & 0xFFFF0000u);
                    uint2 wlo; wlo.x = lo0; wlo.y = lo1;
                    uint2 whi; whi.x = hi0; whi.y = hi1;
                    *(uint2*)&Ah[(size_t)r1 * 40 + 4 * g4] = wlo;
                    *(uint2*)&Ah[(size_t)(r1 + 1) * 40 + 4 * g4] = whi;
                }
            }
            __syncthreads();
            if (ch + 1 < NCH) {
                #pragma unroll
                for (int u = 0; u < 32; ++u) {
                    int slot = (ch + 1) * 32 + u;
                    if (slot < S2) {
                        int ci = slot / 12, pl = slot - ci * 12;
                        pf[u] = (stager && vld[pl]) ? *(const uint*)(in_b + ci * (HW * HW) + hofs[pl]) : 0u;
                    } else pf[u] = 0u;
                }
            }
            #pragma unroll
            for (int dd = 0; dd < 9; ++dd) {
                half8 bf1 = *(const half8*)(wm + (ch * 9 + dd) * 512 + wbase);
                const int doff = ((dd / 3) * 22 + (dd % 3)) * 40;
                #pragma unroll
                for (int s = 0; s < 4; ++s) {
                    if (wt + 8 * s < 25) {
                        half8 af = *(const half8*)(Ah + baseh[s] + doff);
                        acc[p][s] = __builtin_amdgcn_mfma_f32_16x16x32_f16(af, bf1, acc[p][s], 0, 0, 0);
                    }
                }
            }
            if (ch + 1 < NCH) __syncthreads();
        }
    }

    // ---- write c4 rows (relu(A)+relu(B)) to LDS ----
    if (m16 < 2) {
        #pragma unroll
        for (int s = 0; s < 4; ++s) {
            int t = wt + 8 * s;
            if (t < 25) {
                int km0 = t * 16 + q4 * 4;
                #pragma unroll
                for (int r = 0; r < 4; ++r)
                    rows[m16][km0 + r] = fmaxf(acc[0][s][r], 0.f) + fmaxf(acc[1][s][r], 0.f);
            }
        }
    }
    __syncthreads();

    // ---- softmax: wave 0 -> row 0, wave 1 -> row 1 ----
    if (wv < 2) {
        const int q = wv;
        float v[7];
        float mx = -1e30f;
        #pragma unroll
        for (int u = 0; u < 7; ++u) {
            int k = lane + 64 * u;
            v[u] = (k < HW) ? rows[q][k] : -1e30f;
            mx = fmaxf(mx, v[u]);
        }
        #pragma unroll
        for (int off = 32; off; off >>= 1) mx = fmaxf(mx, __shfl_xor(mx, off));
        float sum = 0.f;
        #pragma unroll
        for (int u = 0; u < 7; ++u) {
            int k = lane + 64 * u;
            if (k < HW) {
                float e = __expf(TEMPF * (v[u] - mx));
                sum += e;
                union { _Float16 h; ushort_t u16; } cv; cv.h = (_Float16)e;
                P[q][k] = cv.u16;
            }
        }
        if (lane < 16) P[q][400 + lane] = 0;   // zero pad (avoid 0*NaN in MFMA)
        #pragma unroll
        for (int off = 32; off; off >>= 1) sum += __shfl_xor(sum, off);
        if (lane == 0) invl[q] = 1.0f / sum;
    }
    __syncthreads();

    // ---- AV: wave handles 2 c-tiles; C[m=c][n=q], keep n<2 ----
    const ushort_t* fb = fsh + (size_t)b * CH * 416;
    #pragma unroll
    for (int tt = 0; tt < 2; ++tt) {
        const int ct = wv * 2 + tt;
        const ushort_t* fc = fb + (size_t)(ct * 16 + m16) * 416 + q4 * 8;
        f32x4 acc2 = {};
        #pragma unroll
        for (int ks = 0; ks < 13; ++ks) {
            half8 afr = *(const half8*)(fc + ks * 32);
            half8 bfr = *(const half8*)&P[m16][ks * 32 + q4 * 8];
            acc2 = __builtin_amdgcn_mfma_f32_16x16x32_f16(afr, bfr, acc2, 0, 0, 0);
        }
        if (m16 < 2) {
            const int q = ij0 + m16;
            const float il = invl[m16];
            #pragma unroll
            for (int r = 0; r < 4; ++r) {
                int c = ct * 16 + q4 * 4 + r;
                att[((size_t)(b * CH + c)) * HW + q] = acc2[r] * il;
            }
        }
    }
}

// ---------------------------------------------------------------------------
// Kernel 6 (v2): fq = l2norm(f_q, ch) + 0.5 * l2norm(att_fq, ch).
// ---------------------------------------------------------------------------
__global__ __launch_bounds__(256) void final_fq(const float* __restrict__ f_q,
                                                const float* __restrict__ att,
                                                float* __restrict__ out_fq) {
    __shared__ float2 red[4];
    int b = blockIdx.y, q = blockIdx.x;
    int tid = threadIdx.x, wv = tid >> 6, lane = tid & 63;
    size_t idx = (size_t)(b * CH + tid) * HW + q;
    float f = f_q[idx];
    float a = att[idx];
    float vf = f * f, va = a * a;
    #pragma unroll
    for (int off = 32; off; off >>= 1) {
        vf += __shfl_xor(vf, off);
        va += __shfl_xor(va, off);
    }
    if (lane == 0) red[wv] = make_float2(vf, va);
    __syncthreads();
    float sf = red[0].x + red[1].x + red[2].x + red[3].x;
    float sa = red[0].y + red[1].y + red[2].y + red[3].y;
    float invf = 1.0f / fmaxf(sqrtf(sf), EPSF);
    float inva = 1.0f / fmaxf(sqrtf(sa), EPSF);
    out_fq[idx] = f * invf + 0.5f * a * inva;
}

// ---------------------------------------------------------------------------
extern "C" void kernel_launch(void* const* d_in, const int* in_sizes, int n_in,
                              void* d_out, int out_size, void* d_ws, size_t ws_size,
                              hipStream_t stream) {
    const float* fq_feats = (const float*)d_in[0];
    const float* fs_feats = (const float*)d_in[1];
    const float* f_q      = (const float*)d_in[2];
    const float* f_s      = (const float*)d_in[3];
    const float* w1       = (const float*)d_in[4];
    const float* w2       = (const float*)d_in[5];
    const float* w3       = (const float*)d_in[6];
    float* out = (float*)d_out;              // fq at 0, att_fq at 204800

    float* ws      = (float*)d_ws;
    float* wbuf    = ws;                     // weight tables
    float* ssbuf   = wbuf + 115200;          // 14,400 fl: fused-norm ss
    float* corr    = ssbuf + 14400;          // corr f16 + fsh f16 region
    float* buf1    = corr + 2880000;         // 3,200,000 (At / b1A+b1B)
    float* buf2    = buf1 + 3200000;         // 3,200,000 (Bt / b2A+b2B)
    float* att     = out + 204800;

    ushort_t* corr_h = (ushort_t*)corr;
    ushort_t* fsh    = (ushort_t*)(corr + 1440000);
    ushort_t* At = (ushort_t*)buf1;
    ushort_t* Bt = (ushort_t*)buf2;
    ushort_t* b1A = (ushort_t*)buf1;
    ushort_t* b1B = b1A + 3200000;
    ushort_t* b2A = (ushort_t*)buf2;
    ushort_t* b2B = b2A + 3200000;

    ushort_t* wb0   = (ushort_t*)wbuf;
    ushort_t* wbL1A = wb0;
    ushort_t* wbL1B = wb0 + 13824;
    ushort_t* wbL2A = wb0 + 27648;
    ushort_t* wbL2B = wb0 + 41472;
    ushort_t* wbL3Am = wb0 + 55296;
    ushort_t* wbL3Bm = wb0 + 73728;

    prep_all<<<832, 256, 0, stream>>>(w1, w2, w3, f_s, wb0, fsh, ssbuf);

    for (int half = 0; half < 2; ++half) {
        int base = half * 9;
        transpose_f16<<<dim3(16, 7, 18), 256, 0, stream>>>(fq_feats, fs_feats, At, Bt, ssbuf, base);
        corr_gemm_mfma<<<dim3(7, 13, 9), 256, 0, stream>>>(At, Bt, ssbuf, corr_h, base);
    }

    // L1: 800 blocks (block-poor) -> 512 threads
    conv4d_v14h<9, 10, true, true><<<dim3(400, NB, 1), 512, 0, stream>>>(
        corr_h, corr_h, wbL1A, wbL1B, b1A, b1B);
    // L2: 1600 blocks (block-rich) -> 256 threads, proven v8 structure
    conv4d_v8h<10, 10, false, true><<<dim3(400, NB, 2), 256, 0, stream>>>(
        b1A, b1B, wbL2A, wbL2B, b2A, b2B);
    // L3 FUSED: conv(both paths) + softmax + attn.V in one kernel, 400 blocks
    conv4d_l3f<10><<<dim3(200, NB), 512, 0, stream>>>(
        b2A, b2B, wbL3Am, wbL3Bm, fsh, att);

    final_fq<<<dim3(400, NB), 256, 0, stream>>>(f_q, att, out);

    (void)in_sizes; (void)n_in; (void)out_size; (void)ws_size;
}

// Round 11
// 324.165 us; speedup vs baseline: 1.1886x; 1.0152x over previous
//
#include <hip/hip_runtime.h>
#include <math.h>
#include <stddef.h>

#define L9   9
#define NB   2
#define CF   1024
#define HW   400     // 20*20
#define CH   256
#define TEMPF 20.0f
#define EPSF  1e-12f

typedef _Float16 half8 __attribute__((ext_vector_type(8)));
typedef float f32x4 __attribute__((ext_vector_type(4)));
typedef unsigned short ushort_t;

// Zero only the 84 halo rows of the 22x22 (pitch-40-half) A-tile.
#define HALO_ZERO(NT)                                                          \
    for (int h = threadIdx.x; h < 84 * 20; h += (NT)) {                        \
        int rs = h / 20, c = h - rs * 20;                                      \
        int row = rs < 22 ? rs                                                 \
                : rs < 44 ? 440 + rs                                           \
                : rs < 64 ? (rs - 43) * 22                                     \
                          : (rs - 63) * 22 + 21;                               \
        ((uint*)Ah)[row * 20 + c] = 0;                                         \
    }

// ---------------------------------------------------------------------------
// Kernel P: ALL prep work in ONE launch (weight tables + fsh + ss zero).
// ---------------------------------------------------------------------------
__global__ __launch_bounds__(256) void prep_all(const float* __restrict__ w1,
                                                const float* __restrict__ w2,
                                                const float* __restrict__ w3,
                                                const float* __restrict__ f_s,
                                                ushort_t* __restrict__ wb0,
                                                ushort_t* __restrict__ fsh,
                                                float* __restrict__ ssbuf) {
    int gid = blockIdx.x * 256 + threadIdx.x;
    if (gid < NB * CH * 416) {
        int s = gid % 416, bc = gid / 416;
        float v = (s < HW) ? f_s[(size_t)bc * HW + s] : 0.f;
        union { _Float16 h; ushort_t u; } cv; cv.h = (_Float16)v;
        fsh[gid] = cv.u;
    }
    if (gid < 14400) ssbuf[gid] = 0.f;
    if (gid < 6 * 18432) {
        int job = gid / 18432, idx = gid - job * 18432;
        int k = idx & 31, n = (idx >> 5) & 15, dd = (idx >> 9) % 9, ch = idx / 4608;
        int dk = dd / 3, dm = dd % 3;
        float v = 0.f;
        if (job < 4) {
            if (idx < 13824) {
                int CIN = (job < 2) ? 9 : 10;
                const float* wt = (job < 2) ? w1 : w2;
                bool swap = job & 1;
                int slot = ch * 32 + k;
                if (n < 10 && slot < CIN * 9) {
                    int ci = slot / 9, pl = slot - ci * 9;
                    int di = pl / 3, dj = pl % 3;
                    int widx = swap ? ((((n * CIN + ci) * 3 + dk) * 3 + dm) * 3 + di) * 3 + dj
                                    : ((((n * CIN + ci) * 3 + di) * 3 + dj) * 3 + dk) * 3 + dm;
                    v = wt[widx];
                }
                union { _Float16 h; ushort_t u; } cv; cv.h = (_Float16)v;
                wb0[job * 13824 + idx] = cv.u;
            }
        } else {
            bool swap = (job == 5);
            int slot = ch * 32 + k;
            if (slot < 120) {
                int ci = slot / 12, r = slot - ci * 12;
                int di = r >> 2, dj4 = r & 3;
                int e = dj4 - n;
                if (n < 2 && e >= 0 && e <= 2) {
                    int widx = swap ? (((ci * 3 + dk) * 3 + dm) * 3 + di) * 3 + e
                                    : (((ci * 3 + di) * 3 + e) * 3 + dk) * 3 + dm;
                    v = w3[widx];
                }
            }
            union { _Float16 h; ushort_t u; } cv; cv.h = (_Float16)v;
            wb0[55296 + (job - 4) * 18432 + idx] = cv.u;
        }
    }
}

// ---------------------------------------------------------------------------
// Kernel 3a (v2): transpose+convert WITH FUSED NORM PARTIALS.
// ---------------------------------------------------------------------------
__global__ __launch_bounds__(256) void transpose_f16(const float* __restrict__ fq,
                                                     const float* __restrict__ fs,
                                                     ushort_t* __restrict__ At,
                                                     ushort_t* __restrict__ Bt,
                                                     float* __restrict__ ssbuf,
                                                     int lb_base) {
    __shared__ float tile[64][65];
    __shared__ float red4[4][64];
    int z = blockIdx.z;
    int tsel = z / 9, li = z - tsel * 9;
    int lb = lb_base + li;
    const float* src = (tsel ? fs : fq) + (size_t)lb * CF * HW;
    ushort_t* dst = (tsel ? Bt : At) + (size_t)li * HW * CF;
    int c0 = blockIdx.x * 64, ij0 = blockIdx.y * 64;
    int tid = threadIdx.x;
    int cl = tid >> 6;
    int col = tid & 63;
    float ssp = 0.f;
    #pragma unroll
    for (int rr = 0; rr < 16; ++rr) {
        int c_local = rr * 4 + cl;
        int ij = ij0 + col;
        float v = (ij < HW) ? src[(size_t)(c0 + c_local) * HW + ij] : 0.f;
        tile[c_local][col] = v;
        ssp = fmaf(v, v, ssp);
    }
    red4[cl][col] = ssp;
    __syncthreads();
    if (cl == 0) {
        int ij = ij0 + col;
        if (ij < HW) {
            float s4 = red4[0][col] + red4[1][col] + red4[2][col] + red4[3][col];
            atomicAdd(&ssbuf[(size_t)(tsel * 18 + lb) * HW + ij], s4);
        }
    }
    int cp = (tid & 31) * 2;
    int rowsel = tid >> 5;
    #pragma unroll
    for (int rr = 0; rr < 8; ++rr) {
        int ij_local = rr * 8 + rowsel;
        int ij = ij0 + ij_local;
        if (ij < HW) {
            union { _Float16 h; ushort_t u; } h0, h1;
            h0.h = (_Float16)tile[cp][ij_local];
            h1.h = (_Float16)tile[cp + 1][ij_local];
            ushort2 o; o.x = h0.u; o.y = h1.u;
            *(ushort2*)(dst + (size_t)ij * CF + c0 + cp) = o;
        }
    }
}

// ---------------------------------------------------------------------------
// Kernel 3b (v2): MFMA fp16 correlation GEMM, M-SPLIT 32x64 tiles.
// ---------------------------------------------------------------------------
__global__ __launch_bounds__(256) void corr_gemm_mfma(const ushort_t* __restrict__ At,
                                                      const ushort_t* __restrict__ Bt,
                                                      const float* __restrict__ ssbuf,
                                                      ushort_t* __restrict__ corr,
                                                      int lb_base) {
    __shared__ ushort_t As[32][72];
    __shared__ ushort_t Bs[64][72];
    int li = blockIdx.z, lb = lb_base + li;
    int l = lb >> 1, b = lb & 1;
    int i0 = blockIdx.y * 32, j0 = blockIdx.x * 64;
    int tid = threadIdx.x, lane = tid & 63, w = tid >> 6;
    int mw = (w >> 1) * 16, nw = (w & 1) * 32;
    f32x4 acc[2] = {};
    const ushort_t* Abase = At + (size_t)li * HW * CF;
    const ushort_t* Bbase = Bt + (size_t)li * HW * CF;

    for (int kt = 0; kt < 16; ++kt) {
        int c0 = kt * 64;
        __syncthreads();
        {
            int row = tid >> 3, c8 = tid & 7;
            uint4 va = make_uint4(0, 0, 0, 0);
            if (i0 + row < HW) va = *(const uint4*)(Abase + (size_t)(i0 + row) * CF + c0 + c8 * 8);
            *(uint4*)&As[row][c8 * 8] = va;
        }
        #pragma unroll
        for (int p = 0; p < 2; ++p) {
            int idx = tid + p * 256;
            int row = idx >> 3, c8 = idx & 7;
            uint4 vb = make_uint4(0, 0, 0, 0);
            if (j0 + row < HW) vb = *(const uint4*)(Bbase + (size_t)(j0 + row) * CF + c0 + c8 * 8);
            *(uint4*)&Bs[row][c8 * 8] = vb;
        }
        __syncthreads();
        #pragma unroll
        for (int ks = 0; ks < 2; ++ks) {
            int k0 = ks * 32 + (lane >> 4) * 8;
            half8 a0 = *(const half8*)&As[mw + (lane & 15)][k0];
            half8 b0 = *(const half8*)&Bs[nw + (lane & 15)][k0];
            half8 b1 = *(const half8*)&Bs[nw + 16 + (lane & 15)][k0];
            acc[0] = __builtin_amdgcn_mfma_f32_16x16x32_f16(a0, b0, acc[0], 0, 0, 0);
            acc[1] = __builtin_amdgcn_mfma_f32_16x16x32_f16(a0, b1, acc[1], 0, 0, 0);
        }
    }
    int obase = (b * 9 + l) * HW;
    #pragma unroll
    for (int ni = 0; ni < 2; ++ni) {
        int km = j0 + nw + ni * 16 + (lane & 15);
        if (km >= HW) continue;
        float ib = 1.0f / fmaxf(sqrtf(ssbuf[(size_t)(18 + lb) * HW + km]), EPSF);
        #pragma unroll
        for (int r = 0; r < 4; ++r) {
            int ij = i0 + mw + (lane >> 4) * 4 + r;
            if (ij < HW) {
                float ia = 1.0f / fmaxf(sqrtf(ssbuf[(size_t)lb * HW + ij]), EPSF);
                union { _Float16 h; ushort_t u; } cv;
                cv.h = (_Float16)(acc[ni][r] * ia * ib);
                corr[(size_t)(obase + ij) * HW + km] = cv.u;
            }
        }
    }
}

// ---------------------------------------------------------------------------
// Kernel 4 (v8h): 256-thread conv (L2, 1600-block regime).
// ---------------------------------------------------------------------------
template <int CIN, int COUT, bool DUAL, bool OUTF16>
__global__ __launch_bounds__(256) void conv4d_v8h(const ushort_t* __restrict__ inA,
                                                  const ushort_t* __restrict__ inB,
                                                  const ushort_t* __restrict__ wbA,
                                                  const ushort_t* __restrict__ wbB,
                                                  void* __restrict__ outA,
                                                  void* __restrict__ outB) {
    constexpr int S = CIN * 9;
    constexpr int NCH = (S + 31) / 32;
    __shared__ __align__(16) ushort_t Ah[484 * 40];
    const int b = blockIdx.y, ij = blockIdx.x;
    const int z = blockIdx.z;
    const ushort_t* in = (DUAL || z == 0) ? inA : inB;
    const ushort_t* wbS = (DUAL || z == 0) ? wbA : wbB;
    void* outS = (DUAL || z == 0) ? outA : outB;
    const int i = ij / 20, j = ij - (ij / 20) * 20;
    const int tid = threadIdx.x, wv = tid >> 6, lane = tid & 63;
    const int m16 = lane & 15, q4 = lane >> 4;

    HALO_ZERO(256)

    int baseh[7];
    #pragma unroll
    for (int s = 0; s < 7; ++s) {
        int t = wv + 4 * s;
        if (t < 25) {
            int km = t * 16 + m16;
            int kk = km / 20, mm = km - kk * 20;
            baseh[s] = (kk * 22 + mm) * 40 + q4 * 8;
        } else baseh[s] = 0;
    }
    f32x4 accA[7] = {};
    f32x4 accB[7] = {};

    const bool stager = tid < 200;
    const int km1 = 2 * tid;
    const int r1 = stager ? ((km1 / 20 + 1) * 22 + (km1 % 20) + 1) : 0;
    int hofs[9]; bool vld[9];
    #pragma unroll
    for (int pl = 0; pl < 9; ++pl) {
        int ii = i + pl / 3 - 1, jj = j + pl % 3 - 1;
        vld[pl] = (unsigned)ii < 20u && (unsigned)jj < 20u;
        hofs[pl] = (ii * 20 + jj) * HW + km1;
    }
    const ushort_t* in_b = in + (size_t)b * CIN * HW * HW;
    const int wbase = m16 * 32 + q4 * 8;

    uint pf[32];
    #pragma unroll
    for (int u = 0; u < 32; ++u) {
        int slot = u;
        if (slot < S) {
            int ci = slot / 9, pl = slot - ci * 9;
            pf[u] = (stager && vld[pl]) ? *(const uint*)(in_b + ci * (HW * HW) + hofs[pl]) : 0u;
        } else pf[u] = 0u;
    }
    __syncthreads();

    #pragma unroll
    for (int ch = 0; ch < NCH; ++ch) {
        if (stager) {
            #pragma unroll
            for (int g4 = 0; g4 < 8; ++g4) {
                uint lo0 = (pf[4 * g4] & 0xFFFFu) | (pf[4 * g4 + 1] << 16);
                uint lo1 = (pf[4 * g4 + 2] & 0xFFFFu) | (pf[4 * g4 + 3] << 16);
                uint hi0 = (pf[4 * g4] >> 16) | (pf[4 * g4 + 1] & 0xFFFF0000u);
                uint hi1 = (pf[4 * g4 + 2] >> 16) | (pf[4 * g4 + 3] & 0xFFFF0000u);
                uint2 wlo; wlo.x = lo0; wlo.y = lo1;
                uint2 whi; whi.x = hi0; whi.y = hi1;
                *(uint2*)&Ah[(size_t)r1 * 40 + 4 * g4] = wlo;
                *(uint2*)&Ah[(size_t)(r1 + 1) * 40 + 4 * g4] = whi;
            }
        }
        __syncthreads();
        if (ch + 1 < NCH) {
            #pragma unroll
            for (int u = 0; u < 32; ++u) {
                int slot = (ch + 1) * 32 + u;
                if (slot < S) {
                    int ci = slot / 9, pl = slot - ci * 9;
                    pf[u] = (stager && vld[pl]) ? *(const uint*)(in_b + ci * (HW * HW) + hofs[pl]) : 0u;
                } else pf[u] = 0u;
            }
        }
        #pragma unroll
        for (int dd = 0; dd < 9; ++dd) {
            half8 bfA = *(const half8*)(wbS + (ch * 9 + dd) * 512 + wbase);
            half8 bfB;
            if (DUAL) bfB = *(const half8*)(wbB + (ch * 9 + dd) * 512 + wbase);
            const int doff = ((dd / 3) * 22 + (dd % 3)) * 40;
            #pragma unroll
            for (int s = 0; s < 7; ++s) {
                if (wv + 4 * s < 25) {
                    half8 af = *(const half8*)(Ah + baseh[s] + doff);
                    accA[s] = __builtin_amdgcn_mfma_f32_16x16x32_f16(af, bfA, accA[s], 0, 0, 0);
                    if (DUAL) accB[s] = __builtin_amdgcn_mfma_f32_16x16x32_f16(af, bfB, accB[s], 0, 0, 0);
                }
            }
        }
        if (ch + 1 < NCH) __syncthreads();
    }

    const int co = m16;
    if (co < COUT) {
        #pragma unroll
        for (int s = 0; s < 7; ++s) {
            int t = wv + 4 * s;
            if (t < 25) {
                int km0 = t * 16 + q4 * 4;
                size_t o = ((size_t)(b * COUT + co) * HW + ij) * HW + km0;
                if (OUTF16) {
                    union { ushort_t us[4]; uint2 u2; } pk;
                    #pragma unroll
                    for (int r = 0; r < 4; ++r) {
                        union { _Float16 h; ushort_t u16; } cv;
                        cv.h = (_Float16)fmaxf(accA[s][r], 0.f);
                        pk.us[r] = cv.u16;
                    }
                    *(uint2*)((ushort_t*)outS + o) = pk.u2;
                    if (DUAL) {
                        #pragma unroll
                        for (int r = 0; r < 4; ++r) {
                            union { _Float16 h; ushort_t u16; } cv;
                            cv.h = (_Float16)fmaxf(accB[s][r], 0.f);
                            pk.us[r] = cv.u16;
                        }
                        *(uint2*)((ushort_t*)outB + o) = pk.u2;
                    }
                } else {
                    f32x4 ov;
                    #pragma unroll
                    for (int r = 0; r < 4; ++r) ov[r] = fmaxf(accA[s][r], 0.f);
                    *(f32x4*)((float*)outS + o) = ov;
                }
            }
        }
    }
}

// ---------------------------------------------------------------------------
// Kernel 4 (v14h): 512-thread conv for block-poor dispatches (L1: 800 blocks).
// ---------------------------------------------------------------------------
template <int CIN, int COUT, bool DUAL, bool OUTF16>
__global__ __launch_bounds__(512, 2) void conv4d_v14h(const ushort_t* __restrict__ inA,
                                                      const ushort_t* __restrict__ inB,
                                                      const ushort_t* __restrict__ wbA,
                                                      const ushort_t* __restrict__ wbB,
                                                      void* __restrict__ outA,
                                                      void* __restrict__ outB) {
    constexpr int S = CIN * 9;
    constexpr int NCH = (S + 31) / 32;
    __shared__ __align__(16) ushort_t Ah[484 * 40];
    const int b = blockIdx.y, ij = blockIdx.x;
    const int z = blockIdx.z;
    const ushort_t* in = (DUAL || z == 0) ? inA : inB;
    const ushort_t* wbS = (DUAL || z == 0) ? wbA : wbB;
    void* outS = (DUAL || z == 0) ? outA : outB;
    const int i = ij / 20, j = ij - (ij / 20) * 20;
    const int tid = threadIdx.x, wv = tid >> 6, lane = tid & 63;
    const int m16 = lane & 15, q4 = lane >> 4;
    const int wt = 7 - wv;

    HALO_ZERO(512)

    int baseh[4];
    #pragma unroll
    for (int s = 0; s < 4; ++s) {
        int t = wt + 8 * s;
        if (t < 25) {
            int km = t * 16 + m16;
            int kk = km / 20, mm = km - kk * 20;
            baseh[s] = (kk * 22 + mm) * 40 + q4 * 8;
        } else baseh[s] = 0;
    }
    f32x4 accA[4] = {};
    f32x4 accB[4] = {};

    const bool stager = tid < 200;
    const int km1 = 2 * tid;
    const int r1 = stager ? ((km1 / 20 + 1) * 22 + (km1 % 20) + 1) : 0;
    int hofs[9]; bool vld[9];
    #pragma unroll
    for (int pl = 0; pl < 9; ++pl) {
        int ii = i + pl / 3 - 1, jj = j + pl % 3 - 1;
        vld[pl] = (unsigned)ii < 20u && (unsigned)jj < 20u;
        hofs[pl] = (ii * 20 + jj) * HW + km1;
    }
    const ushort_t* in_b = in + (size_t)b * CIN * HW * HW;
    const int wbase = m16 * 32 + q4 * 8;

    uint pf[32];
    #pragma unroll
    for (int u = 0; u < 32; ++u) {
        int slot = u;
        if (slot < S) {
            int ci = slot / 9, pl = slot - ci * 9;
            pf[u] = (stager && vld[pl]) ? *(const uint*)(in_b + ci * (HW * HW) + hofs[pl]) : 0u;
        } else pf[u] = 0u;
    }
    __syncthreads();

    #pragma unroll
    for (int ch = 0; ch < NCH; ++ch) {
        if (stager) {
            #pragma unroll
            for (int g4 = 0; g4 < 8; ++g4) {
                uint lo0 = (pf[4 * g4] & 0xFFFFu) | (pf[4 * g4 + 1] << 16);
                uint lo1 = (pf[4 * g4 + 2] & 0xFFFFu) | (pf[4 * g4 + 3] << 16);
                uint hi0 = (pf[4 * g4] >> 16) | (pf[4 * g4 + 1] & 0xFFFF0000u);
                uint hi1 = (pf[4 * g4 + 2] >> 16) | (pf[4 * g4 + 3] & 0xFFFF0000u);
                uint2 wlo; wlo.x = lo0; wlo.y = lo1;
                uint2 whi; whi.x = hi0; whi.y = hi1;
                *(uint2*)&Ah[(size_t)r1 * 40 + 4 * g4] = wlo;
                *(uint2*)&Ah[(size_t)(r1 + 1) * 40 + 4 * g4] = whi;
            }
        }
        __syncthreads();
        if (ch + 1 < NCH) {
            #pragma unroll
            for (int u = 0; u < 32; ++u) {
                int slot = (ch + 1) * 32 + u;
                if (slot < S) {
                    int ci = slot / 9, pl = slot - ci * 9;
                    pf[u] = (stager && vld[pl]) ? *(const uint*)(in_b + ci * (HW * HW) + hofs[pl]) : 0u;
                } else pf[u] = 0u;
            }
        }
        #pragma unroll
        for (int dd = 0; dd < 9; ++dd) {
            half8 bfA = *(const half8*)(wbS + (ch * 9 + dd) * 512 + wbase);
            half8 bfB;
            if (DUAL) bfB = *(const half8*)(wbB + (ch * 9 + dd) * 512 + wbase);
            const int doff = ((dd / 3) * 22 + (dd % 3)) * 40;
            #pragma unroll
            for (int s = 0; s < 4; ++s) {
                if (wt + 8 * s < 25) {
                    half8 af = *(const half8*)(Ah + baseh[s] + doff);
                    accA[s] = __builtin_amdgcn_mfma_f32_16x16x32_f16(af, bfA, accA[s], 0, 0, 0);
                    if (DUAL) accB[s] = __builtin_amdgcn_mfma_f32_16x16x32_f16(af, bfB, accB[s], 0, 0, 0);
                }
            }
        }
        if (ch + 1 < NCH) __syncthreads();
    }

    const int co = m16;
    if (co < COUT) {
        #pragma unroll
        for (int s = 0; s < 4; ++s) {
            int t = wt + 8 * s;
            if (t < 25) {
                int km0 = t * 16 + q4 * 4;
                size_t o = ((size_t)(b * COUT + co) * HW + ij) * HW + km0;
                if (OUTF16) {
                    union { ushort_t us[4]; uint2 u2; } pk;
                    #pragma unroll
                    for (int r = 0; r < 4; ++r) {
                        union { _Float16 h; ushort_t u16; } cv;
                        cv.h = (_Float16)fmaxf(accA[s][r], 0.f);
                        pk.us[r] = cv.u16;
                    }
                    *(uint2*)((ushort_t*)outS + o) = pk.u2;
                    if (DUAL) {
                        #pragma unroll
                        for (int r = 0; r < 4; ++r) {
                            union { _Float16 h; ushort_t u16; } cv;
                            cv.h = (_Float16)fmaxf(accB[s][r], 0.f);
                            pk.us[r] = cv.u16;
                        }
                        *(uint2*)((ushort_t*)outB + o) = pk.u2;
                    }
                } else {
                    f32x4 ov;
                    #pragma unroll
                    for (int r = 0; r < 4; ++r) ov[r] = fmaxf(accA[s][r], 0.f);
                    *(f32x4*)((float*)outS + o) = ov;
                }
            }
        }
    }
}

// ---------------------------------------------------------------------------
// Kernel 4b (L3 FUSED, v16): 2-ij merged-N conv over BOTH paths + in-block
// row softmax + attention.V MFMA + FUSED final_fq.
// The block computes att[c][q] for ALL 256 c and its 2 q values, so the
// per-(b,q) channel norms of final_fq reduce entirely in-block:
//   AV lanes (m16<2) keep attv = acc2*invl and read f_q[c][q] (8 scattered
//   reads each); per-lane sum(a^2), sum(f^2) -> shfl_xor(16,32) across q4
//   -> per-wave LDS -> 2 threads finalize invf/inva -> broadcast -> AV
//   lanes write att AND out_fq. Removes the final_fq dispatch + att/f_q
//   re-read passes.
// ---------------------------------------------------------------------------
template <int CIN>
__global__ __launch_bounds__(512, 2) void conv4d_l3f(
        const ushort_t* __restrict__ b2A, const ushort_t* __restrict__ b2B,
        const ushort_t* __restrict__ wAm, const ushort_t* __restrict__ wBm,
        const ushort_t* __restrict__ fsh, const float* __restrict__ f_q,
        float* __restrict__ att, float* __restrict__ out_fq) {
    constexpr int S2 = CIN * 12;
    constexpr int NCH = (S2 + 31) / 32;
    __shared__ __align__(16) ushort_t Ah[484 * 40];
    __shared__ float rows[2][400];
    __shared__ __align__(16) ushort_t P[16][416];   // only rows 0,1 written
    __shared__ float invl[2];
    __shared__ float redA[8][2], redF[8][2];
    __shared__ float invAF[2][2];                   // [q][0]=invf, [1]=inva
    const int b = blockIdx.y, bx = blockIdx.x;
    const int i = bx / 10, jp = bx - (bx / 10) * 10;
    const int j0 = 2 * jp;
    const int ij0 = i * 20 + j0;
    const int tid = threadIdx.x, wv = tid >> 6, lane = tid & 63;
    const int m16 = lane & 15, q4 = lane >> 4;
    const int wt = 7 - wv;

    HALO_ZERO(512)

    int baseh[4];
    #pragma unroll
    for (int s = 0; s < 4; ++s) {
        int t = wt + 8 * s;
        if (t < 25) {
            int km = t * 16 + m16;
            int kk = km / 20, mm = km - kk * 20;
            baseh[s] = (kk * 22 + mm) * 40 + q4 * 8;
        } else baseh[s] = 0;
    }
    f32x4 acc[2][4] = {};

    const bool stager = tid < 200;
    const int km1 = 2 * tid;
    const int r1 = stager ? ((km1 / 20 + 1) * 22 + (km1 % 20) + 1) : 0;
    int hofs[12]; bool vld[12];
    #pragma unroll
    for (int pl = 0; pl < 12; ++pl) {
        int di = pl >> 2, dj = pl & 3;
        int ii = i + di - 1, jj = j0 + dj - 1;
        vld[pl] = (unsigned)ii < 20u && (unsigned)jj < 20u;
        hofs[pl] = (ii * 20 + jj) * HW + km1;
    }
    const int wbase = m16 * 32 + q4 * 8;
    uint pf[32];

    #pragma unroll
    for (int p = 0; p < 2; ++p) {
        const ushort_t* in_b = (p ? b2B : b2A) + (size_t)b * CIN * HW * HW;
        const ushort_t* wm = p ? wBm : wAm;
        #pragma unroll
        for (int u = 0; u < 32; ++u) {
            int slot = u;
            if (slot < S2) {
                int ci = slot / 12, pl = slot - ci * 12;
                pf[u] = (stager && vld[pl]) ? *(const uint*)(in_b + ci * (HW * HW) + hofs[pl]) : 0u;
            } else pf[u] = 0u;
        }
        __syncthreads();   // p=0: halo-zero done; p=1: path-A MFMA done

        #pragma unroll
        for (int ch = 0; ch < NCH; ++ch) {
            if (stager) {
                #pragma unroll
                for (int g4 = 0; g4 < 8; ++g4) {
                    uint lo0 = (pf[4 * g4] & 0xFFFFu) | (pf[4 * g4 + 1] << 16);
                    uint lo1 = (pf[4 * g4 + 2] & 0xFFFFu) | (pf[4 * g4 + 3] << 16);
                    uint hi0 = (pf[4 * g4] >> 16) | (pf[4 * g4 + 1] & 0xFFFF0000u);
                    uint hi1 = (pf[4 * g4 + 2] >> 16) | (pf[4 * g4 + 3] & 0xFFFF0000u);
                    uint2 wlo; wlo.x = lo0; wlo.y = lo1;
                    uint2 whi; whi.x = hi0; whi.y = hi1;
                    *(uint2*)&Ah[(size_t)r1 * 40 + 4 * g4] = wlo;
                    *(uint2*)&Ah[(size_t)(r1 + 1) * 40 + 4 * g4] = whi;
                }
            }
            __syncthreads();
            if (ch + 1 < NCH) {
                #pragma unroll
                for (int u = 0; u < 32; ++u) {
                    int slot = (ch + 1) * 32 + u;
                    if (slot < S2) {
                        int ci = slot / 12, pl = slot - ci * 12;
                        pf[u] = (stager && vld[pl]) ? *(const uint*)(in_b + ci * (HW * HW) + hofs[pl]) : 0u;
                    } else pf[u] = 0u;
                }
            }
            #pragma unroll
            for (int dd = 0; dd < 9; ++dd) {
                half8 bf1 = *(const half8*)(wm + (ch * 9 + dd) * 512 + wbase);
                const int doff = ((dd / 3) * 22 + (dd % 3)) * 40;
                #pragma unroll
                for (int s = 0; s < 4; ++s) {
                    if (wt + 8 * s < 25) {
                        half8 af = *(const half8*)(Ah + baseh[s] + doff);
                        acc[p][s] = __builtin_amdgcn_mfma_f32_16x16x32_f16(af, bf1, acc[p][s], 0, 0, 0);
                    }
                }
            }
            if (ch + 1 < NCH) __syncthreads();
        }
    }

    // ---- write c4 rows (relu(A)+relu(B)) to LDS ----
    if (m16 < 2) {
        #pragma unroll
        for (int s = 0; s < 4; ++s) {
            int t = wt + 8 * s;
            if (t < 25) {
                int km0 = t * 16 + q4 * 4;
                #pragma unroll
                for (int r = 0; r < 4; ++r)
                    rows[m16][km0 + r] = fmaxf(acc[0][s][r], 0.f) + fmaxf(acc[1][s][r], 0.f);
            }
        }
    }
    __syncthreads();

    // ---- softmax: wave 0 -> row 0, wave 1 -> row 1 ----
    if (wv < 2) {
        const int q = wv;
        float v[7];
        float mx = -1e30f;
        #pragma unroll
        for (int u = 0; u < 7; ++u) {
            int k = lane + 64 * u;
            v[u] = (k < HW) ? rows[q][k] : -1e30f;
            mx = fmaxf(mx, v[u]);
        }
        #pragma unroll
        for (int off = 32; off; off >>= 1) mx = fmaxf(mx, __shfl_xor(mx, off));
        float sum = 0.f;
        #pragma unroll
        for (int u = 0; u < 7; ++u) {
            int k = lane + 64 * u;
            if (k < HW) {
                float e = __expf(TEMPF * (v[u] - mx));
                sum += e;
                union { _Float16 h; ushort_t u16; } cv; cv.h = (_Float16)e;
                P[q][k] = cv.u16;
            }
        }
        if (lane < 16) P[q][400 + lane] = 0;   // zero pad (avoid 0*NaN in MFMA)
        #pragma unroll
        for (int off = 32; off; off >>= 1) sum += __shfl_xor(sum, off);
        if (lane == 0) invl[q] = 1.0f / sum;
    }
    __syncthreads();

    // ---- AV: wave handles 2 c-tiles; keep attv + f_q values in registers ----
    const ushort_t* fb = fsh + (size_t)b * CH * 416;
    float attv[2][4];
    float fvv[2][4];
    float apart = 0.f, fpart = 0.f;
    #pragma unroll
    for (int tt = 0; tt < 2; ++tt) {
        const int ct = wv * 2 + tt;
        const ushort_t* fc = fb + (size_t)(ct * 16 + m16) * 416 + q4 * 8;
        f32x4 acc2 = {};
        #pragma unroll
        for (int ks = 0; ks < 13; ++ks) {
            half8 afr = *(const half8*)(fc + ks * 32);
            half8 bfr = *(const half8*)&P[m16][ks * 32 + q4 * 8];
            acc2 = __builtin_amdgcn_mfma_f32_16x16x32_f16(afr, bfr, acc2, 0, 0, 0);
        }
        if (m16 < 2) {
            const float il = invl[m16];
            #pragma unroll
            for (int r = 0; r < 4; ++r) {
                float a = acc2[r] * il;
                attv[tt][r] = a;
                apart = fmaf(a, a, apart);
                int c = ct * 16 + q4 * 4 + r;
                float f = f_q[((size_t)(b * CH + c)) * HW + ij0 + m16];
                fvv[tt][r] = f;
                fpart = fmaf(f, f, fpart);
            }
        }
    }

    // ---- fused final_fq: reduce a^2, f^2 over c (per q) ----
    // lanes q4*16+m16 (m16<2): xor 16/32 flips q4 bits, preserves m16.
    apart += __shfl_xor(apart, 16);
    apart += __shfl_xor(apart, 32);
    fpart += __shfl_xor(fpart, 16);
    fpart += __shfl_xor(fpart, 32);
    if (lane < 2) { redA[wv][lane] = apart; redF[wv][lane] = fpart; }
    __syncthreads();
    if (tid < 2) {
        float sa = 0.f, sf = 0.f;
        #pragma unroll
        for (int w8 = 0; w8 < 8; ++w8) { sa += redA[w8][tid]; sf += redF[w8][tid]; }
        invAF[tid][0] = 1.0f / fmaxf(sqrtf(sf), EPSF);
        invAF[tid][1] = 1.0f / fmaxf(sqrtf(sa), EPSF);
    }
    __syncthreads();

    if (m16 < 2) {
        const int q = ij0 + m16;
        const float invf = invAF[m16][0], inva = invAF[m16][1];
        #pragma unroll
        for (int tt = 0; tt < 2; ++tt) {
            const int ct = wv * 2 + tt;
            #pragma unroll
            for (int r = 0; r < 4; ++r) {
                int c = ct * 16 + q4 * 4 + r;
                size_t o = ((size_t)(b * CH + c)) * HW + q;
                att[o] = attv[tt][r];
                out_fq[o] = fvv[tt][r] * invf + 0.5f * attv[tt][r] * inva;
            }
        }
    }
}

// ---------------------------------------------------------------------------
extern "C" void kernel_launch(void* const* d_in, const int* in_sizes, int n_in,
                              void* d_out, int out_size, void* d_ws, size_t ws_size,
                              hipStream_t stream) {
    const float* fq_feats = (const float*)d_in[0];
    const float* fs_feats = (const float*)d_in[1];
    const float* f_q      = (const float*)d_in[2];
    const float* f_s      = (const float*)d_in[3];
    const float* w1       = (const float*)d_in[4];
    const float* w2       = (const float*)d_in[5];
    const float* w3       = (const float*)d_in[6];
    float* out = (float*)d_out;              // fq at 0, att_fq at 204800

    float* ws      = (float*)d_ws;
    float* wbuf    = ws;                     // weight tables
    float* ssbuf   = wbuf + 115200;          // 14,400 fl: fused-norm ss
    float* corr    = ssbuf + 14400;          // corr f16 + fsh f16 region
    float* buf1    = corr + 2880000;         // 3,200,000 (At / b1A+b1B)
    float* buf2    = buf1 + 3200000;         // 3,200,000 (Bt / b2A+b2B)
    float* att     = out + 204800;

    ushort_t* corr_h = (ushort_t*)corr;
    ushort_t* fsh    = (ushort_t*)(corr + 1440000);
    ushort_t* At = (ushort_t*)buf1;
    ushort_t* Bt = (ushort_t*)buf2;
    ushort_t* b1A = (ushort_t*)buf1;
    ushort_t* b1B = b1A + 3200000;
    ushort_t* b2A = (ushort_t*)buf2;
    ushort_t* b2B = b2A + 3200000;

    ushort_t* wb0   = (ushort_t*)wbuf;
    ushort_t* wbL1A = wb0;
    ushort_t* wbL1B = wb0 + 13824;
    ushort_t* wbL2A = wb0 + 27648;
    ushort_t* wbL2B = wb0 + 41472;
    ushort_t* wbL3Am = wb0 + 55296;
    ushort_t* wbL3Bm = wb0 + 73728;

    prep_all<<<832, 256, 0, stream>>>(w1, w2, w3, f_s, wb0, fsh, ssbuf);

    for (int half = 0; half < 2; ++half) {
        int base = half * 9;
        transpose_f16<<<dim3(16, 7, 18), 256, 0, stream>>>(fq_feats, fs_feats, At, Bt, ssbuf, base);
        corr_gemm_mfma<<<dim3(7, 13, 9), 256, 0, stream>>>(At, Bt, ssbuf, corr_h, base);
    }

    // L1: 800 blocks (block-poor) -> 512 threads
    conv4d_v14h<9, 10, true, true><<<dim3(400, NB, 1), 512, 0, stream>>>(
        corr_h, corr_h, wbL1A, wbL1B, b1A, b1B);
    // L2: 1600 blocks (block-rich) -> 256 threads, proven v8 structure
    conv4d_v8h<10, 10, false, true><<<dim3(400, NB, 2), 256, 0, stream>>>(
        b1A, b1B, wbL2A, wbL2B, b2A, b2B);
    // L3 FUSED: conv(both paths) + softmax + attn.V + final_fq, 400 blocks
    conv4d_l3f<10><<<dim3(200, NB), 512, 0, stream>>>(
        b2A, b2B, wbL3Am, wbL3Bm, fsh, f_q, att, out);

    (void)in_sizes; (void)n_in; (void)out_size; (void)ws_size;
}